// Round 12
// baseline (1026.422 us; speedup 1.0000x reference)
//
#include <hip/hip_runtime.h>

namespace {

constexpr int N   = 100000;
constexpr int E   = 600000;
constexpr int B   = 50;
constexpr int F   = 40;
constexpr int TF  = B * F;     // 2000
constexpr int D0  = 64;
constexpr int H   = 128;
constexpr int C   = 2;

typedef __attribute__((ext_vector_type(8))) __bf16 bf16x8;
typedef __attribute__((ext_vector_type(8))) unsigned short us8;
typedef __attribute__((ext_vector_type(4))) float f32x4;

__device__ __forceinline__ float asf(unsigned u) { return __uint_as_float(u); }
// round-to-nearest-even fp32 -> bf16 (returns low 16 bits)
__device__ __forceinline__ unsigned bfr(float x) {
  unsigned u = __float_as_uint(x);
  return (u + 0x7FFFu + ((u >> 16) & 1u)) >> 16;
}

// ---------------- histograms / CSR build ----------------

__global__ void hist_edges(const int* __restrict__ dst, int* __restrict__ deg) {
  int e = blockIdx.x * 256 + threadIdx.x;
  if (e < E) atomicAdd(&deg[dst[e]], 1);
}

__global__ void hist_nodes(const int* __restrict__ b0, const int* __restrict__ a0l,
                           int* __restrict__ cnt1, int* __restrict__ assign0) {
  __shared__ int lh[TF];
  int t = threadIdx.x;
  for (int j = t; j < TF; j += 256) lh[j] = 0;
  __syncthreads();
  int i = blockIdx.x * 256 + t;
  if (i < N) {
    int g = b0[i];
    int a = g * F + a0l[i];
    assign0[i] = a;
    atomicAdd(&lh[a], 1);
  }
  __syncthreads();
  for (int j = t; j < TF; j += 256) {
    int c = lh[j];
    if (c) atomicAdd(&cnt1[j], c);
  }
}

__global__ void scan1(const int* __restrict__ cnt, int* __restrict__ offs,
                      int* __restrict__ part) {
  __shared__ int lds[256];
  int t = threadIdx.x;
  int base = blockIdx.x * 1024 + t * 4;
  int v[4];
#pragma unroll
  for (int j = 0; j < 4; ++j) v[j] = (base + j < N) ? cnt[base + j] : 0;
  int s = v[0] + v[1] + v[2] + v[3];
  lds[t] = s;
  __syncthreads();
  for (int off = 1; off < 256; off <<= 1) {
    int x = (t >= off) ? lds[t - off] : 0;
    __syncthreads();
    lds[t] += x;
    __syncthreads();
  }
  int ex = lds[t] - s;
  if (t == 255) part[blockIdx.x] = lds[255];
  int run = ex;
#pragma unroll
  for (int j = 0; j < 4; ++j) {
    if (base + j < N) offs[base + j] = run;
    run += v[j];
  }
}

__global__ void scan2(const int* __restrict__ part, int* __restrict__ partEx, int nb) {
  __shared__ int lds[128];
  int t = threadIdx.x;
  int s = (t < nb) ? part[t] : 0;
  lds[t] = s;
  __syncthreads();
  for (int off = 1; off < 128; off <<= 1) {
    int x = (t >= off) ? lds[t - off] : 0;
    __syncthreads();
    lds[t] += x;
    __syncthreads();
  }
  partEx[t] = lds[t] - s;
}

__global__ void scan3(int* __restrict__ offs, const int* __restrict__ partEx,
                      const int* __restrict__ deg, float* __restrict__ rdeg,
                      const int* __restrict__ cnt1, float* __restrict__ rdeg1,
                      float* __restrict__ rdegB) {
  int i = blockIdx.x * 256 + threadIdx.x;
  if (i < N) {
    offs[i] += partEx[i >> 10];
    rdeg[i] = 1.0f / fmaxf((float)deg[i], 1.0f);
    if (i == 0) offs[N] = E;
    if (i < TF) rdeg1[i] = 1.0f / fmaxf((float)cnt1[i], 1.0f);
    if (i < B) {
      int s = 0;
      for (int f = 0; f < F; ++f) s += cnt1[i * F + f];
      rdegB[i] = 1.0f / fmaxf((float)s, 1.0f);
    }
  }
}

__global__ void scatter_k(const int* __restrict__ src, const int* __restrict__ dst,
                          const int* __restrict__ offs, int* __restrict__ cursor,
                          int* __restrict__ srcS) {
  int e = blockIdx.x * 256 + threadIdx.x;
  if (e < E) {
    int d = dst[e];
    int pos = offs[d] + atomicAdd(&cursor[d], 1);
    srcS[pos] = src[e];
  }
}

// ---- weight conversion: fp32 [k][c] -> split-bf16, slice-major, col-permuted ----
// per H*H matrix (32768 shorts): hi [ks][c_s][32] at 0, lo at +16384.
// storage slot c_s = (c&7)*16 + (c>>3) holds output column c -> epilogue
// fragment (nf,lm) covers cols lm*8+nf (lane-contiguous).
struct WPtrs { const float* w[19]; };
__global__ void conv_w(WPtrs wp, unsigned short* __restrict__ wt) {
  int i = blockIdx.x >> 6;                         // matrix index
  int e = (blockIdx.x & 63) * 256 + threadIdx.x;   // 0..16383
  int k = e >> 7, c = e & 127;
  float x = wp.w[i][e];
  unsigned h = bfr(x);
  unsigned l = bfr(x - asf(h << 16));
  int cs = (c & 7) * 16 + (c >> 3);
  size_t o = (size_t)i * 32768 + (k >> 5) * 4096 + cs * 32 + (k & 31);
  wt[o] = (unsigned short)h;
  wt[o + 16384] = (unsigned short)l;
}

// Wp: fp32 [64][128] -> hi (2 slices * 4096) + lo at +8192
__global__ void conv_wp(const float* __restrict__ w, unsigned short* __restrict__ wt) {
  int e = blockIdx.x * 256 + threadIdx.x;  // 0..8191
  int k = e >> 7, c = e & 127;
  float x = w[e];
  unsigned h = bfr(x);
  unsigned l = bfr(x - asf(h << 16));
  int cs = (c & 7) * 16 + (c >> 3);
  size_t o = (size_t)(k >> 5) * 4096 + cs * 32 + (k & 31);
  wt[o] = (unsigned short)h;
  wt[o + 8192] = (unsigned short)l;
}

// x0 fp32 [N][64] -> interleaved rows [hi64 | lo64] (stride 128 shorts)
__global__ void x0split(const float* __restrict__ x0, unsigned short* __restrict__ xs) {
  int i = blockIdx.x * 256 + threadIdx.x;  // elem index
  if (i >= N * D0) return;
  int row = i >> 6, c = i & 63;
  float x = x0[i];
  unsigned h = bfr(x);
  unsigned l = bfr(x - asf(h << 16));
  xs[(size_t)row * 128 + c] = (unsigned short)h;
  xs[(size_t)row * 128 + 64 + c] = (unsigned short)l;
}

// ---------------- edge aggregation (interleaved hi|lo rows, 512B) ----------------
__global__ void agg_k(const unsigned short* __restrict__ Act,
                      const int* __restrict__ offs, const int* __restrict__ srcS,
                      const float* __restrict__ rdeg, unsigned short* __restrict__ Out) {
  int wid = blockIdx.x * 4 + (threadIdx.x >> 6);
  int lane = threadIdx.x & 63;
  if (wid >= N) return;
  int o0 = offs[wid], o1 = offs[wid + 1];
  float s0 = 0.f, s1 = 0.f, s2 = 0.f, s3 = 0.f;
  int e = o0;
  for (; e + 3 < o1; e += 4) {
    uint2 v0 = *(const uint2*)(Act + (size_t)srcS[e] * 256 + lane * 4);
    uint2 v1 = *(const uint2*)(Act + (size_t)srcS[e + 1] * 256 + lane * 4);
    uint2 v2 = *(const uint2*)(Act + (size_t)srcS[e + 2] * 256 + lane * 4);
    uint2 v3 = *(const uint2*)(Act + (size_t)srcS[e + 3] * 256 + lane * 4);
    s0 += asf(v0.x << 16) + asf(v1.x << 16) + asf(v2.x << 16) + asf(v3.x << 16);
    s1 += asf(v0.x & 0xFFFF0000u) + asf(v1.x & 0xFFFF0000u) +
          asf(v2.x & 0xFFFF0000u) + asf(v3.x & 0xFFFF0000u);
    s2 += asf(v0.y << 16) + asf(v1.y << 16) + asf(v2.y << 16) + asf(v3.y << 16);
    s3 += asf(v0.y & 0xFFFF0000u) + asf(v1.y & 0xFFFF0000u) +
          asf(v2.y & 0xFFFF0000u) + asf(v3.y & 0xFFFF0000u);
  }
  for (; e < o1; ++e) {
    uint2 v0 = *(const uint2*)(Act + (size_t)srcS[e] * 256 + lane * 4);
    s0 += asf(v0.x << 16);
    s1 += asf(v0.x & 0xFFFF0000u);
    s2 += asf(v0.y << 16);
    s3 += asf(v0.y & 0xFFFF0000u);
  }
  float sc = rdeg[wid];
  float v0 = (s0 + __shfl_xor(s0, 32)) * sc;
  float v1 = (s1 + __shfl_xor(s1, 32)) * sc;
  float v2 = (s2 + __shfl_xor(s2, 32)) * sc;
  float v3 = (s3 + __shfl_xor(s3, 32)) * sc;
  unsigned h0 = bfr(v0), h1 = bfr(v1), h2 = bfr(v2), h3 = bfr(v3);
  unsigned w0, w1;
  if (lane < 32) {
    w0 = h0 | (h1 << 16);
    w1 = h2 | (h3 << 16);
  } else {
    unsigned l0 = bfr(v0 - asf(h0 << 16)), l1 = bfr(v1 - asf(h1 << 16));
    unsigned l2 = bfr(v2 - asf(h2 << 16)), l3 = bfr(v3 - asf(h3 << 16));
    w0 = l0 | (l1 << 16);
    w1 = l2 | (l3 << 16);
  }
  unsigned short* po = Out + (size_t)wid * 256 + (lane & 31) * 4 + (lane >= 32 ? 128 : 0);
  *(uint2*)po = make_uint2(w0, w1);
}

// ---------------- split-bf16 MFMA GEMM, LDS-staged weights (N-row layers) ----------------
template <int KD, bool AGG, bool GATH>
__global__ __launch_bounds__(256, 3)
void mgemm(const unsigned short* __restrict__ Ai, const unsigned short* __restrict__ W1,
           const unsigned short* __restrict__ Bi, const unsigned short* __restrict__ W2,
           const float* __restrict__ Gt, const int* __restrict__ Gidx,
           const float* __restrict__ bias, unsigned short* __restrict__ Oi, int n) {
  __shared__ unsigned short wlds[2][2][4096];  // [buf][hi/lo][slice]
  constexpr int KS = KD / 32;
  constexpr int NS = (AGG ? 2 : 1) * KS;
  constexpr int KLO = KD * 128;
  constexpr int ARS = 2 * KD;
  const int t = threadIdx.x, wv = t >> 6, ln = t & 63;
  const int row0 = blockIdx.x * 128 + wv * 32;
  const int lm = ln & 15, kg = ln >> 4;
  int ar0 = row0 + lm, ar1 = row0 + 16 + lm;
  if (ar0 >= n) ar0 = 0;
  if (ar1 >= n) ar1 = 0;
  const size_t a0off = (size_t)ar0 * ARS, a1off = (size_t)ar1 * ARS;

  f32x4 acc[2][8];
#pragma unroll
  for (int i = 0; i < 2; ++i)
#pragma unroll
    for (int j = 0; j < 8; ++j) acc[i][j] = (f32x4){0.f, 0.f, 0.f, 0.f};

  uint4 sA, sB, sC, sD;
  bf16x8 a0h[2], a0l[2], a1h[2], a1l[2];

  auto ldst = [&](int s) {
    const unsigned short* W = (AGG && s >= KS) ? W2 : W1;
    const unsigned short* ph = W + (s & (KS - 1)) * 4096;
    sA = *(const uint4*)(ph + t * 8);
    sB = *(const uint4*)(ph + 2048 + t * 8);
    sC = *(const uint4*)(ph + KLO + t * 8);
    sD = *(const uint4*)(ph + KLO + 2048 + t * 8);
  };
  auto wrst = [&](int buf) {
    *(uint4*)&wlds[buf][0][t * 8] = sA;
    *(uint4*)&wlds[buf][0][2048 + t * 8] = sB;
    *(uint4*)&wlds[buf][1][t * 8] = sC;
    *(uint4*)&wlds[buf][1][2048 + t * 8] = sD;
  };
  auto loadA = [&](int s, int w) {
    const unsigned short* X = (AGG && s >= KS) ? Bi : Ai;
    int kk = (s & (KS - 1)) * 32 + kg * 8;
    a0h[w] = *(const bf16x8*)(X + a0off + kk);
    a0l[w] = *(const bf16x8*)(X + a0off + KD + kk);
    a1h[w] = *(const bf16x8*)(X + a1off + kk);
    a1l[w] = *(const bf16x8*)(X + a1off + KD + kk);
  };

  ldst(0); wrst(0); loadA(0, 0);
  __syncthreads();

#pragma unroll
  for (int s = 0; s < NS; ++s) {
    const int buf = s & 1;
    if (s + 1 < NS) { ldst(s + 1); loadA(s + 1, buf ^ 1); }
#pragma unroll
    for (int nf = 0; nf < 8; ++nf) {
      const int wo = (nf * 16 + lm) * 32 + kg * 8;
      bf16x8 wh = *(const bf16x8*)&wlds[buf][0][wo];
      bf16x8 wl = *(const bf16x8*)&wlds[buf][1][wo];
      acc[0][nf] = __builtin_amdgcn_mfma_f32_16x16x32_bf16(a0h[buf], wh, acc[0][nf], 0, 0, 0);
      acc[0][nf] = __builtin_amdgcn_mfma_f32_16x16x32_bf16(a0h[buf], wl, acc[0][nf], 0, 0, 0);
      acc[0][nf] = __builtin_amdgcn_mfma_f32_16x16x32_bf16(a0l[buf], wh, acc[0][nf], 0, 0, 0);
      acc[1][nf] = __builtin_amdgcn_mfma_f32_16x16x32_bf16(a1h[buf], wh, acc[1][nf], 0, 0, 0);
      acc[1][nf] = __builtin_amdgcn_mfma_f32_16x16x32_bf16(a1h[buf], wl, acc[1][nf], 0, 0, 0);
      acc[1][nf] = __builtin_amdgcn_mfma_f32_16x16x32_bf16(a1l[buf], wh, acc[1][nf], 0, 0, 0);
    }
    if (s + 1 < NS) wrst(buf ^ 1);
    __syncthreads();
  }

  float4 bq0 = *(const float4*)&bias[lm * 8];
  float4 bq1 = *(const float4*)&bias[lm * 8 + 4];
  float bsv[8] = {bq0.x, bq0.y, bq0.z, bq0.w, bq1.x, bq1.y, bq1.z, bq1.w};
#pragma unroll
  for (int mf = 0; mf < 2; ++mf)
#pragma unroll
    for (int rr = 0; rr < 4; ++rr) {
      int row = row0 + mf * 16 + kg * 4 + rr;
      if (row >= n) continue;
      float gvv[8];
      if (GATH) {
        const float* grow = Gt + (size_t)Gidx[row] * H + lm * 8;
        float4 g0 = *(const float4*)grow;
        float4 g1 = *(const float4*)(grow + 4);
        gvv[0] = g0.x; gvv[1] = g0.y; gvv[2] = g0.z; gvv[3] = g0.w;
        gvv[4] = g1.x; gvv[5] = g1.y; gvv[6] = g1.z; gvv[7] = g1.w;
      }
      us8 hv, lv;
#pragma unroll
      for (int nf = 0; nf < 8; ++nf) {
        float v = acc[mf][nf][rr] + bsv[nf];
        if (GATH) v += gvv[nf];
        v = fmaxf(v, 0.f);
        unsigned h = bfr(v);
        hv[nf] = (unsigned short)h;
        lv[nf] = (unsigned short)bfr(v - asf(h << 16));
      }
      *(us8*)(Oi + (size_t)row * 256 + lm * 8) = hv;
      *(us8*)(Oi + (size_t)row * 256 + 128 + lm * 8) = lv;
    }
}

// ---------------- fused small-scale chain, MFMA + half-matrix pipeline ----------------
// 10 stages (5 matrices x 2 half-matrices of 32KB), double-buffered wl[2].
// Half-matrix = 16384 shorts = 2048 uint4 = 8 uint4/thread (R11 bug: moved
// only 4/thread -> lo plane of wl never written -> absmax 1.6e-4).
// Pipeline per stage s: issue loads for s+2 -> MFMA on s -> write s+1 -> barrier.
template <int MF, bool ISH1>
__global__ __launch_bounds__(256)
void fused_chain(const unsigned short* __restrict__ Ai,
                 const float* __restrict__ P, const float* __restrict__ pscale,
                 const float* __restrict__ Gt,
                 const unsigned short* __restrict__ Wd,
                 const unsigned short* __restrict__ Wa,
                 const unsigned short* __restrict__ Wu,
                 const unsigned short* __restrict__ We0,
                 const unsigned short* __restrict__ We1,
                 const float* __restrict__ bn, const float* __restrict__ be0,
                 const float* __restrict__ be1,
                 float* __restrict__ outD, unsigned short* __restrict__ Ao,
                 float* __restrict__ outF, int n) {
  __shared__ unsigned short act[MF * 64 * 256];  // MF=2: 64KB, MF=1: 32KB
  __shared__ unsigned short wl[2][16384];        // 2 x 32KB halves (hi|lo)
  const int t = threadIdx.x, wv = t >> 6, ln = t & 63;
  const int lm = ln & 15, kg = ln >> 4;
  const int rbase = blockIdx.x * (MF * 64) + wv * (MF * 16);
  const int lbase = wv * (MF * 16);
  int arr[MF];
#pragma unroll
  for (int mf = 0; mf < MF; ++mf) {
    int a = rbase + mf * 16 + lm;
    arr[mf] = (a < n) ? a : 0;
  }

  const unsigned short* mats[5] = {Wd, Wa, Wu, We0, We1};

  f32x4 acc[MF][8];
  auto zacc = [&]() {
#pragma unroll
    for (int mf = 0; mf < MF; ++mf)
#pragma unroll
      for (int nf = 0; nf < 8; ++nf) acc[mf][nf] = (f32x4){0.f, 0.f, 0.f, 0.f};
  };

  uint4 bufA[8], bufB[8];
  // half s: hi = matrix shorts [(s&1)*8192, +8192), lo = [16384+(s&1)*8192, +8192)
  // 16384 shorts total = 2048 uint4 = 8 uint4/thread.
  auto ldhalf = [&](int s, uint4* buf) {
    const unsigned short* m = mats[s >> 1];
    const uint4* hi = (const uint4*)(m + (s & 1) * 8192);
    const uint4* lo = (const uint4*)(m + 16384 + (s & 1) * 8192);
#pragma unroll
    for (int j = 0; j < 4; ++j) buf[j] = hi[t + j * 256];
#pragma unroll
    for (int j = 0; j < 4; ++j) buf[4 + j] = lo[t + j * 256];
  };
  auto wrhalf = [&](int b, const uint4* buf) {
    uint4* d = (uint4*)wl[b];
#pragma unroll
    for (int j = 0; j < 4; ++j) d[t + j * 256] = buf[j];          // hi: shorts [0,8192)
#pragma unroll
    for (int j = 0; j < 4; ++j) d[t + 1024 + j * 256] = buf[4 + j];  // lo: [8192,16384)
  };

  auto donf = [&](int b, int ksl, const bf16x8* ah, const bf16x8* al) {
#pragma unroll
    for (int nf = 0; nf < 8; ++nf) {
      const int wo = ksl * 4096 + (nf * 16 + lm) * 32 + kg * 8;
      bf16x8 wh = *(const bf16x8*)&wl[b][wo];
      bf16x8 wq = *(const bf16x8*)&wl[b][8192 + wo];
#pragma unroll
      for (int mf = 0; mf < MF; ++mf) {
        acc[mf][nf] = __builtin_amdgcn_mfma_f32_16x16x32_bf16(ah[mf], wh, acc[mf][nf], 0, 0, 0);
        acc[mf][nf] = __builtin_amdgcn_mfma_f32_16x16x32_bf16(ah[mf], wq, acc[mf][nf], 0, 0, 0);
        acc[mf][nf] = __builtin_amdgcn_mfma_f32_16x16x32_bf16(al[mf], wh, acc[mf][nf], 0, 0, 0);
      }
    }
  };

  auto epiAct = [&](const float* bias, bool gath) {
    float4 b0 = *(const float4*)&bias[lm * 8];
    float4 b1 = *(const float4*)&bias[lm * 8 + 4];
    float bv[8] = {b0.x, b0.y, b0.z, b0.w, b1.x, b1.y, b1.z, b1.w};
#pragma unroll
    for (int mf = 0; mf < MF; ++mf)
#pragma unroll
      for (int rr = 0; rr < 4; ++rr) {
        int rl = lbase + mf * 16 + kg * 4 + rr;
        int rg = rbase + mf * 16 + kg * 4 + rr;
        float gv[8] = {0.f, 0.f, 0.f, 0.f, 0.f, 0.f, 0.f, 0.f};
        if (ISH1 && gath && rg < n) {
          const float* grow = Gt + (size_t)(rg / F) * H + lm * 8;
          float4 g0 = *(const float4*)grow;
          float4 g1 = *(const float4*)(grow + 4);
          gv[0] = g0.x; gv[1] = g0.y; gv[2] = g0.z; gv[3] = g0.w;
          gv[4] = g1.x; gv[5] = g1.y; gv[6] = g1.z; gv[7] = g1.w;
        }
        us8 hv, lv;
#pragma unroll
        for (int nf = 0; nf < 8; ++nf) {
          float v = acc[mf][nf][rr] + bv[nf] + gv[nf];
          v = fmaxf(v, 0.f);
          unsigned h = bfr(v);
          hv[nf] = (unsigned short)h;
          lv[nf] = (unsigned short)bfr(v - asf(h << 16));
        }
        *(us8*)&act[rl * 256 + lm * 8] = hv;
        *(us8*)&act[rl * 256 + 128 + lm * 8] = lv;
      }
  };

  // ---- pipeline prologue ----
  ldhalf(0, bufA);
  wrhalf(0, bufA);
  __syncthreads();           // one exposed drain (stage-0 half)
  ldhalf(1, bufA);           // stage-1 loads in flight across stage-0 MFMA

#pragma unroll
  for (int s = 0; s < 10; ++s) {
    const int b = s & 1;
    if (s + 2 < 10) ldhalf(s + 2, (s & 1) ? bufA : bufB);  // early issue
    if (s == 0 || s == 2 || s == 6 || s == 8) zacc();
    const int m = s >> 1;
#pragma unroll
    for (int ksl = 0; ksl < 2; ++ksl) {
      const int ks = (s & 1) * 2 + ksl;
      bf16x8 ah[MF], al[MF];
      if (m <= 1) {           // Wd / Wa pass: A from global interleaved Ai
#pragma unroll
        for (int mf = 0; mf < MF; ++mf) {
          const unsigned short* ap = Ai + (size_t)arr[mf] * 256 + ks * 32 + kg * 8;
          ah[mf] = *(const bf16x8*)ap;
          al[mf] = *(const bf16x8*)(ap + 128);
        }
      } else if (m == 2) {    // Wu pass: A from fp32 P (optionally scaled)
#pragma unroll
        for (int mf = 0; mf < MF; ++mf) {
          const float* pp = P + (size_t)arr[mf] * H + ks * 32 + kg * 8;
          float4 f0 = *(const float4*)pp;
          float4 f1 = *(const float4*)(pp + 4);
          if (ISH1) {
            float sc = pscale[arr[mf]];
            f0.x *= sc; f0.y *= sc; f0.z *= sc; f0.w *= sc;
            f1.x *= sc; f1.y *= sc; f1.z *= sc; f1.w *= sc;
          }
          float fv[8] = {f0.x, f0.y, f0.z, f0.w, f1.x, f1.y, f1.z, f1.w};
          us8 h8, l8;
#pragma unroll
          for (int j = 0; j < 8; ++j) {
            unsigned h = bfr(fv[j]);
            h8[j] = (unsigned short)h;
            l8[j] = (unsigned short)bfr(fv[j] - asf(h << 16));
          }
          ah[mf] = __builtin_bit_cast(bf16x8, h8);
          al[mf] = __builtin_bit_cast(bf16x8, l8);
        }
      } else {                // We0 / We1 pass: A from LDS act (own rows)
#pragma unroll
        for (int mf = 0; mf < MF; ++mf) {
          int rl = lbase + mf * 16 + lm;
          ah[mf] = *(const bf16x8*)&act[rl * 256 + ks * 32 + kg * 8];
          al[mf] = *(const bf16x8*)&act[rl * 256 + 128 + ks * 32 + kg * 8];
        }
      }
      donf(b, ksl, ah, al);
    }
    // ---- epilogues (acc-only; act rows are wave-private) ----
    if (s == 1) {
#pragma unroll
      for (int mf = 0; mf < MF; ++mf)
#pragma unroll
        for (int rr = 0; rr < 4; ++rr) {
          int rg = rbase + mf * 16 + kg * 4 + rr;
          if (rg < n) {
            float* op = outD + (size_t)rg * H + lm * 8;
            *(float4*)op = make_float4(acc[mf][0][rr], acc[mf][1][rr], acc[mf][2][rr], acc[mf][3][rr]);
            *(float4*)(op + 4) = make_float4(acc[mf][4][rr], acc[mf][5][rr], acc[mf][6][rr], acc[mf][7][rr]);
          }
        }
    }
    if (s == 5) epiAct(bn, true);
    if (s == 7) epiAct(be0, false);
    if (s == 9) {
      float4 b0 = *(const float4*)&be1[lm * 8];
      float4 b1 = *(const float4*)&be1[lm * 8 + 4];
      float bv[8] = {b0.x, b0.y, b0.z, b0.w, b1.x, b1.y, b1.z, b1.w};
#pragma unroll
      for (int mf = 0; mf < MF; ++mf)
#pragma unroll
        for (int rr = 0; rr < 4; ++rr) {
          int rg = rbase + mf * 16 + kg * 4 + rr;
          if (rg >= n) continue;
          us8 hv, lv;
          float fv[8];
#pragma unroll
          for (int nf = 0; nf < 8; ++nf) {
            float v = fmaxf(acc[mf][nf][rr] + bv[nf], 0.f);
            fv[nf] = v;
            unsigned h = bfr(v);
            hv[nf] = (unsigned short)h;
            lv[nf] = (unsigned short)bfr(v - asf(h << 16));
          }
          *(us8*)(Ao + (size_t)rg * 256 + lm * 8) = hv;
          *(us8*)(Ao + (size_t)rg * 256 + 128 + lm * 8) = lv;
          if (outF) {
            float* op = outF + (size_t)rg * H + lm * 8;
            *(float4*)op = make_float4(fv[0], fv[1], fv[2], fv[3]);
            *(float4*)(op + 4) = make_float4(fv[4], fv[5], fv[6], fv[7]);
          }
        }
    }
    if (s + 1 < 10) {
      wrhalf(b ^ 1, (s & 1) ? bufB : bufA);  // s+1 data (landed during MFMA)
      __syncthreads();
    }
  }
}

// ---------------- initial h1/h2: enc-plain on zeros => identical rows ----------------
__global__ void init_bcast(const float* __restrict__ Ws1, const float* __restrict__ b1,
                           const float* __restrict__ Ws2, const float* __restrict__ b2,
                           unsigned short* __restrict__ h1i, unsigned short* __restrict__ h2i) {
  __shared__ float z0[128];
  int t = threadIdx.x;  // 128
  bool ish2 = (blockIdx.x == 20);
  const float* W = ish2 ? Ws2 : Ws1;
  const float* bb = ish2 ? b2 : b1;
  z0[t] = fmaxf(bb[t], 0.f);
  __syncthreads();
  float s = bb[128 + t];
  for (int k = 0; k < 128; ++k) s += z0[k] * W[16384 + k * 128 + t];
  s = fmaxf(s, 0.f);
  unsigned h = bfr(s);
  unsigned l = bfr(s - asf(h << 16));
  if (ish2) {
    for (int r = 0; r < B; ++r) {
      h2i[(size_t)r * 256 + t] = (unsigned short)h;
      h2i[(size_t)r * 256 + 128 + t] = (unsigned short)l;
    }
  } else {
    int r0 = blockIdx.x * 100;
    for (int r = 0; r < 100; ++r) {
      h1i[(size_t)(r0 + r) * 256 + t] = (unsigned short)h;
      h1i[(size_t)(r0 + r) * 256 + 128 + t] = (unsigned short)l;
    }
  }
}

// ---------------- pooling (interleaved rows) ----------------
__global__ void pool_p01(const unsigned short* __restrict__ Act,
                         const int* __restrict__ a0l, const int* __restrict__ b0,
                         float* __restrict__ p01s) {
  __shared__ float acc[F][H];
  int t = threadIdx.x;  // 128
#pragma unroll
  for (int f = 0; f < F; ++f) acc[f][t] = 0.f;
  int rowbase = blockIdx.x * 250;
  for (int i = 0; i < 250; ++i) {
    size_t r = (size_t)(rowbase + i) * 256 + t;
    acc[a0l[rowbase + i]][t] += asf((unsigned)Act[r] << 16) + asf((unsigned)Act[r + 128] << 16);
  }
  int g = b0[rowbase];
#pragma unroll
  for (int f = 0; f < F; ++f)
    atomicAdd(&p01s[((size_t)(g * F + f)) * H + t], acc[f][t]);
}

__global__ void pool_g0(const unsigned short* __restrict__ Act,
                        const int* __restrict__ b0, float* __restrict__ g0s) {
  int t = threadIdx.x;
  int rowbase = blockIdx.x * 250;
  float a = 0.f;
  for (int i = 0; i < 250; ++i) {
    size_t r = (size_t)(rowbase + i) * 256 + t;
    a += asf((unsigned)Act[r] << 16) + asf((unsigned)Act[r + 128] << 16);
  }
  atomicAdd(&g0s[(size_t)b0[rowbase] * H + t], a);
}

// mean over F contiguous interleaved-bf16 rows per graph -> fp32
__global__ void mean40i(const unsigned short* __restrict__ Act, float* __restrict__ outp) {
  int t = threadIdx.x, g = blockIdx.x;
  float a = 0.f;
  for (int i = 0; i < F; ++i) {
    size_t r = (size_t)(g * F + i) * 256 + t;
    a += asf((unsigned)Act[r] << 16) + asf((unsigned)Act[r + 128] << 16);
  }
  outp[(size_t)g * H + t] = a * (1.0f / F);
}

// ---------------- head MLP ----------------
__global__ void head_k(const float* __restrict__ g0s, const float* __restrict__ rdegB,
                       const float* __restrict__ g1, const float* __restrict__ h2,
                       const float* __restrict__ W1h, const float* __restrict__ b1h,
                       const float* __restrict__ W2h, const float* __restrict__ b2h,
                       float* __restrict__ out) {
  __shared__ float gv[3 * H];
  __shared__ float z[H];
  int b = blockIdx.x, t = threadIdx.x;
  gv[t] = g0s[(size_t)b * H + t] * rdegB[b];
  gv[H + t] = g1[(size_t)b * H + t];
  gv[2 * H + t] = h2[(size_t)b * H + t];
  __syncthreads();
  float s = b1h[t];
  for (int k = 0; k < 3 * H; ++k) s += gv[k] * W1h[k * H + t];
  z[t] = fmaxf(s, 0.f);
  __syncthreads();
  if (t < C) {
    float o = b2h[t];
    for (int k = 0; k < H; ++k) o += z[k] * W2h[k * C + t];
    out[b * C + t] = o;
  }
}

}  // namespace

extern "C" void kernel_launch(void* const* d_in, const int* in_sizes, int n_in,
                              void* d_out, int out_size, void* d_ws, size_t ws_size,
                              hipStream_t stream) {
  (void)in_sizes; (void)n_in; (void)out_size; (void)ws_size;
  const float* x0   = (const float*)d_in[0];
  const int*   ei   = (const int*)d_in[1];
  const int*   src  = ei;
  const int*   dst  = ei + E;
  const int*   b0   = (const int*)d_in[2];
  const int*   a0l  = (const int*)d_in[3];
  const float* Wp   = (const float*)d_in[4];
  const float* bp   = (const float*)d_in[5];
  const float* e0in_Ws = (const float*)d_in[6];
  const float* e0in_Wn = (const float*)d_in[7];
  const float* e0in_b  = (const float*)d_in[8];
  const float* enc0_Ws = (const float*)d_in[9];
  const float* enc0_Wn = (const float*)d_in[10];
  const float* enc0_b  = (const float*)d_in[11];
  const float* e1in_Ws = (const float*)d_in[12];
  const float* e1in_b  = (const float*)d_in[13];
  const float* e2in_Ws = (const float*)d_in[14];
  const float* e2in_b  = (const float*)d_in[15];
  const float* enc1_Ws = (const float*)d_in[16];
  const float* enc1_b  = (const float*)d_in[17];
  const float* enc2_Ws = (const float*)d_in[18];
  const float* enc2_b  = (const float*)d_in[19];
  const float* A0 = (const float*)d_in[20];
  const float* A1 = (const float*)d_in[21];
  const float* A2 = (const float*)d_in[22];
  const float* U0 = (const float*)d_in[23];
  const float* U1 = (const float*)d_in[24];
  const float* D1 = (const float*)d_in[25];
  const float* D2 = (const float*)d_in[26];
  const float* ib0 = (const float*)d_in[27];
  const float* ib1 = (const float*)d_in[28];
  const float* ib2 = (const float*)d_in[29];
  const float* H1w = (const float*)d_in[30];
  const float* hb1 = (const float*)d_in[31];
  const float* H2w = (const float*)d_in[32];
  const float* hb2 = (const float*)d_in[33];
  float* out = (float*)d_out;

  // ---- workspace carve ----
  char* p = (char*)d_ws;
  auto carve = [&](size_t bytes) {
    char* r = p;
    p += (bytes + 255) & ~(size_t)255;
    return r;
  };
  char* z0 = p;  // zeroed-every-call region
  int*   deg    = (int*)carve((size_t)N * 4);
  int*   cursor = (int*)carve((size_t)N * 4);
  int*   cnt1   = (int*)carve((size_t)TF * 4);
  float* g0s    = (float*)carve((size_t)B * H * 4);
  size_t zbytes = (size_t)(p - z0);
  unsigned short* h0i  = (unsigned short*)carve((size_t)N * 256 * 2);
  unsigned short* aggi = (unsigned short*)carve((size_t)N * 256 * 2);
  unsigned short* h1a  = (unsigned short*)carve((size_t)TF * 256 * 2);
  unsigned short* h2ai = (unsigned short*)carve((size_t)64 * 256 * 2);
  float* h1d  = (float*)carve((size_t)TF * H * 4);
  float* h2d  = (float*)carve((size_t)64 * H * 4);
  float* h2f  = (float*)carve((size_t)B * H * 4);
  float* p01s = (float*)carve((size_t)TF * H * 4);
  float* p12  = (float*)carve((size_t)B * H * 4);
  float* g1   = (float*)carve((size_t)B * H * 4);
  float* rdeg = (float*)carve((size_t)N * 4);
  float* rdeg1 = (float*)carve((size_t)TF * 4);
  float* rdegB = (float*)carve(64 * 4);
  int* offs    = (int*)carve((size_t)(N + 64) * 4);
  int* srcS    = (int*)carve((size_t)E * 4);
  int* part    = (int*)carve(128 * 4);
  int* partEx  = (int*)carve(128 * 4);
  int* assign0 = (int*)carve((size_t)N * 4);
  unsigned short* wt  = (unsigned short*)carve((size_t)19 * 32768 * 2);
  unsigned short* wt9 = (unsigned short*)carve((size_t)16384 * 2);
  unsigned short* xs  = aggi;  // alias: x0-split used only before first agg_k

  const int HH = H * H;
  const int MG = (N + 127) / 128;  // 782

  // ---- CSR + histograms + weight/x0 split ----
  hipMemsetAsync(z0, 0, zbytes, stream);
  hist_edges<<<(E + 255) / 256, 256, 0, stream>>>(dst, deg);
  hist_nodes<<<(N + 255) / 256, 256, 0, stream>>>(b0, a0l, cnt1, assign0);
  const int nb1 = (N + 1023) / 1024;
  scan1<<<nb1, 256, 0, stream>>>(deg, offs, part);
  scan2<<<1, 128, 0, stream>>>(part, partEx, nb1);
  scan3<<<(N + 255) / 256, 256, 0, stream>>>(offs, partEx, deg, rdeg, cnt1, rdeg1,
                                             rdegB);
  scatter_k<<<(E + 255) / 256, 256, 0, stream>>>(src, dst, offs, cursor, srcS);
  {
    WPtrs wp;
    wp.w[0] = e0in_Ws;      wp.w[1] = e0in_Ws + HH;
    wp.w[2] = e0in_Wn;      wp.w[3] = e0in_Wn + HH;
    wp.w[4] = enc0_Ws;      wp.w[5] = enc0_Ws + HH;
    wp.w[6] = enc0_Wn;      wp.w[7] = enc0_Wn + HH;
    wp.w[8] = A0;
    wp.w[9] = D1;           wp.w[10] = A1;
    wp.w[11] = U0;          wp.w[12] = enc1_Ws;   wp.w[13] = enc1_Ws + HH;
    wp.w[14] = D2;          wp.w[15] = A2;
    wp.w[16] = U1;          wp.w[17] = enc2_Ws;   wp.w[18] = enc2_Ws + HH;
    conv_w<<<19 * 64, 256, 0, stream>>>(wp, wt);
  }
  conv_wp<<<32, 256, 0, stream>>>(Wp, wt9);
  x0split<<<(N * D0 + 255) / 256, 256, 0, stream>>>(x0, xs);

  // ---- input projection (MFMA, K=64) ----
  mgemm<64, false, false><<<MG, 256, 0, stream>>>(
      xs, wt9, nullptr, nullptr, nullptr, nullptr, bp, h0i, N);

  auto encEdgeM = [&](int wsIdx, int wnIdx, const float* barr) {
    for (int l = 0; l < 2; ++l) {
      agg_k<<<N / 4, 256, 0, stream>>>(h0i, offs, srcS, rdeg, aggi);
      mgemm<128, true, false><<<MG, 256, 0, stream>>>(
          h0i, wt + (size_t)(wsIdx + l) * 32768, aggi,
          wt + (size_t)(wnIdx + l) * 32768, nullptr, nullptr, barr + l * H, h0i, N);
    }
  };

  encEdgeM(0, 2, e0in_b);
  init_bcast<<<21, 128, 0, stream>>>(e1in_Ws, e1in_b, e2in_Ws, e2in_b, h1a, h2ai);

  for (int step = 0; step < 2; ++step) {
    hipMemsetAsync(p01s, 0, (size_t)TF * H * 4, stream);
    pool_p01<<<400, 128, 0, stream>>>(h0i, a0l, b0, p01s);
    mean40i<<<B, 128, 0, stream>>>(h1a, p12);
    // h2 chain: D2 -> h2d; n2 = relu(h2@A2 + p12@U1 + ib2); enc2 x2 -> h2ai/h2f
    fused_chain<1, false><<<1, 256, 0, stream>>>(
        h2ai, p12, nullptr, nullptr,
        wt + (size_t)14 * 32768, wt + (size_t)15 * 32768, wt + (size_t)16 * 32768,
        wt + (size_t)17 * 32768, wt + (size_t)18 * 32768,
        ib2, enc2_b, enc2_b + H, h2d, h2ai, h2f, B);
    // h1 chain: D1 -> h1d; n1 = relu(h1@A1 + (p01s*rdeg1)@U0 + h2d[r/F] + ib1); enc1 x2
    fused_chain<2, true><<<(TF + 127) / 128, 256, 0, stream>>>(
        h1a, p01s, rdeg1, h2d,
        wt + (size_t)9 * 32768, wt + (size_t)10 * 32768, wt + (size_t)11 * 32768,
        wt + (size_t)12 * 32768, wt + (size_t)13 * 32768,
        ib1, enc1_b, enc1_b + H, h1d, h1a, nullptr, TF);
    // n0 = relu(h0@A0 + h1d[assign0] + ib0)   (in-place, MFMA)
    mgemm<128, false, true><<<MG, 256, 0, stream>>>(
        h0i, wt + (size_t)8 * 32768, nullptr, nullptr, h1d, assign0, ib0, h0i, N);
    encEdgeM(4, 6, enc0_b);
  }

  pool_g0<<<400, 128, 0, stream>>>(h0i, b0, g0s);
  mean40i<<<B, 128, 0, stream>>>(h1a, g1);
  head_k<<<B, 128, 0, stream>>>(g0s, rdegB, g1, h2f, H1w, hb1, H2w, hb2, out);
}

// Round 13
// 985.230 us; speedup vs baseline: 1.0418x; 1.0418x over previous
//
#include <hip/hip_runtime.h>

namespace {

constexpr int N   = 100000;
constexpr int E   = 600000;
constexpr int B   = 50;
constexpr int F   = 40;
constexpr int TF  = B * F;     // 2000
constexpr int D0  = 64;
constexpr int H   = 128;
constexpr int C   = 2;

typedef __attribute__((ext_vector_type(8))) __bf16 bf16x8;
typedef __attribute__((ext_vector_type(8))) unsigned short us8;
typedef __attribute__((ext_vector_type(4))) float f32x4;

__device__ __forceinline__ float asf(unsigned u) { return __uint_as_float(u); }
// round-to-nearest-even fp32 -> bf16 (returns low 16 bits)
__device__ __forceinline__ unsigned bfr(float x) {
  unsigned u = __float_as_uint(x);
  return (u + 0x7FFFu + ((u >> 16) & 1u)) >> 16;
}

// async global->LDS: 16B per lane, LDS dest = uniform base + lane*16,
// global src = per-lane address. Counts in vmcnt (drained by __syncthreads).
__device__ __forceinline__ void glds16(const void* g, void* l) {
  __builtin_amdgcn_global_load_lds(
      (const __attribute__((address_space(1))) unsigned*)g,
      (__attribute__((address_space(3))) unsigned*)l, 16, 0, 0);
}

// ---------------- histograms / CSR build ----------------

__global__ void hist_edges(const int* __restrict__ dst, int* __restrict__ deg) {
  int e = blockIdx.x * 256 + threadIdx.x;
  if (e < E) atomicAdd(&deg[dst[e]], 1);
}

__global__ void hist_nodes(const int* __restrict__ b0, const int* __restrict__ a0l,
                           int* __restrict__ cnt1, int* __restrict__ assign0) {
  __shared__ int lh[TF];
  int t = threadIdx.x;
  for (int j = t; j < TF; j += 256) lh[j] = 0;
  __syncthreads();
  int i = blockIdx.x * 256 + t;
  if (i < N) {
    int g = b0[i];
    int a = g * F + a0l[i];
    assign0[i] = a;
    atomicAdd(&lh[a], 1);
  }
  __syncthreads();
  for (int j = t; j < TF; j += 256) {
    int c = lh[j];
    if (c) atomicAdd(&cnt1[j], c);
  }
}

__global__ void scan1(const int* __restrict__ cnt, int* __restrict__ offs,
                      int* __restrict__ part) {
  __shared__ int lds[256];
  int t = threadIdx.x;
  int base = blockIdx.x * 1024 + t * 4;
  int v[4];
#pragma unroll
  for (int j = 0; j < 4; ++j) v[j] = (base + j < N) ? cnt[base + j] : 0;
  int s = v[0] + v[1] + v[2] + v[3];
  lds[t] = s;
  __syncthreads();
  for (int off = 1; off < 256; off <<= 1) {
    int x = (t >= off) ? lds[t - off] : 0;
    __syncthreads();
    lds[t] += x;
    __syncthreads();
  }
  int ex = lds[t] - s;
  if (t == 255) part[blockIdx.x] = lds[255];
  int run = ex;
#pragma unroll
  for (int j = 0; j < 4; ++j) {
    if (base + j < N) offs[base + j] = run;
    run += v[j];
  }
}

__global__ void scan2(const int* __restrict__ part, int* __restrict__ partEx, int nb) {
  __shared__ int lds[128];
  int t = threadIdx.x;
  int s = (t < nb) ? part[t] : 0;
  lds[t] = s;
  __syncthreads();
  for (int off = 1; off < 128; off <<= 1) {
    int x = (t >= off) ? lds[t - off] : 0;
    __syncthreads();
    lds[t] += x;
    __syncthreads();
  }
  partEx[t] = lds[t] - s;
}

__global__ void scan3(int* __restrict__ offs, const int* __restrict__ partEx,
                      const int* __restrict__ deg, float* __restrict__ rdeg,
                      const int* __restrict__ cnt1, float* __restrict__ rdeg1,
                      float* __restrict__ rdegB) {
  int i = blockIdx.x * 256 + threadIdx.x;
  if (i < N) {
    offs[i] += partEx[i >> 10];
    rdeg[i] = 1.0f / fmaxf((float)deg[i], 1.0f);
    if (i == 0) offs[N] = E;
    if (i < TF) rdeg1[i] = 1.0f / fmaxf((float)cnt1[i], 1.0f);
    if (i < B) {
      int s = 0;
      for (int f = 0; f < F; ++f) s += cnt1[i * F + f];
      rdegB[i] = 1.0f / fmaxf((float)s, 1.0f);
    }
  }
}

__global__ void scatter_k(const int* __restrict__ src, const int* __restrict__ dst,
                          const int* __restrict__ offs, int* __restrict__ cursor,
                          int* __restrict__ srcS) {
  int e = blockIdx.x * 256 + threadIdx.x;
  if (e < E) {
    int d = dst[e];
    int pos = offs[d] + atomicAdd(&cursor[d], 1);
    srcS[pos] = src[e];
  }
}

// ---- weight conversion: fp32 [k][c] -> split-bf16, slice-major, col-permuted ----
// per H*H matrix (32768 shorts): hi [ks][c_s][32] at 0, lo at +16384.
// storage slot c_s = (c&7)*16 + (c>>3) holds output column c -> epilogue
// fragment (nf,lm) covers cols lm*8+nf (lane-contiguous).
struct WPtrs { const float* w[19]; };
__global__ void conv_w(WPtrs wp, unsigned short* __restrict__ wt) {
  int i = blockIdx.x >> 6;                         // matrix index
  int e = (blockIdx.x & 63) * 256 + threadIdx.x;   // 0..16383
  int k = e >> 7, c = e & 127;
  float x = wp.w[i][e];
  unsigned h = bfr(x);
  unsigned l = bfr(x - asf(h << 16));
  int cs = (c & 7) * 16 + (c >> 3);
  size_t o = (size_t)i * 32768 + (k >> 5) * 4096 + cs * 32 + (k & 31);
  wt[o] = (unsigned short)h;
  wt[o + 16384] = (unsigned short)l;
}

// Wp: fp32 [64][128] -> hi (2 slices * 4096) + lo at +8192
__global__ void conv_wp(const float* __restrict__ w, unsigned short* __restrict__ wt) {
  int e = blockIdx.x * 256 + threadIdx.x;  // 0..8191
  int k = e >> 7, c = e & 127;
  float x = w[e];
  unsigned h = bfr(x);
  unsigned l = bfr(x - asf(h << 16));
  int cs = (c & 7) * 16 + (c >> 3);
  size_t o = (size_t)(k >> 5) * 4096 + cs * 32 + (k & 31);
  wt[o] = (unsigned short)h;
  wt[o + 8192] = (unsigned short)l;
}

// x0 fp32 [N][64] -> interleaved rows [hi64 | lo64] (stride 128 shorts)
__global__ void x0split(const float* __restrict__ x0, unsigned short* __restrict__ xs) {
  int i = blockIdx.x * 256 + threadIdx.x;  // elem index
  if (i >= N * D0) return;
  int row = i >> 6, c = i & 63;
  float x = x0[i];
  unsigned h = bfr(x);
  unsigned l = bfr(x - asf(h << 16));
  xs[(size_t)row * 128 + c] = (unsigned short)h;
  xs[(size_t)row * 128 + 64 + c] = (unsigned short)l;
}

// ---------------- edge aggregation (interleaved hi|lo rows, 512B) ----------------
__global__ void agg_k(const unsigned short* __restrict__ Act,
                      const int* __restrict__ offs, const int* __restrict__ srcS,
                      const float* __restrict__ rdeg, unsigned short* __restrict__ Out) {
  int wid = blockIdx.x * 4 + (threadIdx.x >> 6);
  int lane = threadIdx.x & 63;
  if (wid >= N) return;
  int o0 = offs[wid], o1 = offs[wid + 1];
  float s0 = 0.f, s1 = 0.f, s2 = 0.f, s3 = 0.f;
  int e = o0;
  for (; e + 3 < o1; e += 4) {
    uint2 v0 = *(const uint2*)(Act + (size_t)srcS[e] * 256 + lane * 4);
    uint2 v1 = *(const uint2*)(Act + (size_t)srcS[e + 1] * 256 + lane * 4);
    uint2 v2 = *(const uint2*)(Act + (size_t)srcS[e + 2] * 256 + lane * 4);
    uint2 v3 = *(const uint2*)(Act + (size_t)srcS[e + 3] * 256 + lane * 4);
    s0 += asf(v0.x << 16) + asf(v1.x << 16) + asf(v2.x << 16) + asf(v3.x << 16);
    s1 += asf(v0.x & 0xFFFF0000u) + asf(v1.x & 0xFFFF0000u) +
          asf(v2.x & 0xFFFF0000u) + asf(v3.x & 0xFFFF0000u);
    s2 += asf(v0.y << 16) + asf(v1.y << 16) + asf(v2.y << 16) + asf(v3.y << 16);
    s3 += asf(v0.y & 0xFFFF0000u) + asf(v1.y & 0xFFFF0000u) +
          asf(v2.y & 0xFFFF0000u) + asf(v3.y & 0xFFFF0000u);
  }
  for (; e < o1; ++e) {
    uint2 v0 = *(const uint2*)(Act + (size_t)srcS[e] * 256 + lane * 4);
    s0 += asf(v0.x << 16);
    s1 += asf(v0.x & 0xFFFF0000u);
    s2 += asf(v0.y << 16);
    s3 += asf(v0.y & 0xFFFF0000u);
  }
  float sc = rdeg[wid];
  float v0 = (s0 + __shfl_xor(s0, 32)) * sc;
  float v1 = (s1 + __shfl_xor(s1, 32)) * sc;
  float v2 = (s2 + __shfl_xor(s2, 32)) * sc;
  float v3 = (s3 + __shfl_xor(s3, 32)) * sc;
  unsigned h0 = bfr(v0), h1 = bfr(v1), h2 = bfr(v2), h3 = bfr(v3);
  unsigned w0, w1;
  if (lane < 32) {
    w0 = h0 | (h1 << 16);
    w1 = h2 | (h3 << 16);
  } else {
    unsigned l0 = bfr(v0 - asf(h0 << 16)), l1 = bfr(v1 - asf(h1 << 16));
    unsigned l2 = bfr(v2 - asf(h2 << 16)), l3 = bfr(v3 - asf(h3 << 16));
    w0 = l0 | (l1 << 16);
    w1 = l2 | (l3 << 16);
  }
  unsigned short* po = Out + (size_t)wid * 256 + (lane & 31) * 4 + (lane >= 32 ? 128 : 0);
  *(uint2*)po = make_uint2(w0, w1);
}

// ---------------- split-bf16 MFMA GEMM, LDS-staged weights (N-row layers) ----------------
template <int KD, bool AGG, bool GATH>
__global__ __launch_bounds__(256, 3)
void mgemm(const unsigned short* __restrict__ Ai, const unsigned short* __restrict__ W1,
           const unsigned short* __restrict__ Bi, const unsigned short* __restrict__ W2,
           const float* __restrict__ Gt, const int* __restrict__ Gidx,
           const float* __restrict__ bias, unsigned short* __restrict__ Oi, int n) {
  __shared__ unsigned short wlds[2][2][4096];  // [buf][hi/lo][slice]
  constexpr int KS = KD / 32;
  constexpr int NS = (AGG ? 2 : 1) * KS;
  constexpr int KLO = KD * 128;
  constexpr int ARS = 2 * KD;
  const int t = threadIdx.x, wv = t >> 6, ln = t & 63;
  const int row0 = blockIdx.x * 128 + wv * 32;
  const int lm = ln & 15, kg = ln >> 4;
  int ar0 = row0 + lm, ar1 = row0 + 16 + lm;
  if (ar0 >= n) ar0 = 0;
  if (ar1 >= n) ar1 = 0;
  const size_t a0off = (size_t)ar0 * ARS, a1off = (size_t)ar1 * ARS;

  f32x4 acc[2][8];
#pragma unroll
  for (int i = 0; i < 2; ++i)
#pragma unroll
    for (int j = 0; j < 8; ++j) acc[i][j] = (f32x4){0.f, 0.f, 0.f, 0.f};

  uint4 sA, sB, sC, sD;
  bf16x8 a0h[2], a0l[2], a1h[2], a1l[2];

  auto ldst = [&](int s) {
    const unsigned short* W = (AGG && s >= KS) ? W2 : W1;
    const unsigned short* ph = W + (s & (KS - 1)) * 4096;
    sA = *(const uint4*)(ph + t * 8);
    sB = *(const uint4*)(ph + 2048 + t * 8);
    sC = *(const uint4*)(ph + KLO + t * 8);
    sD = *(const uint4*)(ph + KLO + 2048 + t * 8);
  };
  auto wrst = [&](int buf) {
    *(uint4*)&wlds[buf][0][t * 8] = sA;
    *(uint4*)&wlds[buf][0][2048 + t * 8] = sB;
    *(uint4*)&wlds[buf][1][t * 8] = sC;
    *(uint4*)&wlds[buf][1][2048 + t * 8] = sD;
  };
  auto loadA = [&](int s, int w) {
    const unsigned short* X = (AGG && s >= KS) ? Bi : Ai;
    int kk = (s & (KS - 1)) * 32 + kg * 8;
    a0h[w] = *(const bf16x8*)(X + a0off + kk);
    a0l[w] = *(const bf16x8*)(X + a0off + KD + kk);
    a1h[w] = *(const bf16x8*)(X + a1off + kk);
    a1l[w] = *(const bf16x8*)(X + a1off + KD + kk);
  };

  ldst(0); wrst(0); loadA(0, 0);
  __syncthreads();

#pragma unroll
  for (int s = 0; s < NS; ++s) {
    const int buf = s & 1;
    if (s + 1 < NS) { ldst(s + 1); loadA(s + 1, buf ^ 1); }
#pragma unroll
    for (int nf = 0; nf < 8; ++nf) {
      const int wo = (nf * 16 + lm) * 32 + kg * 8;
      bf16x8 wh = *(const bf16x8*)&wlds[buf][0][wo];
      bf16x8 wl = *(const bf16x8*)&wlds[buf][1][wo];
      acc[0][nf] = __builtin_amdgcn_mfma_f32_16x16x32_bf16(a0h[buf], wh, acc[0][nf], 0, 0, 0);
      acc[0][nf] = __builtin_amdgcn_mfma_f32_16x16x32_bf16(a0h[buf], wl, acc[0][nf], 0, 0, 0);
      acc[0][nf] = __builtin_amdgcn_mfma_f32_16x16x32_bf16(a0l[buf], wh, acc[0][nf], 0, 0, 0);
      acc[1][nf] = __builtin_amdgcn_mfma_f32_16x16x32_bf16(a1h[buf], wh, acc[1][nf], 0, 0, 0);
      acc[1][nf] = __builtin_amdgcn_mfma_f32_16x16x32_bf16(a1h[buf], wl, acc[1][nf], 0, 0, 0);
      acc[1][nf] = __builtin_amdgcn_mfma_f32_16x16x32_bf16(a1l[buf], wh, acc[1][nf], 0, 0, 0);
    }
    if (s + 1 < NS) wrst(buf ^ 1);
    __syncthreads();
  }

  float4 bq0 = *(const float4*)&bias[lm * 8];
  float4 bq1 = *(const float4*)&bias[lm * 8 + 4];
  float bsv[8] = {bq0.x, bq0.y, bq0.z, bq0.w, bq1.x, bq1.y, bq1.z, bq1.w};
#pragma unroll
  for (int mf = 0; mf < 2; ++mf)
#pragma unroll
    for (int rr = 0; rr < 4; ++rr) {
      int row = row0 + mf * 16 + kg * 4 + rr;
      if (row >= n) continue;
      float gvv[8];
      if (GATH) {
        const float* grow = Gt + (size_t)Gidx[row] * H + lm * 8;
        float4 g0 = *(const float4*)grow;
        float4 g1 = *(const float4*)(grow + 4);
        gvv[0] = g0.x; gvv[1] = g0.y; gvv[2] = g0.z; gvv[3] = g0.w;
        gvv[4] = g1.x; gvv[5] = g1.y; gvv[6] = g1.z; gvv[7] = g1.w;
      }
      us8 hv, lv;
#pragma unroll
      for (int nf = 0; nf < 8; ++nf) {
        float v = acc[mf][nf][rr] + bsv[nf];
        if (GATH) v += gvv[nf];
        v = fmaxf(v, 0.f);
        unsigned h = bfr(v);
        hv[nf] = (unsigned short)h;
        lv[nf] = (unsigned short)bfr(v - asf(h << 16));
      }
      *(us8*)(Oi + (size_t)row * 256 + lm * 8) = hv;
      *(us8*)(Oi + (size_t)row * 256 + 128 + lm * 8) = lv;
    }
}

// ---------------- fused small-scale chain, MFMA + global_load_lds pipeline ----
// 10 stages (5 matrices x 2 x 32KB halves), wl double-buffered. All staging via
// global_load_lds (zero dest VGPRs, deep async queue) -- R10/R12 reg-staged
// versions were outstanding-request-limited (FETCH=2.8MB all-HBM at ~16 blocks,
// 96us @ 0.4% MfmaUtil). Ai rows preloaded once into act (stages 0-3 read LDS).
// Byte accounting: 32KB half = hi 16KB + lo 16KB; per wave quarter of each =
// 4KB = 4 glds calls x 1KB (64 lanes x 16B). act = MF*64KB/2: MF*8 calls/wave.
// Schedule: {MFMA(wl[b]) -> barrier (drains loads issued 1 stage ago) ->
// issue wl[b] <- half s+2}. k-slice order identical to R10 -> same numerics.
template <int MF, bool ISH1>
__global__ __launch_bounds__(256)
void fused_chain(const unsigned short* __restrict__ Ai,
                 const float* __restrict__ P, const float* __restrict__ pscale,
                 const float* __restrict__ Gt,
                 const unsigned short* __restrict__ Wd,
                 const unsigned short* __restrict__ Wa,
                 const unsigned short* __restrict__ Wu,
                 const unsigned short* __restrict__ We0,
                 const unsigned short* __restrict__ We1,
                 const float* __restrict__ bn, const float* __restrict__ be0,
                 const float* __restrict__ be1,
                 float* __restrict__ outD, unsigned short* __restrict__ Ao,
                 float* __restrict__ outF, int n) {
  __shared__ unsigned short act[MF * 64 * 256];  // MF=2: 64KB, MF=1: 32KB
  __shared__ unsigned short wl[2][16384];        // 2 x 32KB halves (hi|lo)
  const int t = threadIdx.x, wv = t >> 6, ln = t & 63;
  const int lm = ln & 15, kg = ln >> 4;
  const int rbase = blockIdx.x * (MF * 64) + wv * (MF * 16);
  const int lbase = wv * (MF * 16);
  int arr[MF];
#pragma unroll
  for (int mf = 0; mf < MF; ++mf) {
    int a = rbase + mf * 16 + lm;
    arr[mf] = (a < n) ? a : 0;
  }

  const unsigned short* mats[5] = {Wd, Wa, Wu, We0, We1};

  f32x4 acc[MF][8];
  auto zacc = [&]() {
#pragma unroll
    for (int mf = 0; mf < MF; ++mf)
#pragma unroll
      for (int nf = 0; nf < 8; ++nf) acc[mf][nf] = (f32x4){0.f, 0.f, 0.f, 0.f};
  };

  // issue async loads of half s into wl[b]: per wave 8 x 1KB (4 hi + 4 lo)
  auto ldwl = [&](int s, int b) {
    const unsigned short* hi = mats[s >> 1] + (s & 1) * 8192;
    const unsigned short* lo = mats[s >> 1] + 16384 + (s & 1) * 8192;
    const int wo = wv * 2048;       // wave quarter of 8192-short plane
    const int lo8 = ln * 8;         // lane slot (16B) in global src
#pragma unroll
    for (int j = 0; j < 4; ++j) {
      glds16(hi + wo + j * 512 + lo8, &wl[b][wo + j * 512]);
      glds16(lo + wo + j * 512 + lo8, &wl[b][8192 + wo + j * 512]);
    }
  };
  // issue async preload of this block's Ai rows into act (linear copy)
  auto ldact = [&]() {
    const unsigned short* src = Ai + (size_t)blockIdx.x * (MF * 64 * 256);
    const int base = wv * (MF * 4096);  // wave quarter in shorts
    const int lo8 = ln * 8;
#pragma unroll
    for (int j = 0; j < MF * 8; ++j)
      glds16(src + base + j * 512 + lo8, &act[base + j * 512]);
  };

  auto donf = [&](int b, int ksl, const bf16x8* ah, const bf16x8* al) {
#pragma unroll
    for (int nf = 0; nf < 8; ++nf) {
      const int wo = ksl * 4096 + (nf * 16 + lm) * 32 + kg * 8;
      bf16x8 wh = *(const bf16x8*)&wl[b][wo];
      bf16x8 wq = *(const bf16x8*)&wl[b][8192 + wo];
#pragma unroll
      for (int mf = 0; mf < MF; ++mf) {
        acc[mf][nf] = __builtin_amdgcn_mfma_f32_16x16x32_bf16(ah[mf], wh, acc[mf][nf], 0, 0, 0);
        acc[mf][nf] = __builtin_amdgcn_mfma_f32_16x16x32_bf16(ah[mf], wq, acc[mf][nf], 0, 0, 0);
        acc[mf][nf] = __builtin_amdgcn_mfma_f32_16x16x32_bf16(al[mf], wh, acc[mf][nf], 0, 0, 0);
      }
    }
  };

  auto epiAct = [&](const float* bias, bool gath) {
    float4 b0 = *(const float4*)&bias[lm * 8];
    float4 b1 = *(const float4*)&bias[lm * 8 + 4];
    float bv[8] = {b0.x, b0.y, b0.z, b0.w, b1.x, b1.y, b1.z, b1.w};
#pragma unroll
    for (int mf = 0; mf < MF; ++mf)
#pragma unroll
      for (int rr = 0; rr < 4; ++rr) {
        int rl = lbase + mf * 16 + kg * 4 + rr;
        int rg = rbase + mf * 16 + kg * 4 + rr;
        float gv[8] = {0.f, 0.f, 0.f, 0.f, 0.f, 0.f, 0.f, 0.f};
        if (ISH1 && gath && rg < n) {
          const float* grow = Gt + (size_t)(rg / F) * H + lm * 8;
          float4 g0 = *(const float4*)grow;
          float4 g1 = *(const float4*)(grow + 4);
          gv[0] = g0.x; gv[1] = g0.y; gv[2] = g0.z; gv[3] = g0.w;
          gv[4] = g1.x; gv[5] = g1.y; gv[6] = g1.z; gv[7] = g1.w;
        }
        us8 hv, lv;
#pragma unroll
        for (int nf = 0; nf < 8; ++nf) {
          float v = acc[mf][nf][rr] + bv[nf] + gv[nf];
          v = fmaxf(v, 0.f);
          unsigned h = bfr(v);
          hv[nf] = (unsigned short)h;
          lv[nf] = (unsigned short)bfr(v - asf(h << 16));
        }
        *(us8*)&act[rl * 256 + lm * 8] = hv;
        *(us8*)&act[rl * 256 + 128 + lm * 8] = lv;
      }
  };

  // ---- pipeline prologue: one exposed drain ----
  ldact();
  ldwl(0, 0);
  __syncthreads();           // drains act preload + half 0
  ldwl(1, 1);                // half 1 in flight across stage-0 MFMA

#pragma unroll
  for (int s = 0; s < 10; ++s) {
    const int b = s & 1;
    if (s == 0 || s == 2 || s == 6 || s == 8) zacc();
    const int m = s >> 1;
#pragma unroll
    for (int ksl = 0; ksl < 2; ++ksl) {
      const int ks = (s & 1) * 2 + ksl;
      bf16x8 ah[MF], al[MF];
      if (m == 2) {           // Wu pass: A from fp32 P (optionally scaled)
#pragma unroll
        for (int mf = 0; mf < MF; ++mf) {
          const float* pp = P + (size_t)arr[mf] * H + ks * 32 + kg * 8;
          float4 f0 = *(const float4*)pp;
          float4 f1 = *(const float4*)(pp + 4);
          if (ISH1) {
            float sc = pscale[arr[mf]];
            f0.x *= sc; f0.y *= sc; f0.z *= sc; f0.w *= sc;
            f1.x *= sc; f1.y *= sc; f1.z *= sc; f1.w *= sc;
          }
          float fv[8] = {f0.x, f0.y, f0.z, f0.w, f1.x, f1.y, f1.z, f1.w};
          us8 h8, l8;
#pragma unroll
          for (int j = 0; j < 8; ++j) {
            unsigned h = bfr(fv[j]);
            h8[j] = (unsigned short)h;
            l8[j] = (unsigned short)bfr(fv[j] - asf(h << 16));
          }
          ah[mf] = __builtin_bit_cast(bf16x8, h8);
          al[mf] = __builtin_bit_cast(bf16x8, l8);
        }
      } else {                // Wd/Wa (preloaded Ai) and We0/We1: A from act
#pragma unroll
        for (int mf = 0; mf < MF; ++mf) {
          int rl = lbase + mf * 16 + lm;
          ah[mf] = *(const bf16x8*)&act[rl * 256 + ks * 32 + kg * 8];
          al[mf] = *(const bf16x8*)&act[rl * 256 + 128 + ks * 32 + kg * 8];
        }
      }
      donf(b, ksl, ah, al);
    }
    // ---- epilogues (acc-only; act rows are wave-private) ----
    if (s == 1) {
#pragma unroll
      for (int mf = 0; mf < MF; ++mf)
#pragma unroll
        for (int rr = 0; rr < 4; ++rr) {
          int rg = rbase + mf * 16 + kg * 4 + rr;
          if (rg < n) {
            float* op = outD + (size_t)rg * H + lm * 8;
            *(float4*)op = make_float4(acc[mf][0][rr], acc[mf][1][rr], acc[mf][2][rr], acc[mf][3][rr]);
            *(float4*)(op + 4) = make_float4(acc[mf][4][rr], acc[mf][5][rr], acc[mf][6][rr], acc[mf][7][rr]);
          }
        }
    }
    if (s == 5) epiAct(bn, true);
    if (s == 7) epiAct(be0, false);
    if (s == 9) {
      float4 b0 = *(const float4*)&be1[lm * 8];
      float4 b1 = *(const float4*)&be1[lm * 8 + 4];
      float bv[8] = {b0.x, b0.y, b0.z, b0.w, b1.x, b1.y, b1.z, b1.w};
#pragma unroll
      for (int mf = 0; mf < MF; ++mf)
#pragma unroll
        for (int rr = 0; rr < 4; ++rr) {
          int rg = rbase + mf * 16 + kg * 4 + rr;
          if (rg >= n) continue;
          us8 hv, lv;
          float fv[8];
#pragma unroll
          for (int nf = 0; nf < 8; ++nf) {
            float v = fmaxf(acc[mf][nf][rr] + bv[nf], 0.f);
            fv[nf] = v;
            unsigned h = bfr(v);
            hv[nf] = (unsigned short)h;
            lv[nf] = (unsigned short)bfr(v - asf(h << 16));
          }
          *(us8*)(Ao + (size_t)rg * 256 + lm * 8) = hv;
          *(us8*)(Ao + (size_t)rg * 256 + 128 + lm * 8) = lv;
          if (outF) {
            float* op = outF + (size_t)rg * H + lm * 8;
            *(float4*)op = make_float4(fv[0], fv[1], fv[2], fv[3]);
            *(float4*)(op + 4) = make_float4(fv[4], fv[5], fv[6], fv[7]);
          }
        }
    }
    if (s + 1 < 10) {
      __syncthreads();            // all waves done with wl[b]; drains s+1 loads
      if (s + 2 < 10) ldwl(s + 2, b);  // refill the buffer just released
    }
  }
}

// ---------------- initial h1/h2: enc-plain on zeros => identical rows ----------------
__global__ void init_bcast(const float* __restrict__ Ws1, const float* __restrict__ b1,
                           const float* __restrict__ Ws2, const float* __restrict__ b2,
                           unsigned short* __restrict__ h1i, unsigned short* __restrict__ h2i) {
  __shared__ float z0[128];
  int t = threadIdx.x;  // 128
  bool ish2 = (blockIdx.x == 20);
  const float* W = ish2 ? Ws2 : Ws1;
  const float* bb = ish2 ? b2 : b1;
  z0[t] = fmaxf(bb[t], 0.f);
  __syncthreads();
  float s = bb[128 + t];
  for (int k = 0; k < 128; ++k) s += z0[k] * W[16384 + k * 128 + t];
  s = fmaxf(s, 0.f);
  unsigned h = bfr(s);
  unsigned l = bfr(s - asf(h << 16));
  if (ish2) {
    for (int r = 0; r < B; ++r) {
      h2i[(size_t)r * 256 + t] = (unsigned short)h;
      h2i[(size_t)r * 256 + 128 + t] = (unsigned short)l;
    }
  } else {
    int r0 = blockIdx.x * 100;
    for (int r = 0; r < 100; ++r) {
      h1i[(size_t)(r0 + r) * 256 + t] = (unsigned short)h;
      h1i[(size_t)(r0 + r) * 256 + 128 + t] = (unsigned short)l;
    }
  }
}

// ---------------- pooling (interleaved rows) ----------------
__global__ void pool_p01(const unsigned short* __restrict__ Act,
                         const int* __restrict__ a0l, const int* __restrict__ b0,
                         float* __restrict__ p01s) {
  __shared__ float acc[F][H];
  int t = threadIdx.x;  // 128
#pragma unroll
  for (int f = 0; f < F; ++f) acc[f][t] = 0.f;
  int rowbase = blockIdx.x * 250;
  for (int i = 0; i < 250; ++i) {
    size_t r = (size_t)(rowbase + i) * 256 + t;
    acc[a0l[rowbase + i]][t] += asf((unsigned)Act[r] << 16) + asf((unsigned)Act[r + 128] << 16);
  }
  int g = b0[rowbase];
#pragma unroll
  for (int f = 0; f < F; ++f)
    atomicAdd(&p01s[((size_t)(g * F + f)) * H + t], acc[f][t]);
}

__global__ void pool_g0(const unsigned short* __restrict__ Act,
                        const int* __restrict__ b0, float* __restrict__ g0s) {
  int t = threadIdx.x;
  int rowbase = blockIdx.x * 250;
  float a = 0.f;
  for (int i = 0; i < 250; ++i) {
    size_t r = (size_t)(rowbase + i) * 256 + t;
    a += asf((unsigned)Act[r] << 16) + asf((unsigned)Act[r + 128] << 16);
  }
  atomicAdd(&g0s[(size_t)b0[rowbase] * H + t], a);
}

// mean over F contiguous interleaved-bf16 rows per graph -> fp32
__global__ void mean40i(const unsigned short* __restrict__ Act, float* __restrict__ outp) {
  int t = threadIdx.x, g = blockIdx.x;
  float a = 0.f;
  for (int i = 0; i < F; ++i) {
    size_t r = (size_t)(g * F + i) * 256 + t;
    a += asf((unsigned)Act[r] << 16) + asf((unsigned)Act[r + 128] << 16);
  }
  outp[(size_t)g * H + t] = a * (1.0f / F);
}

// ---------------- head MLP ----------------
__global__ void head_k(const float* __restrict__ g0s, const float* __restrict__ rdegB,
                       const float* __restrict__ g1, const float* __restrict__ h2,
                       const float* __restrict__ W1h, const float* __restrict__ b1h,
                       const float* __restrict__ W2h, const float* __restrict__ b2h,
                       float* __restrict__ out) {
  __shared__ float gv[3 * H];
  __shared__ float z[H];
  int b = blockIdx.x, t = threadIdx.x;
  gv[t] = g0s[(size_t)b * H + t] * rdegB[b];
  gv[H + t] = g1[(size_t)b * H + t];
  gv[2 * H + t] = h2[(size_t)b * H + t];
  __syncthreads();
  float s = b1h[t];
  for (int k = 0; k < 3 * H; ++k) s += gv[k] * W1h[k * H + t];
  z[t] = fmaxf(s, 0.f);
  __syncthreads();
  if (t < C) {
    float o = b2h[t];
    for (int k = 0; k < H; ++k) o += z[k] * W2h[k * C + t];
    out[b * C + t] = o;
  }
}

}  // namespace

extern "C" void kernel_launch(void* const* d_in, const int* in_sizes, int n_in,
                              void* d_out, int out_size, void* d_ws, size_t ws_size,
                              hipStream_t stream) {
  (void)in_sizes; (void)n_in; (void)out_size; (void)ws_size;
  const float* x0   = (const float*)d_in[0];
  const int*   ei   = (const int*)d_in[1];
  const int*   src  = ei;
  const int*   dst  = ei + E;
  const int*   b0   = (const int*)d_in[2];
  const int*   a0l  = (const int*)d_in[3];
  const float* Wp   = (const float*)d_in[4];
  const float* bp   = (const float*)d_in[5];
  const float* e0in_Ws = (const float*)d_in[6];
  const float* e0in_Wn = (const float*)d_in[7];
  const float* e0in_b  = (const float*)d_in[8];
  const float* enc0_Ws = (const float*)d_in[9];
  const float* enc0_Wn = (const float*)d_in[10];
  const float* enc0_b  = (const float*)d_in[11];
  const float* e1in_Ws = (const float*)d_in[12];
  const float* e1in_b  = (const float*)d_in[13];
  const float* e2in_Ws = (const float*)d_in[14];
  const float* e2in_b  = (const float*)d_in[15];
  const float* enc1_Ws = (const float*)d_in[16];
  const float* enc1_b  = (const float*)d_in[17];
  const float* enc2_Ws = (const float*)d_in[18];
  const float* enc2_b  = (const float*)d_in[19];
  const float* A0 = (const float*)d_in[20];
  const float* A1 = (const float*)d_in[21];
  const float* A2 = (const float*)d_in[22];
  const float* U0 = (const float*)d_in[23];
  const float* U1 = (const float*)d_in[24];
  const float* D1 = (const float*)d_in[25];
  const float* D2 = (const float*)d_in[26];
  const float* ib0 = (const float*)d_in[27];
  const float* ib1 = (const float*)d_in[28];
  const float* ib2 = (const float*)d_in[29];
  const float* H1w = (const float*)d_in[30];
  const float* hb1 = (const float*)d_in[31];
  const float* H2w = (const float*)d_in[32];
  const float* hb2 = (const float*)d_in[33];
  float* out = (float*)d_out;

  // ---- workspace carve ----
  char* p = (char*)d_ws;
  auto carve = [&](size_t bytes) {
    char* r = p;
    p += (bytes + 255) & ~(size_t)255;
    return r;
  };
  char* z0 = p;  // zeroed-every-call region
  int*   deg    = (int*)carve((size_t)N * 4);
  int*   cursor = (int*)carve((size_t)N * 4);
  int*   cnt1   = (int*)carve((size_t)TF * 4);
  float* g0s    = (float*)carve((size_t)B * H * 4);
  size_t zbytes = (size_t)(p - z0);
  unsigned short* h0i  = (unsigned short*)carve((size_t)N * 256 * 2);
  unsigned short* aggi = (unsigned short*)carve((size_t)N * 256 * 2);
  unsigned short* h1a  = (unsigned short*)carve((size_t)TF * 256 * 2);
  unsigned short* h2ai = (unsigned short*)carve((size_t)64 * 256 * 2);
  float* h1d  = (float*)carve((size_t)TF * H * 4);
  float* h2d  = (float*)carve((size_t)64 * H * 4);
  float* h2f  = (float*)carve((size_t)B * H * 4);
  float* p01s = (float*)carve((size_t)TF * H * 4);
  float* p12  = (float*)carve((size_t)B * H * 4);
  float* g1   = (float*)carve((size_t)B * H * 4);
  float* rdeg = (float*)carve((size_t)N * 4);
  float* rdeg1 = (float*)carve((size_t)TF * 4);
  float* rdegB = (float*)carve(64 * 4);
  int* offs    = (int*)carve((size_t)(N + 64) * 4);
  int* srcS    = (int*)carve((size_t)E * 4);
  int* part    = (int*)carve(128 * 4);
  int* partEx  = (int*)carve(128 * 4);
  int* assign0 = (int*)carve((size_t)N * 4);
  unsigned short* wt  = (unsigned short*)carve((size_t)19 * 32768 * 2);
  unsigned short* wt9 = (unsigned short*)carve((size_t)16384 * 2);
  unsigned short* xs  = aggi;  // alias: x0-split used only before first agg_k

  const int HH = H * H;
  const int MG = (N + 127) / 128;  // 782

  // ---- CSR + histograms + weight/x0 split ----
  hipMemsetAsync(z0, 0, zbytes, stream);
  hist_edges<<<(E + 255) / 256, 256, 0, stream>>>(dst, deg);
  hist_nodes<<<(N + 255) / 256, 256, 0, stream>>>(b0, a0l, cnt1, assign0);
  const int nb1 = (N + 1023) / 1024;
  scan1<<<nb1, 256, 0, stream>>>(deg, offs, part);
  scan2<<<1, 128, 0, stream>>>(part, partEx, nb1);
  scan3<<<(N + 255) / 256, 256, 0, stream>>>(offs, partEx, deg, rdeg, cnt1, rdeg1,
                                             rdegB);
  scatter_k<<<(E + 255) / 256, 256, 0, stream>>>(src, dst, offs, cursor, srcS);
  {
    WPtrs wp;
    wp.w[0] = e0in_Ws;      wp.w[1] = e0in_Ws + HH;
    wp.w[2] = e0in_Wn;      wp.w[3] = e0in_Wn + HH;
    wp.w[4] = enc0_Ws;      wp.w[5] = enc0_Ws + HH;
    wp.w[6] = enc0_Wn;      wp.w[7] = enc0_Wn + HH;
    wp.w[8] = A0;
    wp.w[9] = D1;           wp.w[10] = A1;
    wp.w[11] = U0;          wp.w[12] = enc1_Ws;   wp.w[13] = enc1_Ws + HH;
    wp.w[14] = D2;          wp.w[15] = A2;
    wp.w[16] = U1;          wp.w[17] = enc2_Ws;   wp.w[18] = enc2_Ws + HH;
    conv_w<<<19 * 64, 256, 0, stream>>>(wp, wt);
  }
  conv_wp<<<32, 256, 0, stream>>>(Wp, wt9);
  x0split<<<(N * D0 + 255) / 256, 256, 0, stream>>>(x0, xs);

  // ---- input projection (MFMA, K=64) ----
  mgemm<64, false, false><<<MG, 256, 0, stream>>>(
      xs, wt9, nullptr, nullptr, nullptr, nullptr, bp, h0i, N);

  auto encEdgeM = [&](int wsIdx, int wnIdx, const float* barr) {
    for (int l = 0; l < 2; ++l) {
      agg_k<<<N / 4, 256, 0, stream>>>(h0i, offs, srcS, rdeg, aggi);
      mgemm<128, true, false><<<MG, 256, 0, stream>>>(
          h0i, wt + (size_t)(wsIdx + l) * 32768, aggi,
          wt + (size_t)(wnIdx + l) * 32768, nullptr, nullptr, barr + l * H, h0i, N);
    }
  };

  encEdgeM(0, 2, e0in_b);
  init_bcast<<<21, 128, 0, stream>>>(e1in_Ws, e1in_b, e2in_Ws, e2in_b, h1a, h2ai);

  for (int step = 0; step < 2; ++step) {
    hipMemsetAsync(p01s, 0, (size_t)TF * H * 4, stream);
    pool_p01<<<400, 128, 0, stream>>>(h0i, a0l, b0, p01s);
    mean40i<<<B, 128, 0, stream>>>(h1a, p12);
    // h2 chain: D2 -> h2d; n2 = relu(h2@A2 + p12@U1 + ib2); enc2 x2 -> h2ai/h2f
    fused_chain<1, false><<<1, 256, 0, stream>>>(
        h2ai, p12, nullptr, nullptr,
        wt + (size_t)14 * 32768, wt + (size_t)15 * 32768, wt + (size_t)16 * 32768,
        wt + (size_t)17 * 32768, wt + (size_t)18 * 32768,
        ib2, enc2_b, enc2_b + H, h2d, h2ai, h2f, B);
    // h1 chain: D1 -> h1d; n1 = relu(h1@A1 + (p01s*rdeg1)@U0 + h2d[r/F] + ib1); enc1 x2
    fused_chain<2, true><<<(TF + 127) / 128, 256, 0, stream>>>(
        h1a, p01s, rdeg1, h2d,
        wt + (size_t)9 * 32768, wt + (size_t)10 * 32768, wt + (size_t)11 * 32768,
        wt + (size_t)12 * 32768, wt + (size_t)13 * 32768,
        ib1, enc1_b, enc1_b + H, h1d, h1a, nullptr, TF);
    // n0 = relu(h0@A0 + h1d[assign0] + ib0)   (in-place, MFMA)
    mgemm<128, false, true><<<MG, 256, 0, stream>>>(
        h0i, wt + (size_t)8 * 32768, nullptr, nullptr, h1d, assign0, ib0, h0i, N);
    encEdgeM(4, 6, enc0_b);
  }

  pool_g0<<<400, 128, 0, stream>>>(h0i, b0, g0s);
  mean40i<<<B, 128, 0, stream>>>(h1a, g1);
  head_k<<<B, 128, 0, stream>>>(g0s, rdegB, g1, h2f, H1w, hb1, H2w, hb2, out);
}

// Round 14
// 925.458 us; speedup vs baseline: 1.1091x; 1.0646x over previous
//
#include <hip/hip_runtime.h>

namespace {

constexpr int N   = 100000;
constexpr int E   = 600000;
constexpr int B   = 50;
constexpr int F   = 40;
constexpr int TF  = B * F;     // 2000
constexpr int D0  = 64;
constexpr int H   = 128;
constexpr int C   = 2;

typedef __attribute__((ext_vector_type(8))) __bf16 bf16x8;
typedef __attribute__((ext_vector_type(8))) unsigned short us8;
typedef __attribute__((ext_vector_type(4))) float f32x4;

__device__ __forceinline__ float asf(unsigned u) { return __uint_as_float(u); }
// round-to-nearest-even fp32 -> bf16 (returns low 16 bits)
__device__ __forceinline__ unsigned bfr(float x) {
  unsigned u = __float_as_uint(x);
  return (u + 0x7FFFu + ((u >> 16) & 1u)) >> 16;
}

// async global->LDS: 16B per lane, LDS dest = uniform base + lane*16,
// global src = per-lane address. Counts in vmcnt (drained by __syncthreads).
__device__ __forceinline__ void glds16(const void* g, void* l) {
  __builtin_amdgcn_global_load_lds(
      (const __attribute__((address_space(1))) unsigned*)g,
      (__attribute__((address_space(3))) unsigned*)l, 16, 0, 0);
}

// ---------------- histograms / CSR build ----------------

__global__ void hist_edges(const int* __restrict__ dst, int* __restrict__ deg) {
  int e = blockIdx.x * 256 + threadIdx.x;
  if (e < E) atomicAdd(&deg[dst[e]], 1);
}

__global__ void hist_nodes(const int* __restrict__ b0, const int* __restrict__ a0l,
                           int* __restrict__ cnt1, int* __restrict__ assign0) {
  __shared__ int lh[TF];
  int t = threadIdx.x;
  for (int j = t; j < TF; j += 256) lh[j] = 0;
  __syncthreads();
  int i = blockIdx.x * 256 + t;
  if (i < N) {
    int g = b0[i];
    int a = g * F + a0l[i];
    assign0[i] = a;
    atomicAdd(&lh[a], 1);
  }
  __syncthreads();
  for (int j = t; j < TF; j += 256) {
    int c = lh[j];
    if (c) atomicAdd(&cnt1[j], c);
  }
}

__global__ void scan1(const int* __restrict__ cnt, int* __restrict__ offs,
                      int* __restrict__ part) {
  __shared__ int lds[256];
  int t = threadIdx.x;
  int base = blockIdx.x * 1024 + t * 4;
  int v[4];
#pragma unroll
  for (int j = 0; j < 4; ++j) v[j] = (base + j < N) ? cnt[base + j] : 0;
  int s = v[0] + v[1] + v[2] + v[3];
  lds[t] = s;
  __syncthreads();
  for (int off = 1; off < 256; off <<= 1) {
    int x = (t >= off) ? lds[t - off] : 0;
    __syncthreads();
    lds[t] += x;
    __syncthreads();
  }
  int ex = lds[t] - s;
  if (t == 255) part[blockIdx.x] = lds[255];
  int run = ex;
#pragma unroll
  for (int j = 0; j < 4; ++j) {
    if (base + j < N) offs[base + j] = run;
    run += v[j];
  }
}

__global__ void scan2(const int* __restrict__ part, int* __restrict__ partEx, int nb) {
  __shared__ int lds[128];
  int t = threadIdx.x;
  int s = (t < nb) ? part[t] : 0;
  lds[t] = s;
  __syncthreads();
  for (int off = 1; off < 128; off <<= 1) {
    int x = (t >= off) ? lds[t - off] : 0;
    __syncthreads();
    lds[t] += x;
    __syncthreads();
  }
  partEx[t] = lds[t] - s;
}

__global__ void scan3(int* __restrict__ offs, const int* __restrict__ partEx,
                      const int* __restrict__ deg, float* __restrict__ rdeg,
                      const int* __restrict__ cnt1, float* __restrict__ rdeg1,
                      float* __restrict__ rdegB) {
  int i = blockIdx.x * 256 + threadIdx.x;
  if (i < N) {
    offs[i] += partEx[i >> 10];
    rdeg[i] = 1.0f / fmaxf((float)deg[i], 1.0f);
    if (i == 0) offs[N] = E;
    if (i < TF) rdeg1[i] = 1.0f / fmaxf((float)cnt1[i], 1.0f);
    if (i < B) {
      int s = 0;
      for (int f = 0; f < F; ++f) s += cnt1[i * F + f];
      rdegB[i] = 1.0f / fmaxf((float)s, 1.0f);
    }
  }
}

__global__ void scatter_k(const int* __restrict__ src, const int* __restrict__ dst,
                          const int* __restrict__ offs, int* __restrict__ cursor,
                          int* __restrict__ srcS) {
  int e = blockIdx.x * 256 + threadIdx.x;
  if (e < E) {
    int d = dst[e];
    int pos = offs[d] + atomicAdd(&cursor[d], 1);
    srcS[pos] = src[e];
  }
}

// ---- weight conversion: fp32 [k][c] -> split-bf16, slice-major, col-permuted ----
struct WPtrs { const float* w[19]; };
__global__ void conv_w(WPtrs wp, unsigned short* __restrict__ wt) {
  int i = blockIdx.x >> 6;                         // matrix index
  int e = (blockIdx.x & 63) * 256 + threadIdx.x;   // 0..16383
  int k = e >> 7, c = e & 127;
  float x = wp.w[i][e];
  unsigned h = bfr(x);
  unsigned l = bfr(x - asf(h << 16));
  int cs = (c & 7) * 16 + (c >> 3);
  size_t o = (size_t)i * 32768 + (k >> 5) * 4096 + cs * 32 + (k & 31);
  wt[o] = (unsigned short)h;
  wt[o + 16384] = (unsigned short)l;
}

// Wp: fp32 [64][128] -> hi (2 slices * 4096) + lo at +8192
__global__ void conv_wp(const float* __restrict__ w, unsigned short* __restrict__ wt) {
  int e = blockIdx.x * 256 + threadIdx.x;  // 0..8191
  int k = e >> 7, c = e & 127;
  float x = w[e];
  unsigned h = bfr(x);
  unsigned l = bfr(x - asf(h << 16));
  int cs = (c & 7) * 16 + (c >> 3);
  size_t o = (size_t)(k >> 5) * 4096 + cs * 32 + (k & 31);
  wt[o] = (unsigned short)h;
  wt[o + 8192] = (unsigned short)l;
}

// x0 fp32 [N][64] -> interleaved rows [hi64 | lo64] (stride 128 shorts)
__global__ void x0split(const float* __restrict__ x0, unsigned short* __restrict__ xs) {
  int i = blockIdx.x * 256 + threadIdx.x;  // elem index
  if (i >= N * D0) return;
  int row = i >> 6, c = i & 63;
  float x = x0[i];
  unsigned h = bfr(x);
  unsigned l = bfr(x - asf(h << 16));
  xs[(size_t)row * 128 + c] = (unsigned short)h;
  xs[(size_t)row * 128 + 64 + c] = (unsigned short)l;
}

// ---- L3/L2 warm: touch the chain weight region so chain misses are cheap ----
__global__ void warm_k(const uint4* __restrict__ w, unsigned* __restrict__ dummy) {
  uint4 v = w[blockIdx.x * 256 + threadIdx.x];
  unsigned x = v.x ^ v.y ^ v.z ^ v.w;
  if (x == 0xDEADBEEFu) dummy[0] = 1u;  // keeps loads live; deterministic
}

// ---------------- edge aggregation (interleaved hi|lo rows, 512B) ----------------
__global__ void agg_k(const unsigned short* __restrict__ Act,
                      const int* __restrict__ offs, const int* __restrict__ srcS,
                      const float* __restrict__ rdeg, unsigned short* __restrict__ Out) {
  int wid = blockIdx.x * 4 + (threadIdx.x >> 6);
  int lane = threadIdx.x & 63;
  if (wid >= N) return;
  int o0 = offs[wid], o1 = offs[wid + 1];
  float s0 = 0.f, s1 = 0.f, s2 = 0.f, s3 = 0.f;
  int e = o0;
  for (; e + 3 < o1; e += 4) {
    uint2 v0 = *(const uint2*)(Act + (size_t)srcS[e] * 256 + lane * 4);
    uint2 v1 = *(const uint2*)(Act + (size_t)srcS[e + 1] * 256 + lane * 4);
    uint2 v2 = *(const uint2*)(Act + (size_t)srcS[e + 2] * 256 + lane * 4);
    uint2 v3 = *(const uint2*)(Act + (size_t)srcS[e + 3] * 256 + lane * 4);
    s0 += asf(v0.x << 16) + asf(v1.x << 16) + asf(v2.x << 16) + asf(v3.x << 16);
    s1 += asf(v0.x & 0xFFFF0000u) + asf(v1.x & 0xFFFF0000u) +
          asf(v2.x & 0xFFFF0000u) + asf(v3.x & 0xFFFF0000u);
    s2 += asf(v0.y << 16) + asf(v1.y << 16) + asf(v2.y << 16) + asf(v3.y << 16);
    s3 += asf(v0.y & 0xFFFF0000u) + asf(v1.y & 0xFFFF0000u) +
          asf(v2.y & 0xFFFF0000u) + asf(v3.y & 0xFFFF0000u);
  }
  for (; e < o1; ++e) {
    uint2 v0 = *(const uint2*)(Act + (size_t)srcS[e] * 256 + lane * 4);
    s0 += asf(v0.x << 16);
    s1 += asf(v0.x & 0xFFFF0000u);
    s2 += asf(v0.y << 16);
    s3 += asf(v0.y & 0xFFFF0000u);
  }
  float sc = rdeg[wid];
  float v0 = (s0 + __shfl_xor(s0, 32)) * sc;
  float v1 = (s1 + __shfl_xor(s1, 32)) * sc;
  float v2 = (s2 + __shfl_xor(s2, 32)) * sc;
  float v3 = (s3 + __shfl_xor(s3, 32)) * sc;
  unsigned h0 = bfr(v0), h1 = bfr(v1), h2 = bfr(v2), h3 = bfr(v3);
  unsigned w0, w1;
  if (lane < 32) {
    w0 = h0 | (h1 << 16);
    w1 = h2 | (h3 << 16);
  } else {
    unsigned l0 = bfr(v0 - asf(h0 << 16)), l1 = bfr(v1 - asf(h1 << 16));
    unsigned l2 = bfr(v2 - asf(h2 << 16)), l3 = bfr(v3 - asf(h3 << 16));
    w0 = l0 | (l1 << 16);
    w1 = l2 | (l3 << 16);
  }
  unsigned short* po = Out + (size_t)wid * 256 + (lane & 31) * 4 + (lane >= 32 ? 128 : 0);
  *(uint2*)po = make_uint2(w0, w1);
}

// ---------------- split-bf16 MFMA GEMM, LDS-staged weights (N-row layers) ----------------
template <int KD, bool AGG, bool GATH>
__global__ __launch_bounds__(256, 3)
void mgemm(const unsigned short* __restrict__ Ai, const unsigned short* __restrict__ W1,
           const unsigned short* __restrict__ Bi, const unsigned short* __restrict__ W2,
           const float* __restrict__ Gt, const int* __restrict__ Gidx,
           const float* __restrict__ bias, unsigned short* __restrict__ Oi, int n) {
  __shared__ unsigned short wlds[2][2][4096];  // [buf][hi/lo][slice]
  constexpr int KS = KD / 32;
  constexpr int NS = (AGG ? 2 : 1) * KS;
  constexpr int KLO = KD * 128;
  constexpr int ARS = 2 * KD;
  const int t = threadIdx.x, wv = t >> 6, ln = t & 63;
  const int row0 = blockIdx.x * 128 + wv * 32;
  const int lm = ln & 15, kg = ln >> 4;
  int ar0 = row0 + lm, ar1 = row0 + 16 + lm;
  if (ar0 >= n) ar0 = 0;
  if (ar1 >= n) ar1 = 0;
  const size_t a0off = (size_t)ar0 * ARS, a1off = (size_t)ar1 * ARS;

  f32x4 acc[2][8];
#pragma unroll
  for (int i = 0; i < 2; ++i)
#pragma unroll
    for (int j = 0; j < 8; ++j) acc[i][j] = (f32x4){0.f, 0.f, 0.f, 0.f};

  uint4 sA, sB, sC, sD;
  bf16x8 a0h[2], a0l[2], a1h[2], a1l[2];

  auto ldst = [&](int s) {
    const unsigned short* W = (AGG && s >= KS) ? W2 : W1;
    const unsigned short* ph = W + (s & (KS - 1)) * 4096;
    sA = *(const uint4*)(ph + t * 8);
    sB = *(const uint4*)(ph + 2048 + t * 8);
    sC = *(const uint4*)(ph + KLO + t * 8);
    sD = *(const uint4*)(ph + KLO + 2048 + t * 8);
  };
  auto wrst = [&](int buf) {
    *(uint4*)&wlds[buf][0][t * 8] = sA;
    *(uint4*)&wlds[buf][0][2048 + t * 8] = sB;
    *(uint4*)&wlds[buf][1][t * 8] = sC;
    *(uint4*)&wlds[buf][1][2048 + t * 8] = sD;
  };
  auto loadA = [&](int s, int w) {
    const unsigned short* X = (AGG && s >= KS) ? Bi : Ai;
    int kk = (s & (KS - 1)) * 32 + kg * 8;
    a0h[w] = *(const bf16x8*)(X + a0off + kk);
    a0l[w] = *(const bf16x8*)(X + a0off + KD + kk);
    a1h[w] = *(const bf16x8*)(X + a1off + kk);
    a1l[w] = *(const bf16x8*)(X + a1off + KD + kk);
  };

  ldst(0); wrst(0); loadA(0, 0);
  __syncthreads();

#pragma unroll
  for (int s = 0; s < NS; ++s) {
    const int buf = s & 1;
    if (s + 1 < NS) { ldst(s + 1); loadA(s + 1, buf ^ 1); }
#pragma unroll
    for (int nf = 0; nf < 8; ++nf) {
      const int wo = (nf * 16 + lm) * 32 + kg * 8;
      bf16x8 wh = *(const bf16x8*)&wlds[buf][0][wo];
      bf16x8 wl = *(const bf16x8*)&wlds[buf][1][wo];
      acc[0][nf] = __builtin_amdgcn_mfma_f32_16x16x32_bf16(a0h[buf], wh, acc[0][nf], 0, 0, 0);
      acc[0][nf] = __builtin_amdgcn_mfma_f32_16x16x32_bf16(a0h[buf], wl, acc[0][nf], 0, 0, 0);
      acc[0][nf] = __builtin_amdgcn_mfma_f32_16x16x32_bf16(a0l[buf], wh, acc[0][nf], 0, 0, 0);
      acc[1][nf] = __builtin_amdgcn_mfma_f32_16x16x32_bf16(a1h[buf], wh, acc[1][nf], 0, 0, 0);
      acc[1][nf] = __builtin_amdgcn_mfma_f32_16x16x32_bf16(a1h[buf], wl, acc[1][nf], 0, 0, 0);
      acc[1][nf] = __builtin_amdgcn_mfma_f32_16x16x32_bf16(a1l[buf], wh, acc[1][nf], 0, 0, 0);
    }
    if (s + 1 < NS) wrst(buf ^ 1);
    __syncthreads();
  }

  float4 bq0 = *(const float4*)&bias[lm * 8];
  float4 bq1 = *(const float4*)&bias[lm * 8 + 4];
  float bsv[8] = {bq0.x, bq0.y, bq0.z, bq0.w, bq1.x, bq1.y, bq1.z, bq1.w};
#pragma unroll
  for (int mf = 0; mf < 2; ++mf)
#pragma unroll
    for (int rr = 0; rr < 4; ++rr) {
      int row = row0 + mf * 16 + kg * 4 + rr;
      if (row >= n) continue;
      float gvv[8];
      if (GATH) {
        const float* grow = Gt + (size_t)Gidx[row] * H + lm * 8;
        float4 g0 = *(const float4*)grow;
        float4 g1 = *(const float4*)(grow + 4);
        gvv[0] = g0.x; gvv[1] = g0.y; gvv[2] = g0.z; gvv[3] = g0.w;
        gvv[4] = g1.x; gvv[5] = g1.y; gvv[6] = g1.z; gvv[7] = g1.w;
      }
      us8 hv, lv;
#pragma unroll
      for (int nf = 0; nf < 8; ++nf) {
        float v = acc[mf][nf][rr] + bsv[nf];
        if (GATH) v += gvv[nf];
        v = fmaxf(v, 0.f);
        unsigned h = bfr(v);
        hv[nf] = (unsigned short)h;
        lv[nf] = (unsigned short)bfr(v - asf(h << 16));
      }
      *(us8*)(Oi + (size_t)row * 256 + lm * 8) = hv;
      *(us8*)(Oi + (size_t)row * 256 + 128 + lm * 8) = lv;
    }
}

// ---------------- fused small-scale chain: 512 threads, 8 waves x 16 rows ----
// 10 stages (5 matrices x 2 x 32KB halves), wl double-buffered, all staging via
// global_load_lds. 8 waves double the per-CU load-issue parallelism vs R13's 4
// (invariant ~85us across R10-R13 = per-CU miss-throughput wall).
// Byte accounting: hi plane 8192 shorts -> 1024 shorts/wave = 2 glds x 512;
// same lo => 4 glds/wave, 32/block = 32KB. act = 128 rows x 256 shorts = 64KB
// = 4096 shorts/wave = 8 glds/wave. Block rows = 128 (buffers padded by caller).
template <bool ISH1>
__global__ __launch_bounds__(512)
void fused_chain(const unsigned short* __restrict__ Ai,
                 const float* __restrict__ P, const float* __restrict__ pscale,
                 const float* __restrict__ Gt,
                 const unsigned short* __restrict__ Wd,
                 const unsigned short* __restrict__ Wa,
                 const unsigned short* __restrict__ Wu,
                 const unsigned short* __restrict__ We0,
                 const unsigned short* __restrict__ We1,
                 const float* __restrict__ bn, const float* __restrict__ be0,
                 const float* __restrict__ be1,
                 float* __restrict__ outD, unsigned short* __restrict__ Ao,
                 float* __restrict__ outF, int n) {
  __shared__ unsigned short act[128 * 256];   // 64KB: 128 interleaved rows
  __shared__ unsigned short wl[2][16384];     // 2 x 32KB halves (hi|lo)
  const int t = threadIdx.x, wv = t >> 6, ln = t & 63;
  const int lm = ln & 15, kg = ln >> 4;
  const int rbase = blockIdx.x * 128 + wv * 16;  // wave owns 16 rows
  const int lbase = wv * 16;
  int ar = rbase + lm;
  if (ar >= n) ar = 0;

  const unsigned short* mats[5] = {Wd, Wa, Wu, We0, We1};

  f32x4 acc[8];
  auto zacc = [&]() {
#pragma unroll
    for (int nf = 0; nf < 8; ++nf) acc[nf] = (f32x4){0.f, 0.f, 0.f, 0.f};
  };

  // half s into wl[b]: per wave 2 glds hi + 2 glds lo (512 shorts each)
  auto ldwl = [&](int s, int b) {
    const unsigned short* hi = mats[s >> 1] + (s & 1) * 8192;
    const unsigned short* lo = mats[s >> 1] + 16384 + (s & 1) * 8192;
    const int wo = wv * 1024;
    const int lo8 = ln * 8;
#pragma unroll
    for (int j = 0; j < 2; ++j) {
      glds16(hi + wo + j * 512 + lo8, &wl[b][wo + j * 512]);
      glds16(lo + wo + j * 512 + lo8, &wl[b][8192 + wo + j * 512]);
    }
  };
  // preload this block's 128 Ai rows (linear 64KB): 8 glds/wave
  auto ldact = [&]() {
    const unsigned short* src = Ai + (size_t)blockIdx.x * (128 * 256);
    const int base = wv * 4096;
    const int lo8 = ln * 8;
#pragma unroll
    for (int j = 0; j < 8; ++j)
      glds16(src + base + j * 512 + lo8, &act[base + j * 512]);
  };

  auto donf = [&](int b, int ksl, bf16x8 ah, bf16x8 al) {
#pragma unroll
    for (int nf = 0; nf < 8; ++nf) {
      const int wo = ksl * 4096 + (nf * 16 + lm) * 32 + kg * 8;
      bf16x8 wh = *(const bf16x8*)&wl[b][wo];
      bf16x8 wq = *(const bf16x8*)&wl[b][8192 + wo];
      acc[nf] = __builtin_amdgcn_mfma_f32_16x16x32_bf16(ah, wh, acc[nf], 0, 0, 0);
      acc[nf] = __builtin_amdgcn_mfma_f32_16x16x32_bf16(ah, wq, acc[nf], 0, 0, 0);
      acc[nf] = __builtin_amdgcn_mfma_f32_16x16x32_bf16(al, wh, acc[nf], 0, 0, 0);
    }
  };

  auto epiAct = [&](const float* bias, bool gath) {
    float4 b0 = *(const float4*)&bias[lm * 8];
    float4 b1 = *(const float4*)&bias[lm * 8 + 4];
    float bv[8] = {b0.x, b0.y, b0.z, b0.w, b1.x, b1.y, b1.z, b1.w};
#pragma unroll
    for (int rr = 0; rr < 4; ++rr) {
      int rl = lbase + kg * 4 + rr;
      int rg = rbase + kg * 4 + rr;
      float gv[8] = {0.f, 0.f, 0.f, 0.f, 0.f, 0.f, 0.f, 0.f};
      if (ISH1 && gath && rg < n) {
        const float* grow = Gt + (size_t)(rg / F) * H + lm * 8;
        float4 g0 = *(const float4*)grow;
        float4 g1 = *(const float4*)(grow + 4);
        gv[0] = g0.x; gv[1] = g0.y; gv[2] = g0.z; gv[3] = g0.w;
        gv[4] = g1.x; gv[5] = g1.y; gv[6] = g1.z; gv[7] = g1.w;
      }
      us8 hv, lv;
#pragma unroll
      for (int nf = 0; nf < 8; ++nf) {
        float v = acc[nf][rr] + bv[nf] + gv[nf];
        v = fmaxf(v, 0.f);
        unsigned h = bfr(v);
        hv[nf] = (unsigned short)h;
        lv[nf] = (unsigned short)bfr(v - asf(h << 16));
      }
      *(us8*)&act[rl * 256 + lm * 8] = hv;
      *(us8*)&act[rl * 256 + 128 + lm * 8] = lv;
    }
  };

  // ---- pipeline prologue: one exposed drain ----
  ldact();
  ldwl(0, 0);
  __syncthreads();           // drains act preload + half 0
  ldwl(1, 1);                // half 1 in flight across stage-0 MFMA

#pragma unroll
  for (int s = 0; s < 10; ++s) {
    const int b = s & 1;
    if (s == 0 || s == 2 || s == 6 || s == 8) zacc();
    const int m = s >> 1;
#pragma unroll
    for (int ksl = 0; ksl < 2; ++ksl) {
      const int ks = (s & 1) * 2 + ksl;
      bf16x8 ah, al;
      if (m == 2) {           // Wu pass: A from fp32 P (optionally scaled)
        const float* pp = P + (size_t)ar * H + ks * 32 + kg * 8;
        float4 f0 = *(const float4*)pp;
        float4 f1 = *(const float4*)(pp + 4);
        if (ISH1) {
          float sc = pscale[ar];
          f0.x *= sc; f0.y *= sc; f0.z *= sc; f0.w *= sc;
          f1.x *= sc; f1.y *= sc; f1.z *= sc; f1.w *= sc;
        }
        float fv[8] = {f0.x, f0.y, f0.z, f0.w, f1.x, f1.y, f1.z, f1.w};
        us8 h8, l8;
#pragma unroll
        for (int j = 0; j < 8; ++j) {
          unsigned h = bfr(fv[j]);
          h8[j] = (unsigned short)h;
          l8[j] = (unsigned short)bfr(fv[j] - asf(h << 16));
        }
        ah = __builtin_bit_cast(bf16x8, h8);
        al = __builtin_bit_cast(bf16x8, l8);
      } else {                // Wd/Wa (preloaded Ai) and We0/We1: A from act
        int rl = lbase + lm;
        ah = *(const bf16x8*)&act[rl * 256 + ks * 32 + kg * 8];
        al = *(const bf16x8*)&act[rl * 256 + 128 + ks * 32 + kg * 8];
      }
      donf(b, ksl, ah, al);
    }
    // ---- epilogues (acc-only; act rows are wave-private) ----
    if (s == 1) {
#pragma unroll
      for (int rr = 0; rr < 4; ++rr) {
        int rg = rbase + kg * 4 + rr;
        if (rg < n) {
          float* op = outD + (size_t)rg * H + lm * 8;
          *(float4*)op = make_float4(acc[0][rr], acc[1][rr], acc[2][rr], acc[3][rr]);
          *(float4*)(op + 4) = make_float4(acc[4][rr], acc[5][rr], acc[6][rr], acc[7][rr]);
        }
      }
    }
    if (s == 5) epiAct(bn, true);
    if (s == 7) epiAct(be0, false);
    if (s == 9) {
      float4 b0 = *(const float4*)&be1[lm * 8];
      float4 b1 = *(const float4*)&be1[lm * 8 + 4];
      float bv[8] = {b0.x, b0.y, b0.z, b0.w, b1.x, b1.y, b1.z, b1.w};
#pragma unroll
      for (int rr = 0; rr < 4; ++rr) {
        int rg = rbase + kg * 4 + rr;
        if (rg >= n) continue;
        us8 hv, lv;
        float fv[8];
#pragma unroll
        for (int nf = 0; nf < 8; ++nf) {
          float v = fmaxf(acc[nf][rr] + bv[nf], 0.f);
          fv[nf] = v;
          unsigned h = bfr(v);
          hv[nf] = (unsigned short)h;
          lv[nf] = (unsigned short)bfr(v - asf(h << 16));
        }
        *(us8*)(Ao + (size_t)rg * 256 + lm * 8) = hv;
        *(us8*)(Ao + (size_t)rg * 256 + 128 + lm * 8) = lv;
        if (outF) {
          float* op = outF + (size_t)rg * H + lm * 8;
          *(float4*)op = make_float4(fv[0], fv[1], fv[2], fv[3]);
          *(float4*)(op + 4) = make_float4(fv[4], fv[5], fv[6], fv[7]);
        }
      }
    }
    if (s + 1 < 10) {
      __syncthreads();            // all waves done with wl[b]; drains s+1 loads
      if (s + 2 < 10) ldwl(s + 2, b);  // refill the buffer just released
    }
  }
}

// ---------------- initial h1/h2: enc-plain on zeros => identical rows ----------------
__global__ void init_bcast(const float* __restrict__ Ws1, const float* __restrict__ b1,
                           const float* __restrict__ Ws2, const float* __restrict__ b2,
                           unsigned short* __restrict__ h1i, unsigned short* __restrict__ h2i) {
  __shared__ float z0[128];
  int t = threadIdx.x;  // 128
  bool ish2 = (blockIdx.x == 20);
  const float* W = ish2 ? Ws2 : Ws1;
  const float* bb = ish2 ? b2 : b1;
  z0[t] = fmaxf(bb[t], 0.f);
  __syncthreads();
  float s = bb[128 + t];
  for (int k = 0; k < 128; ++k) s += z0[k] * W[16384 + k * 128 + t];
  s = fmaxf(s, 0.f);
  unsigned h = bfr(s);
  unsigned l = bfr(s - asf(h << 16));
  if (ish2) {
    for (int r = 0; r < B; ++r) {
      h2i[(size_t)r * 256 + t] = (unsigned short)h;
      h2i[(size_t)r * 256 + 128 + t] = (unsigned short)l;
    }
  } else {
    int r0 = blockIdx.x * 100;
    for (int r = 0; r < 100; ++r) {
      h1i[(size_t)(r0 + r) * 256 + t] = (unsigned short)h;
      h1i[(size_t)(r0 + r) * 256 + 128 + t] = (unsigned short)l;
    }
  }
}

// ---------------- pooling (interleaved rows) ----------------
__global__ void pool_p01(const unsigned short* __restrict__ Act,
                         const int* __restrict__ a0l, const int* __restrict__ b0,
                         float* __restrict__ p01s) {
  __shared__ float acc[F][H];
  int t = threadIdx.x;  // 128
#pragma unroll
  for (int f = 0; f < F; ++f) acc[f][t] = 0.f;
  int rowbase = blockIdx.x * 250;
  for (int i = 0; i < 250; ++i) {
    size_t r = (size_t)(rowbase + i) * 256 + t;
    acc[a0l[rowbase + i]][t] += asf((unsigned)Act[r] << 16) + asf((unsigned)Act[r + 128] << 16);
  }
  int g = b0[rowbase];
#pragma unroll
  for (int f = 0; f < F; ++f)
    atomicAdd(&p01s[((size_t)(g * F + f)) * H + t], acc[f][t]);
}

__global__ void pool_g0(const unsigned short* __restrict__ Act,
                        const int* __restrict__ b0, float* __restrict__ g0s) {
  int t = threadIdx.x;
  int rowbase = blockIdx.x * 250;
  float a = 0.f;
  for (int i = 0; i < 250; ++i) {
    size_t r = (size_t)(rowbase + i) * 256 + t;
    a += asf((unsigned)Act[r] << 16) + asf((unsigned)Act[r + 128] << 16);
  }
  atomicAdd(&g0s[(size_t)b0[rowbase] * H + t], a);
}

// mean over F contiguous interleaved-bf16 rows per graph -> fp32
__global__ void mean40i(const unsigned short* __restrict__ Act, float* __restrict__ outp) {
  int t = threadIdx.x, g = blockIdx.x;
  float a = 0.f;
  for (int i = 0; i < F; ++i) {
    size_t r = (size_t)(g * F + i) * 256 + t;
    a += asf((unsigned)Act[r] << 16) + asf((unsigned)Act[r + 128] << 16);
  }
  outp[(size_t)g * H + t] = a * (1.0f / F);
}

// ---------------- head MLP ----------------
__global__ void head_k(const float* __restrict__ g0s, const float* __restrict__ rdegB,
                       const float* __restrict__ g1, const float* __restrict__ h2,
                       const float* __restrict__ W1h, const float* __restrict__ b1h,
                       const float* __restrict__ W2h, const float* __restrict__ b2h,
                       float* __restrict__ out) {
  __shared__ float gv[3 * H];
  __shared__ float z[H];
  int b = blockIdx.x, t = threadIdx.x;
  gv[t] = g0s[(size_t)b * H + t] * rdegB[b];
  gv[H + t] = g1[(size_t)b * H + t];
  gv[2 * H + t] = h2[(size_t)b * H + t];
  __syncthreads();
  float s = b1h[t];
  for (int k = 0; k < 3 * H; ++k) s += gv[k] * W1h[k * H + t];
  z[t] = fmaxf(s, 0.f);
  __syncthreads();
  if (t < C) {
    float o = b2h[t];
    for (int k = 0; k < H; ++k) o += z[k] * W2h[k * C + t];
    out[b * C + t] = o;
  }
}

}  // namespace

extern "C" void kernel_launch(void* const* d_in, const int* in_sizes, int n_in,
                              void* d_out, int out_size, void* d_ws, size_t ws_size,
                              hipStream_t stream) {
  (void)in_sizes; (void)n_in; (void)out_size; (void)ws_size;
  const float* x0   = (const float*)d_in[0];
  const int*   ei   = (const int*)d_in[1];
  const int*   src  = ei;
  const int*   dst  = ei + E;
  const int*   b0   = (const int*)d_in[2];
  const int*   a0l  = (const int*)d_in[3];
  const float* Wp   = (const float*)d_in[4];
  const float* bp   = (const float*)d_in[5];
  const float* e0in_Ws = (const float*)d_in[6];
  const float* e0in_Wn = (const float*)d_in[7];
  const float* e0in_b  = (const float*)d_in[8];
  const float* enc0_Ws = (const float*)d_in[9];
  const float* enc0_Wn = (const float*)d_in[10];
  const float* enc0_b  = (const float*)d_in[11];
  const float* e1in_Ws = (const float*)d_in[12];
  const float* e1in_b  = (const float*)d_in[13];
  const float* e2in_Ws = (const float*)d_in[14];
  const float* e2in_b  = (const float*)d_in[15];
  const float* enc1_Ws = (const float*)d_in[16];
  const float* enc1_b  = (const float*)d_in[17];
  const float* enc2_Ws = (const float*)d_in[18];
  const float* enc2_b  = (const float*)d_in[19];
  const float* A0 = (const float*)d_in[20];
  const float* A1 = (const float*)d_in[21];
  const float* A2 = (const float*)d_in[22];
  const float* U0 = (const float*)d_in[23];
  const float* U1 = (const float*)d_in[24];
  const float* D1 = (const float*)d_in[25];
  const float* D2 = (const float*)d_in[26];
  const float* ib0 = (const float*)d_in[27];
  const float* ib1 = (const float*)d_in[28];
  const float* ib2 = (const float*)d_in[29];
  const float* H1w = (const float*)d_in[30];
  const float* hb1 = (const float*)d_in[31];
  const float* H2w = (const float*)d_in[32];
  const float* hb2 = (const float*)d_in[33];
  float* out = (float*)d_out;

  // ---- workspace carve ----
  char* p = (char*)d_ws;
  auto carve = [&](size_t bytes) {
    char* r = p;
    p += (bytes + 255) & ~(size_t)255;
    return r;
  };
  char* z0 = p;  // zeroed-every-call region
  int*   deg    = (int*)carve((size_t)N * 4);
  int*   cursor = (int*)carve((size_t)N * 4);
  int*   cnt1   = (int*)carve((size_t)TF * 4);
  float* g0s    = (float*)carve((size_t)B * H * 4);
  size_t zbytes = (size_t)(p - z0);
  unsigned short* h0i  = (unsigned short*)carve((size_t)N * 256 * 2);
  unsigned short* aggi = (unsigned short*)carve((size_t)N * 256 * 2);
  unsigned short* h1a  = (unsigned short*)carve((size_t)2048 * 256 * 2);  // padded to 16 blocks x 128 rows
  unsigned short* h2ai = (unsigned short*)carve((size_t)128 * 256 * 2);   // padded to 128 rows
  float* h1d  = (float*)carve((size_t)TF * H * 4);
  float* h2d  = (float*)carve((size_t)64 * H * 4);
  float* h2f  = (float*)carve((size_t)B * H * 4);
  float* p01s = (float*)carve((size_t)TF * H * 4);
  float* p12  = (float*)carve((size_t)64 * H * 4);
  float* g1   = (float*)carve((size_t)B * H * 4);
  float* rdeg = (float*)carve((size_t)N * 4);
  float* rdeg1 = (float*)carve((size_t)TF * 4);
  float* rdegB = (float*)carve(64 * 4);
  int* offs    = (int*)carve((size_t)(N + 64) * 4);
  int* srcS    = (int*)carve((size_t)E * 4);
  int* part    = (int*)carve(128 * 4);
  int* partEx  = (int*)carve(128 * 4);
  int* assign0 = (int*)carve((size_t)N * 4);
  unsigned short* wt  = (unsigned short*)carve((size_t)19 * 32768 * 2);
  unsigned short* wt9 = (unsigned short*)carve((size_t)16384 * 2);
  unsigned short* xs  = aggi;  // alias: x0-split used only before first agg_k

  const int HH = H * H;
  const int MG = (N + 127) / 128;  // 782

  // ---- CSR + histograms + weight/x0 split ----
  hipMemsetAsync(z0, 0, zbytes, stream);
  hist_edges<<<(E + 255) / 256, 256, 0, stream>>>(dst, deg);
  hist_nodes<<<(N + 255) / 256, 256, 0, stream>>>(b0, a0l, cnt1, assign0);
  const int nb1 = (N + 1023) / 1024;
  scan1<<<nb1, 256, 0, stream>>>(deg, offs, part);
  scan2<<<1, 128, 0, stream>>>(part, partEx, nb1);
  scan3<<<(N + 255) / 256, 256, 0, stream>>>(offs, partEx, deg, rdeg, cnt1, rdeg1,
                                             rdegB);
  scatter_k<<<(E + 255) / 256, 256, 0, stream>>>(src, dst, offs, cursor, srcS);
  {
    WPtrs wp;
    wp.w[0] = e0in_Ws;      wp.w[1] = e0in_Ws + HH;
    wp.w[2] = e0in_Wn;      wp.w[3] = e0in_Wn + HH;
    wp.w[4] = enc0_Ws;      wp.w[5] = enc0_Ws + HH;
    wp.w[6] = enc0_Wn;      wp.w[7] = enc0_Wn + HH;
    wp.w[8] = A0;
    wp.w[9] = D1;           wp.w[10] = A1;
    wp.w[11] = U0;          wp.w[12] = enc1_Ws;   wp.w[13] = enc1_Ws + HH;
    wp.w[14] = D2;          wp.w[15] = A2;
    wp.w[16] = U1;          wp.w[17] = enc2_Ws;   wp.w[18] = enc2_Ws + HH;
    conv_w<<<19 * 64, 256, 0, stream>>>(wp, wt);
  }
  conv_wp<<<32, 256, 0, stream>>>(Wp, wt9);
  x0split<<<(N * D0 + 255) / 256, 256, 0, stream>>>(x0, xs);

  // ---- input projection (MFMA, K=64) ----
  mgemm<64, false, false><<<MG, 256, 0, stream>>>(
      xs, wt9, nullptr, nullptr, nullptr, nullptr, bp, h0i, N);

  auto encEdgeM = [&](int wsIdx, int wnIdx, const float* barr) {
    for (int l = 0; l < 2; ++l) {
      agg_k<<<N / 4, 256, 0, stream>>>(h0i, offs, srcS, rdeg, aggi);
      mgemm<128, true, false><<<MG, 256, 0, stream>>>(
          h0i, wt + (size_t)(wsIdx + l) * 32768, aggi,
          wt + (size_t)(wnIdx + l) * 32768, nullptr, nullptr, barr + l * H, h0i, N);
    }
  };

  encEdgeM(0, 2, e0in_b);
  init_bcast<<<21, 128, 0, stream>>>(e1in_Ws, e1in_b, e2in_Ws, e2in_b, h1a, h2ai);

  for (int step = 0; step < 2; ++step) {
    hipMemsetAsync(p01s, 0, (size_t)TF * H * 4, stream);
    pool_p01<<<400, 128, 0, stream>>>(h0i, a0l, b0, p01s);
    mean40i<<<B, 128, 0, stream>>>(h1a, p12);
    // warm chain weights (10 matrices = 640KB = 160 blocks x 256 x 16B) into L3/L2
    warm_k<<<160, 256, 0, stream>>>((const uint4*)(wt + (size_t)9 * 32768),
                                    (unsigned*)cursor);
    // h2 chain: D2 -> h2d; n2 = relu(h2@A2 + p12@U1 + ib2); enc2 x2 -> h2ai/h2f
    fused_chain<false><<<1, 512, 0, stream>>>(
        h2ai, p12, nullptr, nullptr,
        wt + (size_t)14 * 32768, wt + (size_t)15 * 32768, wt + (size_t)16 * 32768,
        wt + (size_t)17 * 32768, wt + (size_t)18 * 32768,
        ib2, enc2_b, enc2_b + H, h2d, h2ai, h2f, B);
    // h1 chain: D1 -> h1d; n1 = relu(h1@A1 + (p01s*rdeg1)@U0 + h2d[r/F] + ib1); enc1 x2
    fused_chain<true><<<16, 512, 0, stream>>>(
        h1a, p01s, rdeg1, h2d,
        wt + (size_t)9 * 32768, wt + (size_t)10 * 32768, wt + (size_t)11 * 32768,
        wt + (size_t)12 * 32768, wt + (size_t)13 * 32768,
        ib1, enc1_b, enc1_b + H, h1d, h1a, nullptr, TF);
    // n0 = relu(h0@A0 + h1d[assign0] + ib0)   (in-place, MFMA)
    mgemm<128, false, true><<<MG, 256, 0, stream>>>(
        h0i, wt + (size_t)8 * 32768, nullptr, nullptr, h1d, assign0, ib0, h0i, N);
    encEdgeM(4, 6, enc0_b);
  }

  pool_g0<<<400, 128, 0, stream>>>(h0i, b0, g0s);
  mean40i<<<B, 128, 0, stream>>>(h1a, g1);
  head_k<<<B, 128, 0, stream>>>(g0s, rdegB, g1, h2f, H1w, hb1, H2w, hb2, out);
}

// Round 15
// 831.109 us; speedup vs baseline: 1.2350x; 1.1135x over previous
//
#include <hip/hip_runtime.h>

namespace {

constexpr int N   = 100000;
constexpr int E   = 600000;
constexpr int B   = 50;
constexpr int F   = 40;
constexpr int TF  = B * F;     // 2000
constexpr int D0  = 64;
constexpr int H   = 128;
constexpr int C   = 2;

typedef __attribute__((ext_vector_type(8))) __bf16 bf16x8;
typedef __attribute__((ext_vector_type(8))) unsigned short us8;
typedef __attribute__((ext_vector_type(4))) float f32x4;

__device__ __forceinline__ float asf(unsigned u) { return __uint_as_float(u); }
// round-to-nearest-even fp32 -> bf16 (returns low 16 bits)
__device__ __forceinline__ unsigned bfr(float x) {
  unsigned u = __float_as_uint(x);
  return (u + 0x7FFFu + ((u >> 16) & 1u)) >> 16;
}

// async global->LDS: 16B per lane, LDS dest = uniform base + lane*16,
// global src = per-lane address. Counts in vmcnt (drained by __syncthreads).
__device__ __forceinline__ void glds16(const void* g, void* l) {
  __builtin_amdgcn_global_load_lds(
      (const __attribute__((address_space(1))) unsigned*)g,
      (__attribute__((address_space(3))) unsigned*)l, 16, 0, 0);
}

// ---------------- histograms / CSR build ----------------

__global__ void hist_edges(const int* __restrict__ dst, int* __restrict__ deg) {
  int e = blockIdx.x * 256 + threadIdx.x;
  if (e < E) atomicAdd(&deg[dst[e]], 1);
}

__global__ void hist_nodes(const int* __restrict__ b0, const int* __restrict__ a0l,
                           int* __restrict__ cnt1, int* __restrict__ assign0) {
  __shared__ int lh[TF];
  int t = threadIdx.x;
  for (int j = t; j < TF; j += 256) lh[j] = 0;
  __syncthreads();
  int i = blockIdx.x * 256 + t;
  if (i < N) {
    int g = b0[i];
    int a = g * F + a0l[i];
    assign0[i] = a;
    atomicAdd(&lh[a], 1);
  }
  __syncthreads();
  for (int j = t; j < TF; j += 256) {
    int c = lh[j];
    if (c) atomicAdd(&cnt1[j], c);
  }
}

__global__ void scan1(const int* __restrict__ cnt, int* __restrict__ offs,
                      int* __restrict__ part) {
  __shared__ int lds[256];
  int t = threadIdx.x;
  int base = blockIdx.x * 1024 + t * 4;
  int v[4];
#pragma unroll
  for (int j = 0; j < 4; ++j) v[j] = (base + j < N) ? cnt[base + j] : 0;
  int s = v[0] + v[1] + v[2] + v[3];
  lds[t] = s;
  __syncthreads();
  for (int off = 1; off < 256; off <<= 1) {
    int x = (t >= off) ? lds[t - off] : 0;
    __syncthreads();
    lds[t] += x;
    __syncthreads();
  }
  int ex = lds[t] - s;
  if (t == 255) part[blockIdx.x] = lds[255];
  int run = ex;
#pragma unroll
  for (int j = 0; j < 4; ++j) {
    if (base + j < N) offs[base + j] = run;
    run += v[j];
  }
}

__global__ void scan2(const int* __restrict__ part, int* __restrict__ partEx, int nb) {
  __shared__ int lds[128];
  int t = threadIdx.x;
  int s = (t < nb) ? part[t] : 0;
  lds[t] = s;
  __syncthreads();
  for (int off = 1; off < 128; off <<= 1) {
    int x = (t >= off) ? lds[t - off] : 0;
    __syncthreads();
    lds[t] += x;
    __syncthreads();
  }
  partEx[t] = lds[t] - s;
}

__global__ void scan3(int* __restrict__ offs, const int* __restrict__ partEx,
                      const int* __restrict__ deg, float* __restrict__ rdeg,
                      const int* __restrict__ cnt1, float* __restrict__ rdeg1,
                      float* __restrict__ rdegB) {
  int i = blockIdx.x * 256 + threadIdx.x;
  if (i < N) {
    offs[i] += partEx[i >> 10];
    rdeg[i] = 1.0f / fmaxf((float)deg[i], 1.0f);
    if (i == 0) offs[N] = E;
    if (i < TF) rdeg1[i] = 1.0f / fmaxf((float)cnt1[i], 1.0f);
    if (i < B) {
      int s = 0;
      for (int f = 0; f < F; ++f) s += cnt1[i * F + f];
      rdegB[i] = 1.0f / fmaxf((float)s, 1.0f);
    }
  }
}

__global__ void scatter_k(const int* __restrict__ src, const int* __restrict__ dst,
                          const int* __restrict__ offs, int* __restrict__ cursor,
                          int* __restrict__ srcS) {
  int e = blockIdx.x * 256 + threadIdx.x;
  if (e < E) {
    int d = dst[e];
    int pos = offs[d] + atomicAdd(&cursor[d], 1);
    srcS[pos] = src[e];
  }
}

// ---- weight conversion: fp32 [k][c] -> split-bf16, slice-major, col-permuted ----
struct WPtrs { const float* w[19]; };
__global__ void conv_w(WPtrs wp, unsigned short* __restrict__ wt) {
  int i = blockIdx.x >> 6;                         // matrix index
  int e = (blockIdx.x & 63) * 256 + threadIdx.x;   // 0..16383
  int k = e >> 7, c = e & 127;
  float x = wp.w[i][e];
  unsigned h = bfr(x);
  unsigned l = bfr(x - asf(h << 16));
  int cs = (c & 7) * 16 + (c >> 3);
  size_t o = (size_t)i * 32768 + (k >> 5) * 4096 + cs * 32 + (k & 31);
  wt[o] = (unsigned short)h;
  wt[o + 16384] = (unsigned short)l;
}

// Wp: fp32 [64][128] -> hi (2 slices * 4096) + lo at +8192
__global__ void conv_wp(const float* __restrict__ w, unsigned short* __restrict__ wt) {
  int e = blockIdx.x * 256 + threadIdx.x;  // 0..8191
  int k = e >> 7, c = e & 127;
  float x = w[e];
  unsigned h = bfr(x);
  unsigned l = bfr(x - asf(h << 16));
  int cs = (c & 7) * 16 + (c >> 3);
  size_t o = (size_t)(k >> 5) * 4096 + cs * 32 + (k & 31);
  wt[o] = (unsigned short)h;
  wt[o + 8192] = (unsigned short)l;
}

// x0 fp32 [N][64] -> interleaved rows [hi64 | lo64] (stride 128 shorts)
__global__ void x0split(const float* __restrict__ x0, unsigned short* __restrict__ xs) {
  int i = blockIdx.x * 256 + threadIdx.x;  // elem index
  if (i >= N * D0) return;
  int row = i >> 6, c = i & 63;
  float x = x0[i];
  unsigned h = bfr(x);
  unsigned l = bfr(x - asf(h << 16));
  xs[(size_t)row * 128 + c] = (unsigned short)h;
  xs[(size_t)row * 128 + 64 + c] = (unsigned short)l;
}

// ---- L3/L2 warm: touch the chain weight region so chain misses are cheap ----
__global__ void warm_k(const uint4* __restrict__ w, unsigned* __restrict__ dummy) {
  uint4 v = w[blockIdx.x * 256 + threadIdx.x];
  unsigned x = v.x ^ v.y ^ v.z ^ v.w;
  if (x == 0xDEADBEEFu) dummy[0] = 1u;  // keeps loads live; deterministic
}

// ---------------- edge aggregation: hi(bf16)-plane-only gather ----------------
// Reads only the first 256B (hi plane) of each src row: halves the gather
// traffic vs R14 (which hit the ~4.5 B/cy/CU per-CU miss wall at 146MB FETCH).
// Output = bf16 mean written to hi plane of Out only (mgemm BLO=false skips lo).
// Lane covers 2 cols via one u32; wave reads one contiguous 256B line set/edge.
__global__ void agg_k(const unsigned short* __restrict__ Act,
                      const int* __restrict__ offs, const int* __restrict__ srcS,
                      const float* __restrict__ rdeg, unsigned short* __restrict__ Out) {
  int wid = blockIdx.x * 4 + (threadIdx.x >> 6);
  int lane = threadIdx.x & 63;
  if (wid >= N) return;
  int o0 = offs[wid], o1 = offs[wid + 1];
  float s0 = 0.f, s1 = 0.f;
  int e = o0;
  for (; e + 3 < o1; e += 4) {
    unsigned v0 = *(const unsigned*)(Act + (size_t)srcS[e] * 256 + lane * 2);
    unsigned v1 = *(const unsigned*)(Act + (size_t)srcS[e + 1] * 256 + lane * 2);
    unsigned v2 = *(const unsigned*)(Act + (size_t)srcS[e + 2] * 256 + lane * 2);
    unsigned v3 = *(const unsigned*)(Act + (size_t)srcS[e + 3] * 256 + lane * 2);
    s0 += asf(v0 << 16) + asf(v1 << 16) + asf(v2 << 16) + asf(v3 << 16);
    s1 += asf(v0 & 0xFFFF0000u) + asf(v1 & 0xFFFF0000u) +
          asf(v2 & 0xFFFF0000u) + asf(v3 & 0xFFFF0000u);
  }
  for (; e < o1; ++e) {
    unsigned v0 = *(const unsigned*)(Act + (size_t)srcS[e] * 256 + lane * 2);
    s0 += asf(v0 << 16);
    s1 += asf(v0 & 0xFFFF0000u);
  }
  float sc = rdeg[wid];
  unsigned h0 = bfr(s0 * sc), h1 = bfr(s1 * sc);
  *(unsigned*)(Out + (size_t)wid * 256 + lane * 2) = h0 | (h1 << 16);
}

// ---------------- split-bf16 MFMA GEMM, LDS-staged weights (N-row layers) ----
// BLO=false: the B (Agg) operand has no lo plane -- skip its loads and the
// al*wh MFMA (numerically identical to feeding zeros).
template <int KD, bool AGG, bool GATH, bool BLO = true>
__global__ __launch_bounds__(256, 3)
void mgemm(const unsigned short* __restrict__ Ai, const unsigned short* __restrict__ W1,
           const unsigned short* __restrict__ Bi, const unsigned short* __restrict__ W2,
           const float* __restrict__ Gt, const int* __restrict__ Gidx,
           const float* __restrict__ bias, unsigned short* __restrict__ Oi, int n) {
  __shared__ unsigned short wlds[2][2][4096];  // [buf][hi/lo][slice]
  constexpr int KS = KD / 32;
  constexpr int NS = (AGG ? 2 : 1) * KS;
  constexpr int KLO = KD * 128;
  constexpr int ARS = 2 * KD;
  const int t = threadIdx.x, wv = t >> 6, ln = t & 63;
  const int row0 = blockIdx.x * 128 + wv * 32;
  const int lm = ln & 15, kg = ln >> 4;
  int ar0 = row0 + lm, ar1 = row0 + 16 + lm;
  if (ar0 >= n) ar0 = 0;
  if (ar1 >= n) ar1 = 0;
  const size_t a0off = (size_t)ar0 * ARS, a1off = (size_t)ar1 * ARS;

  f32x4 acc[2][8];
#pragma unroll
  for (int i = 0; i < 2; ++i)
#pragma unroll
    for (int j = 0; j < 8; ++j) acc[i][j] = (f32x4){0.f, 0.f, 0.f, 0.f};

  uint4 sA, sB, sC, sD;
  bf16x8 a0h[2], a0l[2], a1h[2], a1l[2];

  auto ldst = [&](int s) {
    const unsigned short* W = (AGG && s >= KS) ? W2 : W1;
    const unsigned short* ph = W + (s & (KS - 1)) * 4096;
    sA = *(const uint4*)(ph + t * 8);
    sB = *(const uint4*)(ph + 2048 + t * 8);
    sC = *(const uint4*)(ph + KLO + t * 8);
    sD = *(const uint4*)(ph + KLO + 2048 + t * 8);
  };
  auto wrst = [&](int buf) {
    *(uint4*)&wlds[buf][0][t * 8] = sA;
    *(uint4*)&wlds[buf][0][2048 + t * 8] = sB;
    *(uint4*)&wlds[buf][1][t * 8] = sC;
    *(uint4*)&wlds[buf][1][2048 + t * 8] = sD;
  };
  auto loadA = [&](int s, int w) {
    const bool bpass = AGG && (s >= KS);
    const unsigned short* X = bpass ? Bi : Ai;
    int kk = (s & (KS - 1)) * 32 + kg * 8;
    a0h[w] = *(const bf16x8*)(X + a0off + kk);
    a1h[w] = *(const bf16x8*)(X + a1off + kk);
    if (!bpass || BLO) {
      a0l[w] = *(const bf16x8*)(X + a0off + KD + kk);
      a1l[w] = *(const bf16x8*)(X + a1off + KD + kk);
    }
  };

  ldst(0); wrst(0); loadA(0, 0);
  __syncthreads();

#pragma unroll
  for (int s = 0; s < NS; ++s) {
    const int buf = s & 1;
    const bool uselo = !(AGG && (s >= KS)) || BLO;
    if (s + 1 < NS) { ldst(s + 1); loadA(s + 1, buf ^ 1); }
#pragma unroll
    for (int nf = 0; nf < 8; ++nf) {
      const int wo = (nf * 16 + lm) * 32 + kg * 8;
      bf16x8 wh = *(const bf16x8*)&wlds[buf][0][wo];
      bf16x8 wl = *(const bf16x8*)&wlds[buf][1][wo];
      acc[0][nf] = __builtin_amdgcn_mfma_f32_16x16x32_bf16(a0h[buf], wh, acc[0][nf], 0, 0, 0);
      acc[0][nf] = __builtin_amdgcn_mfma_f32_16x16x32_bf16(a0h[buf], wl, acc[0][nf], 0, 0, 0);
      if (uselo)
        acc[0][nf] = __builtin_amdgcn_mfma_f32_16x16x32_bf16(a0l[buf], wh, acc[0][nf], 0, 0, 0);
      acc[1][nf] = __builtin_amdgcn_mfma_f32_16x16x32_bf16(a1h[buf], wh, acc[1][nf], 0, 0, 0);
      acc[1][nf] = __builtin_amdgcn_mfma_f32_16x16x32_bf16(a1h[buf], wl, acc[1][nf], 0, 0, 0);
      if (uselo)
        acc[1][nf] = __builtin_amdgcn_mfma_f32_16x16x32_bf16(a1l[buf], wh, acc[1][nf], 0, 0, 0);
    }
    if (s + 1 < NS) wrst(buf ^ 1);
    __syncthreads();
  }

  float4 bq0 = *(const float4*)&bias[lm * 8];
  float4 bq1 = *(const float4*)&bias[lm * 8 + 4];
  float bsv[8] = {bq0.x, bq0.y, bq0.z, bq0.w, bq1.x, bq1.y, bq1.z, bq1.w};
#pragma unroll
  for (int mf = 0; mf < 2; ++mf)
#pragma unroll
    for (int rr = 0; rr < 4; ++rr) {
      int row = row0 + mf * 16 + kg * 4 + rr;
      if (row >= n) continue;
      float gvv[8];
      if (GATH) {
        const float* grow = Gt + (size_t)Gidx[row] * H + lm * 8;
        float4 g0 = *(const float4*)grow;
        float4 g1 = *(const float4*)(grow + 4);
        gvv[0] = g0.x; gvv[1] = g0.y; gvv[2] = g0.z; gvv[3] = g0.w;
        gvv[4] = g1.x; gvv[5] = g1.y; gvv[6] = g1.z; gvv[7] = g1.w;
      }
      us8 hv, lv;
#pragma unroll
      for (int nf = 0; nf < 8; ++nf) {
        float v = acc[mf][nf][rr] + bsv[nf];
        if (GATH) v += gvv[nf];
        v = fmaxf(v, 0.f);
        unsigned h = bfr(v);
        hv[nf] = (unsigned short)h;
        lv[nf] = (unsigned short)bfr(v - asf(h << 16));
      }
      *(us8*)(Oi + (size_t)row * 256 + lm * 8) = hv;
      *(us8*)(Oi + (size_t)row * 256 + 128 + lm * 8) = lv;
    }
}

// ---------------- fused small-scale chain: 512 threads, 8 waves x 16 rows ----
template <bool ISH1>
__global__ __launch_bounds__(512)
void fused_chain(const unsigned short* __restrict__ Ai,
                 const float* __restrict__ P, const float* __restrict__ pscale,
                 const float* __restrict__ Gt,
                 const unsigned short* __restrict__ Wd,
                 const unsigned short* __restrict__ Wa,
                 const unsigned short* __restrict__ Wu,
                 const unsigned short* __restrict__ We0,
                 const unsigned short* __restrict__ We1,
                 const float* __restrict__ bn, const float* __restrict__ be0,
                 const float* __restrict__ be1,
                 float* __restrict__ outD, unsigned short* __restrict__ Ao,
                 float* __restrict__ outF, int n) {
  __shared__ unsigned short act[128 * 256];   // 64KB: 128 interleaved rows
  __shared__ unsigned short wl[2][16384];     // 2 x 32KB halves (hi|lo)
  const int t = threadIdx.x, wv = t >> 6, ln = t & 63;
  const int lm = ln & 15, kg = ln >> 4;
  const int rbase = blockIdx.x * 128 + wv * 16;  // wave owns 16 rows
  const int lbase = wv * 16;
  int ar = rbase + lm;
  if (ar >= n) ar = 0;

  const unsigned short* mats[5] = {Wd, Wa, Wu, We0, We1};

  f32x4 acc[8];
  auto zacc = [&]() {
#pragma unroll
    for (int nf = 0; nf < 8; ++nf) acc[nf] = (f32x4){0.f, 0.f, 0.f, 0.f};
  };

  // half s into wl[b]: per wave 2 glds hi + 2 glds lo (512 shorts each)
  auto ldwl = [&](int s, int b) {
    const unsigned short* hi = mats[s >> 1] + (s & 1) * 8192;
    const unsigned short* lo = mats[s >> 1] + 16384 + (s & 1) * 8192;
    const int wo = wv * 1024;
    const int lo8 = ln * 8;
#pragma unroll
    for (int j = 0; j < 2; ++j) {
      glds16(hi + wo + j * 512 + lo8, &wl[b][wo + j * 512]);
      glds16(lo + wo + j * 512 + lo8, &wl[b][8192 + wo + j * 512]);
    }
  };
  // preload this block's 128 Ai rows (linear 64KB): 8 glds/wave
  auto ldact = [&]() {
    const unsigned short* src = Ai + (size_t)blockIdx.x * (128 * 256);
    const int base = wv * 4096;
    const int lo8 = ln * 8;
#pragma unroll
    for (int j = 0; j < 8; ++j)
      glds16(src + base + j * 512 + lo8, &act[base + j * 512]);
  };

  auto donf = [&](int b, int ksl, bf16x8 ah, bf16x8 al) {
#pragma unroll
    for (int nf = 0; nf < 8; ++nf) {
      const int wo = ksl * 4096 + (nf * 16 + lm) * 32 + kg * 8;
      bf16x8 wh = *(const bf16x8*)&wl[b][wo];
      bf16x8 wq = *(const bf16x8*)&wl[b][8192 + wo];
      acc[nf] = __builtin_amdgcn_mfma_f32_16x16x32_bf16(ah, wh, acc[nf], 0, 0, 0);
      acc[nf] = __builtin_amdgcn_mfma_f32_16x16x32_bf16(ah, wq, acc[nf], 0, 0, 0);
      acc[nf] = __builtin_amdgcn_mfma_f32_16x16x32_bf16(al, wh, acc[nf], 0, 0, 0);
    }
  };

  auto epiAct = [&](const float* bias, bool gath) {
    float4 b0 = *(const float4*)&bias[lm * 8];
    float4 b1 = *(const float4*)&bias[lm * 8 + 4];
    float bv[8] = {b0.x, b0.y, b0.z, b0.w, b1.x, b1.y, b1.z, b1.w};
#pragma unroll
    for (int rr = 0; rr < 4; ++rr) {
      int rl = lbase + kg * 4 + rr;
      int rg = rbase + kg * 4 + rr;
      float gv[8] = {0.f, 0.f, 0.f, 0.f, 0.f, 0.f, 0.f, 0.f};
      if (ISH1 && gath && rg < n) {
        const float* grow = Gt + (size_t)(rg / F) * H + lm * 8;
        float4 g0 = *(const float4*)grow;
        float4 g1 = *(const float4*)(grow + 4);
        gv[0] = g0.x; gv[1] = g0.y; gv[2] = g0.z; gv[3] = g0.w;
        gv[4] = g1.x; gv[5] = g1.y; gv[6] = g1.z; gv[7] = g1.w;
      }
      us8 hv, lv;
#pragma unroll
      for (int nf = 0; nf < 8; ++nf) {
        float v = acc[nf][rr] + bv[nf] + gv[nf];
        v = fmaxf(v, 0.f);
        unsigned h = bfr(v);
        hv[nf] = (unsigned short)h;
        lv[nf] = (unsigned short)bfr(v - asf(h << 16));
      }
      *(us8*)&act[rl * 256 + lm * 8] = hv;
      *(us8*)&act[rl * 256 + 128 + lm * 8] = lv;
    }
  };

  // ---- pipeline prologue: one exposed drain ----
  ldact();
  ldwl(0, 0);
  __syncthreads();           // drains act preload + half 0
  ldwl(1, 1);                // half 1 in flight across stage-0 MFMA

#pragma unroll
  for (int s = 0; s < 10; ++s) {
    const int b = s & 1;
    if (s == 0 || s == 2 || s == 6 || s == 8) zacc();
    const int m = s >> 1;
#pragma unroll
    for (int ksl = 0; ksl < 2; ++ksl) {
      const int ks = (s & 1) * 2 + ksl;
      bf16x8 ah, al;
      if (m == 2) {           // Wu pass: A from fp32 P (optionally scaled)
        const float* pp = P + (size_t)ar * H + ks * 32 + kg * 8;
        float4 f0 = *(const float4*)pp;
        float4 f1 = *(const float4*)(pp + 4);
        if (ISH1) {
          float sc = pscale[ar];
          f0.x *= sc; f0.y *= sc; f0.z *= sc; f0.w *= sc;
          f1.x *= sc; f1.y *= sc; f1.z *= sc; f1.w *= sc;
        }
        float fv[8] = {f0.x, f0.y, f0.z, f0.w, f1.x, f1.y, f1.z, f1.w};
        us8 h8, l8;
#pragma unroll
        for (int j = 0; j < 8; ++j) {
          unsigned h = bfr(fv[j]);
          h8[j] = (unsigned short)h;
          l8[j] = (unsigned short)bfr(fv[j] - asf(h << 16));
        }
        ah = __builtin_bit_cast(bf16x8, h8);
        al = __builtin_bit_cast(bf16x8, l8);
      } else {                // Wd/Wa (preloaded Ai) and We0/We1: A from act
        int rl = lbase + lm;
        ah = *(const bf16x8*)&act[rl * 256 + ks * 32 + kg * 8];
        al = *(const bf16x8*)&act[rl * 256 + 128 + ks * 32 + kg * 8];
      }
      donf(b, ksl, ah, al);
    }
    // ---- epilogues (acc-only; act rows are wave-private) ----
    if (s == 1) {
#pragma unroll
      for (int rr = 0; rr < 4; ++rr) {
        int rg = rbase + kg * 4 + rr;
        if (rg < n) {
          float* op = outD + (size_t)rg * H + lm * 8;
          *(float4*)op = make_float4(acc[0][rr], acc[1][rr], acc[2][rr], acc[3][rr]);
          *(float4*)(op + 4) = make_float4(acc[4][rr], acc[5][rr], acc[6][rr], acc[7][rr]);
        }
      }
    }
    if (s == 5) epiAct(bn, true);
    if (s == 7) epiAct(be0, false);
    if (s == 9) {
      float4 b0 = *(const float4*)&be1[lm * 8];
      float4 b1 = *(const float4*)&be1[lm * 8 + 4];
      float bv[8] = {b0.x, b0.y, b0.z, b0.w, b1.x, b1.y, b1.z, b1.w};
#pragma unroll
      for (int rr = 0; rr < 4; ++rr) {
        int rg = rbase + kg * 4 + rr;
        if (rg >= n) continue;
        us8 hv, lv;
        float fv[8];
#pragma unroll
        for (int nf = 0; nf < 8; ++nf) {
          float v = fmaxf(acc[nf][rr] + bv[nf], 0.f);
          fv[nf] = v;
          unsigned h = bfr(v);
          hv[nf] = (unsigned short)h;
          lv[nf] = (unsigned short)bfr(v - asf(h << 16));
        }
        *(us8*)(Ao + (size_t)rg * 256 + lm * 8) = hv;
        *(us8*)(Ao + (size_t)rg * 256 + 128 + lm * 8) = lv;
        if (outF) {
          float* op = outF + (size_t)rg * H + lm * 8;
          *(float4*)op = make_float4(fv[0], fv[1], fv[2], fv[3]);
          *(float4*)(op + 4) = make_float4(fv[4], fv[5], fv[6], fv[7]);
        }
      }
    }
    if (s + 1 < 10) {
      __syncthreads();            // all waves done with wl[b]; drains s+1 loads
      if (s + 2 < 10) ldwl(s + 2, b);  // refill the buffer just released
    }
  }
}

// ---------------- initial h1/h2: enc-plain on zeros => identical rows ----------------
__global__ void init_bcast(const float* __restrict__ Ws1, const float* __restrict__ b1,
                           const float* __restrict__ Ws2, const float* __restrict__ b2,
                           unsigned short* __restrict__ h1i, unsigned short* __restrict__ h2i) {
  __shared__ float z0[128];
  int t = threadIdx.x;  // 128
  bool ish2 = (blockIdx.x == 20);
  const float* W = ish2 ? Ws2 : Ws1;
  const float* bb = ish2 ? b2 : b1;
  z0[t] = fmaxf(bb[t], 0.f);
  __syncthreads();
  float s = bb[128 + t];
  for (int k = 0; k < 128; ++k) s += z0[k] * W[16384 + k * 128 + t];
  s = fmaxf(s, 0.f);
  unsigned h = bfr(s);
  unsigned l = bfr(s - asf(h << 16));
  if (ish2) {
    for (int r = 0; r < B; ++r) {
      h2i[(size_t)r * 256 + t] = (unsigned short)h;
      h2i[(size_t)r * 256 + 128 + t] = (unsigned short)l;
    }
  } else {
    int r0 = blockIdx.x * 100;
    for (int r = 0; r < 100; ++r) {
      h1i[(size_t)(r0 + r) * 256 + t] = (unsigned short)h;
      h1i[(size_t)(r0 + r) * 256 + 128 + t] = (unsigned short)l;
    }
  }
}

// ---------------- pooling (interleaved rows) ----------------
__global__ void pool_p01(const unsigned short* __restrict__ Act,
                         const int* __restrict__ a0l, const int* __restrict__ b0,
                         float* __restrict__ p01s) {
  __shared__ float acc[F][H];
  int t = threadIdx.x;  // 128
#pragma unroll
  for (int f = 0; f < F; ++f) acc[f][t] = 0.f;
  int rowbase = blockIdx.x * 250;
  for (int i = 0; i < 250; ++i) {
    size_t r = (size_t)(rowbase + i) * 256 + t;
    acc[a0l[rowbase + i]][t] += asf((unsigned)Act[r] << 16) + asf((unsigned)Act[r + 128] << 16);
  }
  int g = b0[rowbase];
#pragma unroll
  for (int f = 0; f < F; ++f)
    atomicAdd(&p01s[((size_t)(g * F + f)) * H + t], acc[f][t]);
}

__global__ void pool_g0(const unsigned short* __restrict__ Act,
                        const int* __restrict__ b0, float* __restrict__ g0s) {
  int t = threadIdx.x;
  int rowbase = blockIdx.x * 250;
  float a = 0.f;
  for (int i = 0; i < 250; ++i) {
    size_t r = (size_t)(rowbase + i) * 256 + t;
    a += asf((unsigned)Act[r] << 16) + asf((unsigned)Act[r + 128] << 16);
  }
  atomicAdd(&g0s[(size_t)b0[rowbase] * H + t], a);
}

// mean over F contiguous interleaved-bf16 rows per graph -> fp32
__global__ void mean40i(const unsigned short* __restrict__ Act, float* __restrict__ outp) {
  int t = threadIdx.x, g = blockIdx.x;
  float a = 0.f;
  for (int i = 0; i < F; ++i) {
    size_t r = (size_t)(g * F + i) * 256 + t;
    a += asf((unsigned)Act[r] << 16) + asf((unsigned)Act[r + 128] << 16);
  }
  outp[(size_t)g * H + t] = a * (1.0f / F);
}

// ---------------- head MLP ----------------
__global__ void head_k(const float* __restrict__ g0s, const float* __restrict__ rdegB,
                       const float* __restrict__ g1, const float* __restrict__ h2,
                       const float* __restrict__ W1h, const float* __restrict__ b1h,
                       const float* __restrict__ W2h, const float* __restrict__ b2h,
                       float* __restrict__ out) {
  __shared__ float gv[3 * H];
  __shared__ float z[H];
  int b = blockIdx.x, t = threadIdx.x;
  gv[t] = g0s[(size_t)b * H + t] * rdegB[b];
  gv[H + t] = g1[(size_t)b * H + t];
  gv[2 * H + t] = h2[(size_t)b * H + t];
  __syncthreads();
  float s = b1h[t];
  for (int k = 0; k < 3 * H; ++k) s += gv[k] * W1h[k * H + t];
  z[t] = fmaxf(s, 0.f);
  __syncthreads();
  if (t < C) {
    float o = b2h[t];
    for (int k = 0; k < H; ++k) o += z[k] * W2h[k * C + t];
    out[b * C + t] = o;
  }
}

}  // namespace

extern "C" void kernel_launch(void* const* d_in, const int* in_sizes, int n_in,
                              void* d_out, int out_size, void* d_ws, size_t ws_size,
                              hipStream_t stream) {
  (void)in_sizes; (void)n_in; (void)out_size; (void)ws_size;
  const float* x0   = (const float*)d_in[0];
  const int*   ei   = (const int*)d_in[1];
  const int*   src  = ei;
  const int*   dst  = ei + E;
  const int*   b0   = (const int*)d_in[2];
  const int*   a0l  = (const int*)d_in[3];
  const float* Wp   = (const float*)d_in[4];
  const float* bp   = (const float*)d_in[5];
  const float* e0in_Ws = (const float*)d_in[6];
  const float* e0in_Wn = (const float*)d_in[7];
  const float* e0in_b  = (const float*)d_in[8];
  const float* enc0_Ws = (const float*)d_in[9];
  const float* enc0_Wn = (const float*)d_in[10];
  const float* enc0_b  = (const float*)d_in[11];
  const float* e1in_Ws = (const float*)d_in[12];
  const float* e1in_b  = (const float*)d_in[13];
  const float* e2in_Ws = (const float*)d_in[14];
  const float* e2in_b  = (const float*)d_in[15];
  const float* enc1_Ws = (const float*)d_in[16];
  const float* enc1_b  = (const float*)d_in[17];
  const float* enc2_Ws = (const float*)d_in[18];
  const float* enc2_b  = (const float*)d_in[19];
  const float* A0 = (const float*)d_in[20];
  const float* A1 = (const float*)d_in[21];
  const float* A2 = (const float*)d_in[22];
  const float* U0 = (const float*)d_in[23];
  const float* U1 = (const float*)d_in[24];
  const float* D1 = (const float*)d_in[25];
  const float* D2 = (const float*)d_in[26];
  const float* ib0 = (const float*)d_in[27];
  const float* ib1 = (const float*)d_in[28];
  const float* ib2 = (const float*)d_in[29];
  const float* H1w = (const float*)d_in[30];
  const float* hb1 = (const float*)d_in[31];
  const float* H2w = (const float*)d_in[32];
  const float* hb2 = (const float*)d_in[33];
  float* out = (float*)d_out;

  // ---- workspace carve ----
  char* p = (char*)d_ws;
  auto carve = [&](size_t bytes) {
    char* r = p;
    p += (bytes + 255) & ~(size_t)255;
    return r;
  };
  char* z0 = p;  // zeroed-every-call region
  int*   deg    = (int*)carve((size_t)N * 4);
  int*   cursor = (int*)carve((size_t)N * 4);
  int*   cnt1   = (int*)carve((size_t)TF * 4);
  float* g0s    = (float*)carve((size_t)B * H * 4);
  size_t zbytes = (size_t)(p - z0);
  unsigned short* h0i  = (unsigned short*)carve((size_t)N * 256 * 2);
  unsigned short* aggi = (unsigned short*)carve((size_t)N * 256 * 2);
  unsigned short* h1a  = (unsigned short*)carve((size_t)2048 * 256 * 2);  // padded to 16 blocks x 128 rows
  unsigned short* h2ai = (unsigned short*)carve((size_t)128 * 256 * 2);   // padded to 128 rows
  float* h1d  = (float*)carve((size_t)TF * H * 4);
  float* h2d  = (float*)carve((size_t)64 * H * 4);
  float* h2f  = (float*)carve((size_t)B * H * 4);
  float* p01s = (float*)carve((size_t)TF * H * 4);
  float* p12  = (float*)carve((size_t)64 * H * 4);
  float* g1   = (float*)carve((size_t)B * H * 4);
  float* rdeg = (float*)carve((size_t)N * 4);
  float* rdeg1 = (float*)carve((size_t)TF * 4);
  float* rdegB = (float*)carve(64 * 4);
  int* offs    = (int*)carve((size_t)(N + 64) * 4);
  int* srcS    = (int*)carve((size_t)E * 4);
  int* part    = (int*)carve(128 * 4);
  int* partEx  = (int*)carve(128 * 4);
  int* assign0 = (int*)carve((size_t)N * 4);
  unsigned short* wt  = (unsigned short*)carve((size_t)19 * 32768 * 2);
  unsigned short* wt9 = (unsigned short*)carve((size_t)16384 * 2);
  unsigned short* xs  = aggi;  // alias: x0-split used only before first agg_k

  const int HH = H * H;
  const int MG = (N + 127) / 128;  // 782

  // ---- CSR + histograms + weight/x0 split ----
  hipMemsetAsync(z0, 0, zbytes, stream);
  hist_edges<<<(E + 255) / 256, 256, 0, stream>>>(dst, deg);
  hist_nodes<<<(N + 255) / 256, 256, 0, stream>>>(b0, a0l, cnt1, assign0);
  const int nb1 = (N + 1023) / 1024;
  scan1<<<nb1, 256, 0, stream>>>(deg, offs, part);
  scan2<<<1, 128, 0, stream>>>(part, partEx, nb1);
  scan3<<<(N + 255) / 256, 256, 0, stream>>>(offs, partEx, deg, rdeg, cnt1, rdeg1,
                                             rdegB);
  scatter_k<<<(E + 255) / 256, 256, 0, stream>>>(src, dst, offs, cursor, srcS);
  {
    WPtrs wp;
    wp.w[0] = e0in_Ws;      wp.w[1] = e0in_Ws + HH;
    wp.w[2] = e0in_Wn;      wp.w[3] = e0in_Wn + HH;
    wp.w[4] = enc0_Ws;      wp.w[5] = enc0_Ws + HH;
    wp.w[6] = enc0_Wn;      wp.w[7] = enc0_Wn + HH;
    wp.w[8] = A0;
    wp.w[9] = D1;           wp.w[10] = A1;
    wp.w[11] = U0;          wp.w[12] = enc1_Ws;   wp.w[13] = enc1_Ws + HH;
    wp.w[14] = D2;          wp.w[15] = A2;
    wp.w[16] = U1;          wp.w[17] = enc2_Ws;   wp.w[18] = enc2_Ws + HH;
    conv_w<<<19 * 64, 256, 0, stream>>>(wp, wt);
  }
  conv_wp<<<32, 256, 0, stream>>>(Wp, wt9);
  x0split<<<(N * D0 + 255) / 256, 256, 0, stream>>>(x0, xs);

  // ---- input projection (MFMA, K=64) ----
  mgemm<64, false, false><<<MG, 256, 0, stream>>>(
      xs, wt9, nullptr, nullptr, nullptr, nullptr, bp, h0i, N);

  auto encEdgeM = [&](int wsIdx, int wnIdx, const float* barr) {
    for (int l = 0; l < 2; ++l) {
      agg_k<<<N / 4, 256, 0, stream>>>(h0i, offs, srcS, rdeg, aggi);
      mgemm<128, true, false, false><<<MG, 256, 0, stream>>>(
          h0i, wt + (size_t)(wsIdx + l) * 32768, aggi,
          wt + (size_t)(wnIdx + l) * 32768, nullptr, nullptr, barr + l * H, h0i, N);
    }
  };

  encEdgeM(0, 2, e0in_b);
  init_bcast<<<21, 128, 0, stream>>>(e1in_Ws, e1in_b, e2in_Ws, e2in_b, h1a, h2ai);

  for (int step = 0; step < 2; ++step) {
    hipMemsetAsync(p01s, 0, (size_t)TF * H * 4, stream);
    pool_p01<<<400, 128, 0, stream>>>(h0i, a0l, b0, p01s);
    mean40i<<<B, 128, 0, stream>>>(h1a, p12);
    // warm chain weights (10 matrices = 640KB = 160 blocks x 256 x 16B) into L3/L2
    warm_k<<<160, 256, 0, stream>>>((const uint4*)(wt + (size_t)9 * 32768),
                                    (unsigned*)cursor);
    // h2 chain: D2 -> h2d; n2 = relu(h2@A2 + p12@U1 + ib2); enc2 x2 -> h2ai/h2f
    fused_chain<false><<<1, 512, 0, stream>>>(
        h2ai, p12, nullptr, nullptr,
        wt + (size_t)14 * 32768, wt + (size_t)15 * 32768, wt + (size_t)16 * 32768,
        wt + (size_t)17 * 32768, wt + (size_t)18 * 32768,
        ib2, enc2_b, enc2_b + H, h2d, h2ai, h2f, B);
    // h1 chain: D1 -> h1d; n1 = relu(h1@A1 + (p01s*rdeg1)@U0 + h2d[r/F] + ib1); enc1 x2
    fused_chain<true><<<16, 512, 0, stream>>>(
        h1a, p01s, rdeg1, h2d,
        wt + (size_t)9 * 32768, wt + (size_t)10 * 32768, wt + (size_t)11 * 32768,
        wt + (size_t)12 * 32768, wt + (size_t)13 * 32768,
        ib1, enc1_b, enc1_b + H, h1d, h1a, nullptr, TF);
    // n0 = relu(h0@A0 + h1d[assign0] + ib0)   (in-place, MFMA)
    mgemm<128, false, true><<<MG, 256, 0, stream>>>(
        h0i, wt + (size_t)8 * 32768, nullptr, nullptr, h1d, assign0, ib0, h0i, N);
    encEdgeM(4, 6, enc0_b);
  }

  pool_g0<<<400, 128, 0, stream>>>(h0i, b0, g0s);
  mean40i<<<B, 128, 0, stream>>>(h1a, g1);
  head_k<<<B, 128, 0, stream>>>(g0s, rdegB, g1, h2f, H1w, hb1, H2w, hb2, out);
}

// Round 16
// 776.861 us; speedup vs baseline: 1.3212x; 1.0698x over previous
//
#include <hip/hip_runtime.h>

namespace {

constexpr int N   = 100000;
constexpr int E   = 600000;
constexpr int B   = 50;
constexpr int F   = 40;
constexpr int TF  = B * F;     // 2000
constexpr int D0  = 64;
constexpr int H   = 128;
constexpr int C   = 2;

typedef __attribute__((ext_vector_type(8))) __bf16 bf16x8;
typedef __attribute__((ext_vector_type(8))) unsigned short us8;
typedef __attribute__((ext_vector_type(4))) float f32x4;

__device__ __forceinline__ float asf(unsigned u) { return __uint_as_float(u); }
// round-to-nearest-even fp32 -> bf16 (returns low 16 bits)
__device__ __forceinline__ unsigned bfr(float x) {
  unsigned u = __float_as_uint(x);
  return (u + 0x7FFFu + ((u >> 16) & 1u)) >> 16;
}

// async global->LDS: 16B per lane, LDS dest = uniform base + lane*16,
// global src = per-lane address. Counts in vmcnt (drained by __syncthreads).
__device__ __forceinline__ void glds16(const void* g, void* l) {
  __builtin_amdgcn_global_load_lds(
      (const __attribute__((address_space(1))) unsigned*)g,
      (__attribute__((address_space(3))) unsigned*)l, 16, 0, 0);
}

// ---------------- histograms / CSR build ----------------

__global__ void hist_edges(const int* __restrict__ dst, int* __restrict__ deg) {
  int e = blockIdx.x * 256 + threadIdx.x;
  if (e < E) atomicAdd(&deg[dst[e]], 1);
}

__global__ void hist_nodes(const int* __restrict__ b0, const int* __restrict__ a0l,
                           int* __restrict__ cnt1, int* __restrict__ assign0) {
  __shared__ int lh[TF];
  int t = threadIdx.x;
  for (int j = t; j < TF; j += 256) lh[j] = 0;
  __syncthreads();
  int i = blockIdx.x * 256 + t;
  if (i < N) {
    int g = b0[i];
    int a = g * F + a0l[i];
    assign0[i] = a;
    atomicAdd(&lh[a], 1);
  }
  __syncthreads();
  for (int j = t; j < TF; j += 256) {
    int c = lh[j];
    if (c) atomicAdd(&cnt1[j], c);
  }
}

__global__ void scan1(const int* __restrict__ cnt, int* __restrict__ offs,
                      int* __restrict__ part) {
  __shared__ int lds[256];
  int t = threadIdx.x;
  int base = blockIdx.x * 1024 + t * 4;
  int v[4];
#pragma unroll
  for (int j = 0; j < 4; ++j) v[j] = (base + j < N) ? cnt[base + j] : 0;
  int s = v[0] + v[1] + v[2] + v[3];
  lds[t] = s;
  __syncthreads();
  for (int off = 1; off < 256; off <<= 1) {
    int x = (t >= off) ? lds[t - off] : 0;
    __syncthreads();
    lds[t] += x;
    __syncthreads();
  }
  int ex = lds[t] - s;
  if (t == 255) part[blockIdx.x] = lds[255];
  int run = ex;
#pragma unroll
  for (int j = 0; j < 4; ++j) {
    if (base + j < N) offs[base + j] = run;
    run += v[j];
  }
}

__global__ void scan2(const int* __restrict__ part, int* __restrict__ partEx, int nb) {
  __shared__ int lds[128];
  int t = threadIdx.x;
  int s = (t < nb) ? part[t] : 0;
  lds[t] = s;
  __syncthreads();
  for (int off = 1; off < 128; off <<= 1) {
    int x = (t >= off) ? lds[t - off] : 0;
    __syncthreads();
    lds[t] += x;
    __syncthreads();
  }
  partEx[t] = lds[t] - s;
}

__global__ void scan3(int* __restrict__ offs, const int* __restrict__ partEx,
                      const int* __restrict__ deg, float* __restrict__ rdeg,
                      const int* __restrict__ cnt1, float* __restrict__ rdeg1,
                      float* __restrict__ rdegB) {
  int i = blockIdx.x * 256 + threadIdx.x;
  if (i < N) {
    offs[i] += partEx[i >> 10];
    rdeg[i] = 1.0f / fmaxf((float)deg[i], 1.0f);
    if (i == 0) offs[N] = E;
    if (i < TF) rdeg1[i] = 1.0f / fmaxf((float)cnt1[i], 1.0f);
    if (i < B) {
      int s = 0;
      for (int f = 0; f < F; ++f) s += cnt1[i * F + f];
      rdegB[i] = 1.0f / fmaxf((float)s, 1.0f);
    }
  }
}

__global__ void scatter_k(const int* __restrict__ src, const int* __restrict__ dst,
                          const int* __restrict__ offs, int* __restrict__ cursor,
                          int* __restrict__ srcS) {
  int e = blockIdx.x * 256 + threadIdx.x;
  if (e < E) {
    int d = dst[e];
    int pos = offs[d] + atomicAdd(&cursor[d], 1);
    srcS[pos] = src[e];
  }
}

// ---- weight conversion: fp32 [k][c] -> split-bf16, slice-major, col-permuted ----
struct WPtrs { const float* w[19]; };
__global__ void conv_w(WPtrs wp, unsigned short* __restrict__ wt) {
  int i = blockIdx.x >> 6;                         // matrix index
  int e = (blockIdx.x & 63) * 256 + threadIdx.x;   // 0..16383
  int k = e >> 7, c = e & 127;
  float x = wp.w[i][e];
  unsigned h = bfr(x);
  unsigned l = bfr(x - asf(h << 16));
  int cs = (c & 7) * 16 + (c >> 3);
  size_t o = (size_t)i * 32768 + (k >> 5) * 4096 + cs * 32 + (k & 31);
  wt[o] = (unsigned short)h;
  wt[o + 16384] = (unsigned short)l;
}

// Wp: fp32 [64][128] -> hi (2 slices * 4096) + lo at +8192
__global__ void conv_wp(const float* __restrict__ w, unsigned short* __restrict__ wt) {
  int e = blockIdx.x * 256 + threadIdx.x;  // 0..8191
  int k = e >> 7, c = e & 127;
  float x = w[e];
  unsigned h = bfr(x);
  unsigned l = bfr(x - asf(h << 16));
  int cs = (c & 7) * 16 + (c >> 3);
  size_t o = (size_t)(k >> 5) * 4096 + cs * 32 + (k & 31);
  wt[o] = (unsigned short)h;
  wt[o + 8192] = (unsigned short)l;
}

// x0 fp32 [N][64] -> interleaved rows [hi64 | lo64] (stride 128 shorts)
__global__ void x0split(const float* __restrict__ x0, unsigned short* __restrict__ xs) {
  int i = blockIdx.x * 256 + threadIdx.x;  // elem index
  if (i >= N * D0) return;
  int row = i >> 6, c = i & 63;
  float x = x0[i];
  unsigned h = bfr(x);
  unsigned l = bfr(x - asf(h << 16));
  xs[(size_t)row * 128 + c] = (unsigned short)h;
  xs[(size_t)row * 128 + 64 + c] = (unsigned short)l;
}

// ---- L3/L2 warm: touch the chain weight region so chain misses are cheap ----
__global__ void warm_k(const uint4* __restrict__ w, unsigned* __restrict__ dummy) {
  uint4 v = w[blockIdx.x * 256 + threadIdx.x];
  unsigned x = v.x ^ v.y ^ v.z ^ v.w;
  if (x == 0xDEADBEEFu) dummy[0] = 1u;  // keeps loads live; deterministic
}

// ---------------- edge aggregation: hi(bf16)-plane-only gather ----------------
__global__ void agg_k(const unsigned short* __restrict__ Act,
                      const int* __restrict__ offs, const int* __restrict__ srcS,
                      const float* __restrict__ rdeg, unsigned short* __restrict__ Out) {
  int wid = blockIdx.x * 4 + (threadIdx.x >> 6);
  int lane = threadIdx.x & 63;
  if (wid >= N) return;
  int o0 = offs[wid], o1 = offs[wid + 1];
  float s0 = 0.f, s1 = 0.f;
  int e = o0;
  for (; e + 3 < o1; e += 4) {
    unsigned v0 = *(const unsigned*)(Act + (size_t)srcS[e] * 256 + lane * 2);
    unsigned v1 = *(const unsigned*)(Act + (size_t)srcS[e + 1] * 256 + lane * 2);
    unsigned v2 = *(const unsigned*)(Act + (size_t)srcS[e + 2] * 256 + lane * 2);
    unsigned v3 = *(const unsigned*)(Act + (size_t)srcS[e + 3] * 256 + lane * 2);
    s0 += asf(v0 << 16) + asf(v1 << 16) + asf(v2 << 16) + asf(v3 << 16);
    s1 += asf(v0 & 0xFFFF0000u) + asf(v1 & 0xFFFF0000u) +
          asf(v2 & 0xFFFF0000u) + asf(v3 & 0xFFFF0000u);
  }
  for (; e < o1; ++e) {
    unsigned v0 = *(const unsigned*)(Act + (size_t)srcS[e] * 256 + lane * 2);
    s0 += asf(v0 << 16);
    s1 += asf(v0 & 0xFFFF0000u);
  }
  float sc = rdeg[wid];
  unsigned h0 = bfr(s0 * sc), h1 = bfr(s1 * sc);
  *(unsigned*)(Out + (size_t)wid * 256 + lane * 2) = h0 | (h1 << 16);
}

// ---------------- split-bf16 MFMA GEMM, LDS-staged weights (N-row layers) ----
template <int KD, bool AGG, bool GATH, bool BLO = true>
__global__ __launch_bounds__(256, 3)
void mgemm(const unsigned short* __restrict__ Ai, const unsigned short* __restrict__ W1,
           const unsigned short* __restrict__ Bi, const unsigned short* __restrict__ W2,
           const float* __restrict__ Gt, const int* __restrict__ Gidx,
           const float* __restrict__ bias, unsigned short* __restrict__ Oi, int n) {
  __shared__ unsigned short wlds[2][2][4096];  // [buf][hi/lo][slice]
  constexpr int KS = KD / 32;
  constexpr int NS = (AGG ? 2 : 1) * KS;
  constexpr int KLO = KD * 128;
  constexpr int ARS = 2 * KD;
  const int t = threadIdx.x, wv = t >> 6, ln = t & 63;
  const int row0 = blockIdx.x * 128 + wv * 32;
  const int lm = ln & 15, kg = ln >> 4;
  int ar0 = row0 + lm, ar1 = row0 + 16 + lm;
  if (ar0 >= n) ar0 = 0;
  if (ar1 >= n) ar1 = 0;
  const size_t a0off = (size_t)ar0 * ARS, a1off = (size_t)ar1 * ARS;

  f32x4 acc[2][8];
#pragma unroll
  for (int i = 0; i < 2; ++i)
#pragma unroll
    for (int j = 0; j < 8; ++j) acc[i][j] = (f32x4){0.f, 0.f, 0.f, 0.f};

  uint4 sA, sB, sC, sD;
  bf16x8 a0h[2], a0l[2], a1h[2], a1l[2];

  auto ldst = [&](int s) {
    const unsigned short* W = (AGG && s >= KS) ? W2 : W1;
    const unsigned short* ph = W + (s & (KS - 1)) * 4096;
    sA = *(const uint4*)(ph + t * 8);
    sB = *(const uint4*)(ph + 2048 + t * 8);
    sC = *(const uint4*)(ph + KLO + t * 8);
    sD = *(const uint4*)(ph + KLO + 2048 + t * 8);
  };
  auto wrst = [&](int buf) {
    *(uint4*)&wlds[buf][0][t * 8] = sA;
    *(uint4*)&wlds[buf][0][2048 + t * 8] = sB;
    *(uint4*)&wlds[buf][1][t * 8] = sC;
    *(uint4*)&wlds[buf][1][2048 + t * 8] = sD;
  };
  auto loadA = [&](int s, int w) {
    const bool bpass = AGG && (s >= KS);
    const unsigned short* X = bpass ? Bi : Ai;
    int kk = (s & (KS - 1)) * 32 + kg * 8;
    a0h[w] = *(const bf16x8*)(X + a0off + kk);
    a1h[w] = *(const bf16x8*)(X + a1off + kk);
    if (!bpass || BLO) {
      a0l[w] = *(const bf16x8*)(X + a0off + KD + kk);
      a1l[w] = *(const bf16x8*)(X + a1off + KD + kk);
    }
  };

  ldst(0); wrst(0); loadA(0, 0);
  __syncthreads();

#pragma unroll
  for (int s = 0; s < NS; ++s) {
    const int buf = s & 1;
    const bool uselo = !(AGG && (s >= KS)) || BLO;
    if (s + 1 < NS) { ldst(s + 1); loadA(s + 1, buf ^ 1); }
#pragma unroll
    for (int nf = 0; nf < 8; ++nf) {
      const int wo = (nf * 16 + lm) * 32 + kg * 8;
      bf16x8 wh = *(const bf16x8*)&wlds[buf][0][wo];
      bf16x8 wl = *(const bf16x8*)&wlds[buf][1][wo];
      acc[0][nf] = __builtin_amdgcn_mfma_f32_16x16x32_bf16(a0h[buf], wh, acc[0][nf], 0, 0, 0);
      acc[0][nf] = __builtin_amdgcn_mfma_f32_16x16x32_bf16(a0h[buf], wl, acc[0][nf], 0, 0, 0);
      if (uselo)
        acc[0][nf] = __builtin_amdgcn_mfma_f32_16x16x32_bf16(a0l[buf], wh, acc[0][nf], 0, 0, 0);
      acc[1][nf] = __builtin_amdgcn_mfma_f32_16x16x32_bf16(a1h[buf], wh, acc[1][nf], 0, 0, 0);
      acc[1][nf] = __builtin_amdgcn_mfma_f32_16x16x32_bf16(a1h[buf], wl, acc[1][nf], 0, 0, 0);
      if (uselo)
        acc[1][nf] = __builtin_amdgcn_mfma_f32_16x16x32_bf16(a1l[buf], wh, acc[1][nf], 0, 0, 0);
    }
    if (s + 1 < NS) wrst(buf ^ 1);
    __syncthreads();
  }

  float4 bq0 = *(const float4*)&bias[lm * 8];
  float4 bq1 = *(const float4*)&bias[lm * 8 + 4];
  float bsv[8] = {bq0.x, bq0.y, bq0.z, bq0.w, bq1.x, bq1.y, bq1.z, bq1.w};
#pragma unroll
  for (int mf = 0; mf < 2; ++mf)
#pragma unroll
    for (int rr = 0; rr < 4; ++rr) {
      int row = row0 + mf * 16 + kg * 4 + rr;
      if (row >= n) continue;
      float gvv[8];
      if (GATH) {
        const float* grow = Gt + (size_t)Gidx[row] * H + lm * 8;
        float4 g0 = *(const float4*)grow;
        float4 g1 = *(const float4*)(grow + 4);
        gvv[0] = g0.x; gvv[1] = g0.y; gvv[2] = g0.z; gvv[3] = g0.w;
        gvv[4] = g1.x; gvv[5] = g1.y; gvv[6] = g1.z; gvv[7] = g1.w;
      }
      us8 hv, lv;
#pragma unroll
      for (int nf = 0; nf < 8; ++nf) {
        float v = acc[mf][nf][rr] + bsv[nf];
        if (GATH) v += gvv[nf];
        v = fmaxf(v, 0.f);
        unsigned h = bfr(v);
        hv[nf] = (unsigned short)h;
        lv[nf] = (unsigned short)bfr(v - asf(h << 16));
      }
      *(us8*)(Oi + (size_t)row * 256 + lm * 8) = hv;
      *(us8*)(Oi + (size_t)row * 256 + 128 + lm * 8) = lv;
    }
}

// ---------------- initial h2d = h2 @ D2 (once, before step loop) ----------------
// 1 block, 512 threads. D2 (64KB) staged whole: 512 thr x 8 glds16 rounds of
// 1KB/wave = 64KB. Waves 0-3 compute 16 rows each (64 >= B).
__global__ __launch_bounds__(512)
void h2d_k(const unsigned short* __restrict__ h2ai, const unsigned short* __restrict__ Wm,
           float* __restrict__ h2d) {
  __shared__ unsigned short wl[32768];  // 64KB
  const int t = threadIdx.x, wv = t >> 6, ln = t & 63;
  const int lm = ln & 15, kg = ln >> 4;
  const int lo8 = ln * 8;
#pragma unroll
  for (int j = 0; j < 8; ++j)
    glds16(Wm + (wv * 8 + j) * 512 + lo8, &wl[(wv * 8 + j) * 512]);
  __syncthreads();
  if (wv >= 4) return;
  int ar = wv * 16 + lm;
  if (ar >= B) ar = 0;
  f32x4 acc[8];
#pragma unroll
  for (int nf = 0; nf < 8; ++nf) acc[nf] = (f32x4){0.f, 0.f, 0.f, 0.f};
#pragma unroll
  for (int ks = 0; ks < 4; ++ks) {
    bf16x8 ah = *(const bf16x8*)(h2ai + (size_t)ar * 256 + ks * 32 + kg * 8);
    bf16x8 al = *(const bf16x8*)(h2ai + (size_t)ar * 256 + 128 + ks * 32 + kg * 8);
#pragma unroll
    for (int nf = 0; nf < 8; ++nf) {
      const int wo = ks * 4096 + (nf * 16 + lm) * 32 + kg * 8;
      bf16x8 wh = *(const bf16x8*)&wl[wo];
      bf16x8 wq = *(const bf16x8*)&wl[16384 + wo];
      acc[nf] = __builtin_amdgcn_mfma_f32_16x16x32_bf16(ah, wh, acc[nf], 0, 0, 0);
      acc[nf] = __builtin_amdgcn_mfma_f32_16x16x32_bf16(ah, wq, acc[nf], 0, 0, 0);
      acc[nf] = __builtin_amdgcn_mfma_f32_16x16x32_bf16(al, wh, acc[nf], 0, 0, 0);
    }
  }
#pragma unroll
  for (int rr = 0; rr < 4; ++rr) {
    int rg = wv * 16 + kg * 4 + rr;
    if (rg < B) {
      float* op = h2d + (size_t)rg * H + lm * 8;
      *(float4*)op = make_float4(acc[0][rr], acc[1][rr], acc[2][rr], acc[3][rr]);
      *(float4*)(op + 4) = make_float4(acc[4][rr], acc[5][rr], acc[6][rr], acc[7][rr]);
    }
  }
}

// ---------------- merged small-scale chains: 17 blocks x 512 threads ----------
// Blocks 0-15: h1 chain (10 stages); block 16: h2 chain (12 stages: the extra
// two stream D2 again and emit NEXT step's h2d from the new h2 -- double-
// buffered h2d so h1 blocks' gather of the CURRENT h2d never races it).
// Merging hides the h2 chain's ~50us serial latency under the h1 chain.
struct ChainArgs {
  const unsigned short* Ai1; const unsigned short* Ai2;
  const float* P1; const float* P2; const float* ps1;
  const float* Gt1;                       // current h2d (h1 gather)
  const unsigned short* w1[5];
  const unsigned short* w2[6];            // 6th = D2 (stages 10-11)
  const float *bn1, *be01, *be11, *bn2, *be02, *be12;
  float* outD1;                           // h1d
  unsigned short* Ao1; unsigned short* Ao2;
  float* outF2;                           // h2f
  float* outDn2;                          // next h2d (stage-11 store)
  int n1, n2;
};

__global__ __launch_bounds__(512)
void fused_chain2(ChainArgs a) {
  __shared__ unsigned short act[128 * 256];   // 64KB: 128 interleaved rows
  __shared__ unsigned short wl[2][16384];     // 2 x 32KB halves (hi|lo)
  const bool role = (blockIdx.x == 16);       // true = h2 chain
  const int t = threadIdx.x, wv = t >> 6, ln = t & 63;
  const int lm = ln & 15, kg = ln >> 4;
  const int rbase = (role ? 0 : blockIdx.x * 128) + wv * 16;
  const int lbase = wv * 16;
  const int n = role ? a.n2 : a.n1;
  const int nst = role ? 12 : 10;
  const unsigned short* Ai = role ? a.Ai2 : a.Ai1;
  const float* P = role ? a.P2 : a.P1;
  unsigned short* Ao = role ? a.Ao2 : a.Ao1;
  const float* bn  = role ? a.bn2 : a.bn1;
  const float* be0 = role ? a.be02 : a.be01;
  const float* be1 = role ? a.be12 : a.be11;
  int ar = rbase + lm;
  if (ar >= n) ar = 0;

  const unsigned short* mats[6];
  if (role) {
#pragma unroll
    for (int i = 0; i < 6; ++i) mats[i] = a.w2[i];
  } else {
#pragma unroll
    for (int i = 0; i < 5; ++i) mats[i] = a.w1[i];
    mats[5] = a.w1[0];  // unused (nst=10)
  }

  f32x4 acc[8];
  auto zacc = [&]() {
#pragma unroll
    for (int nf = 0; nf < 8; ++nf) acc[nf] = (f32x4){0.f, 0.f, 0.f, 0.f};
  };

  // half s into wl[b]: per wave 2 glds hi + 2 glds lo (512 shorts each)
  auto ldwl = [&](int s, int b) {
    const unsigned short* hi = mats[s >> 1] + (s & 1) * 8192;
    const unsigned short* lo = mats[s >> 1] + 16384 + (s & 1) * 8192;
    const int wo = wv * 1024;
    const int lo8 = ln * 8;
#pragma unroll
    for (int j = 0; j < 2; ++j) {
      glds16(hi + wo + j * 512 + lo8, &wl[b][wo + j * 512]);
      glds16(lo + wo + j * 512 + lo8, &wl[b][8192 + wo + j * 512]);
    }
  };
  // preload this block's 128 interleaved rows (linear 64KB): 8 glds/wave
  auto ldact = [&]() {
    const unsigned short* src = Ai + (size_t)(role ? 0 : blockIdx.x) * (128 * 256);
    const int base = wv * 4096;
    const int lo8 = ln * 8;
#pragma unroll
    for (int j = 0; j < 8; ++j)
      glds16(src + base + j * 512 + lo8, &act[base + j * 512]);
  };

  auto donf = [&](int b, int ksl, bf16x8 ah, bf16x8 al) {
#pragma unroll
    for (int nf = 0; nf < 8; ++nf) {
      const int wo = ksl * 4096 + (nf * 16 + lm) * 32 + kg * 8;
      bf16x8 wh = *(const bf16x8*)&wl[b][wo];
      bf16x8 wq = *(const bf16x8*)&wl[b][8192 + wo];
      acc[nf] = __builtin_amdgcn_mfma_f32_16x16x32_bf16(ah, wh, acc[nf], 0, 0, 0);
      acc[nf] = __builtin_amdgcn_mfma_f32_16x16x32_bf16(ah, wq, acc[nf], 0, 0, 0);
      acc[nf] = __builtin_amdgcn_mfma_f32_16x16x32_bf16(al, wh, acc[nf], 0, 0, 0);
    }
  };

  auto epiAct = [&](const float* bias, bool gath) {
    float4 b0 = *(const float4*)&bias[lm * 8];
    float4 b1 = *(const float4*)&bias[lm * 8 + 4];
    float bv[8] = {b0.x, b0.y, b0.z, b0.w, b1.x, b1.y, b1.z, b1.w};
#pragma unroll
    for (int rr = 0; rr < 4; ++rr) {
      int rl = lbase + kg * 4 + rr;
      int rg = rbase + kg * 4 + rr;
      float gv[8] = {0.f, 0.f, 0.f, 0.f, 0.f, 0.f, 0.f, 0.f};
      if (!role && gath && rg < n) {
        const float* grow = a.Gt1 + (size_t)(rg / F) * H + lm * 8;
        float4 g0 = *(const float4*)grow;
        float4 g1 = *(const float4*)(grow + 4);
        gv[0] = g0.x; gv[1] = g0.y; gv[2] = g0.z; gv[3] = g0.w;
        gv[4] = g1.x; gv[5] = g1.y; gv[6] = g1.z; gv[7] = g1.w;
      }
      us8 hv, lv;
#pragma unroll
      for (int nf = 0; nf < 8; ++nf) {
        float v = acc[nf][rr] + bv[nf] + gv[nf];
        v = fmaxf(v, 0.f);
        unsigned h = bfr(v);
        hv[nf] = (unsigned short)h;
        lv[nf] = (unsigned short)bfr(v - asf(h << 16));
      }
      *(us8*)&act[rl * 256 + lm * 8] = hv;
      *(us8*)&act[rl * 256 + 128 + lm * 8] = lv;
    }
  };

  // ---- pipeline prologue: one exposed drain ----
  ldact();
  ldwl(0, 0);
  __syncthreads();           // drains act preload + half 0
  ldwl(1, 1);                // half 1 in flight across stage-0 MFMA

  for (int s = 0; s < nst; ++s) {
    const int b = s & 1;
    if ((s & 1) == 0 && s != 4) zacc();   // s = 0,2,6,8,10
    const int m = s >> 1;
    for (int ksl = 0; ksl < 2; ++ksl) {
      const int ks = (s & 1) * 2 + ksl;
      bf16x8 ah, al;
      if (m == 2) {           // Wu pass: A from fp32 P (h1: scaled by ps1)
        const float* pp = P + (size_t)ar * H + ks * 32 + kg * 8;
        float4 f0 = *(const float4*)pp;
        float4 f1 = *(const float4*)(pp + 4);
        if (!role) {
          float sc = a.ps1[ar];
          f0.x *= sc; f0.y *= sc; f0.z *= sc; f0.w *= sc;
          f1.x *= sc; f1.y *= sc; f1.z *= sc; f1.w *= sc;
        }
        float fv[8] = {f0.x, f0.y, f0.z, f0.w, f1.x, f1.y, f1.z, f1.w};
        us8 h8, l8;
#pragma unroll
        for (int j = 0; j < 8; ++j) {
          unsigned h = bfr(fv[j]);
          h8[j] = (unsigned short)h;
          l8[j] = (unsigned short)bfr(fv[j] - asf(h << 16));
        }
        ah = __builtin_bit_cast(bf16x8, h8);
        al = __builtin_bit_cast(bf16x8, l8);
      } else {                // all other passes: A from act (wave-private rows)
        int rl = lbase + lm;
        ah = *(const bf16x8*)&act[rl * 256 + ks * 32 + kg * 8];
        al = *(const bf16x8*)&act[rl * 256 + 128 + ks * 32 + kg * 8];
      }
      donf(b, ksl, ah, al);
    }
    // ---- epilogues ----
    if (s == 1 && !role) {    // h1: D-pass -> h1d (h2's h2d is precomputed)
#pragma unroll
      for (int rr = 0; rr < 4; ++rr) {
        int rg = rbase + kg * 4 + rr;
        if (rg < n) {
          float* op = a.outD1 + (size_t)rg * H + lm * 8;
          *(float4*)op = make_float4(acc[0][rr], acc[1][rr], acc[2][rr], acc[3][rr]);
          *(float4*)(op + 4) = make_float4(acc[4][rr], acc[5][rr], acc[6][rr], acc[7][rr]);
        }
      }
    }
    if (s == 5) epiAct(bn, true);
    if (s == 7) epiAct(be0, false);
    if (s == 9) {
      float4 b0 = *(const float4*)&be1[lm * 8];
      float4 b1 = *(const float4*)&be1[lm * 8 + 4];
      float bv[8] = {b0.x, b0.y, b0.z, b0.w, b1.x, b1.y, b1.z, b1.w};
#pragma unroll
      for (int rr = 0; rr < 4; ++rr) {
        int rl = lbase + kg * 4 + rr;
        int rg = rbase + kg * 4 + rr;
        us8 hv, lv;
        float fv[8];
#pragma unroll
        for (int nf = 0; nf < 8; ++nf) {
          float v = fmaxf(acc[nf][rr] + bv[nf], 0.f);
          fv[nf] = v;
          unsigned h = bfr(v);
          hv[nf] = (unsigned short)h;
          lv[nf] = (unsigned short)bfr(v - asf(h << 16));
        }
        if (role) {           // h2: also keep new h2 in act for stages 10-11
          *(us8*)&act[rl * 256 + lm * 8] = hv;
          *(us8*)&act[rl * 256 + 128 + lm * 8] = lv;
        }
        if (rg < n) {
          *(us8*)(Ao + (size_t)rg * 256 + lm * 8) = hv;
          *(us8*)(Ao + (size_t)rg * 256 + 128 + lm * 8) = lv;
          if (role) {
            float* op = a.outF2 + (size_t)rg * H + lm * 8;
            *(float4*)op = make_float4(fv[0], fv[1], fv[2], fv[3]);
            *(float4*)(op + 4) = make_float4(fv[4], fv[5], fv[6], fv[7]);
          }
        }
      }
    }
    if (s == 11) {            // h2: next step's h2d = h2_new @ D2 (raw)
#pragma unroll
      for (int rr = 0; rr < 4; ++rr) {
        int rg = rbase + kg * 4 + rr;
        if (rg < n) {
          float* op = a.outDn2 + (size_t)rg * H + lm * 8;
          *(float4*)op = make_float4(acc[0][rr], acc[1][rr], acc[2][rr], acc[3][rr]);
          *(float4*)(op + 4) = make_float4(acc[4][rr], acc[5][rr], acc[6][rr], acc[7][rr]);
        }
      }
    }
    if (s + 1 < nst) {
      __syncthreads();            // all waves done with wl[b]; drains s+1 loads
      if (s + 2 < nst) ldwl(s + 2, b);  // refill the buffer just released
    }
  }
}

// ---------------- initial h1/h2: enc-plain on zeros => identical rows ----------------
__global__ void init_bcast(const float* __restrict__ Ws1, const float* __restrict__ b1,
                           const float* __restrict__ Ws2, const float* __restrict__ b2,
                           unsigned short* __restrict__ h1i, unsigned short* __restrict__ h2i) {
  __shared__ float z0[128];
  int t = threadIdx.x;  // 128
  bool ish2 = (blockIdx.x == 20);
  const float* W = ish2 ? Ws2 : Ws1;
  const float* bb = ish2 ? b2 : b1;
  z0[t] = fmaxf(bb[t], 0.f);
  __syncthreads();
  float s = bb[128 + t];
  for (int k = 0; k < 128; ++k) s += z0[k] * W[16384 + k * 128 + t];
  s = fmaxf(s, 0.f);
  unsigned h = bfr(s);
  unsigned l = bfr(s - asf(h << 16));
  if (ish2) {
    for (int r = 0; r < B; ++r) {
      h2i[(size_t)r * 256 + t] = (unsigned short)h;
      h2i[(size_t)r * 256 + 128 + t] = (unsigned short)l;
    }
  } else {
    int r0 = blockIdx.x * 100;
    for (int r = 0; r < 100; ++r) {
      h1i[(size_t)(r0 + r) * 256 + t] = (unsigned short)h;
      h1i[(size_t)(r0 + r) * 256 + 128 + t] = (unsigned short)l;
    }
  }
}

// ---------------- pooling (interleaved rows) ----------------
__global__ void pool_p01(const unsigned short* __restrict__ Act,
                         const int* __restrict__ a0l, const int* __restrict__ b0,
                         float* __restrict__ p01s) {
  __shared__ float acc[F][H];
  int t = threadIdx.x;  // 128
#pragma unroll
  for (int f = 0; f < F; ++f) acc[f][t] = 0.f;
  int rowbase = blockIdx.x * 250;
  for (int i = 0; i < 250; ++i) {
    size_t r = (size_t)(rowbase + i) * 256 + t;
    acc[a0l[rowbase + i]][t] += asf((unsigned)Act[r] << 16) + asf((unsigned)Act[r + 128] << 16);
  }
  int g = b0[rowbase];
#pragma unroll
  for (int f = 0; f < F; ++f)
    atomicAdd(&p01s[((size_t)(g * F + f)) * H + t], acc[f][t]);
}

__global__ void pool_g0(const unsigned short* __restrict__ Act,
                        const int* __restrict__ b0, float* __restrict__ g0s) {
  int t = threadIdx.x;
  int rowbase = blockIdx.x * 250;
  float a = 0.f;
  for (int i = 0; i < 250; ++i) {
    size_t r = (size_t)(rowbase + i) * 256 + t;
    a += asf((unsigned)Act[r] << 16) + asf((unsigned)Act[r + 128] << 16);
  }
  atomicAdd(&g0s[(size_t)b0[rowbase] * H + t], a);
}

// mean over F contiguous interleaved-bf16 rows per graph -> fp32
__global__ void mean40i(const unsigned short* __restrict__ Act, float* __restrict__ outp) {
  int t = threadIdx.x, g = blockIdx.x;
  float a = 0.f;
  for (int i = 0; i < F; ++i) {
    size_t r = (size_t)(g * F + i) * 256 + t;
    a += asf((unsigned)Act[r] << 16) + asf((unsigned)Act[r + 128] << 16);
  }
  outp[(size_t)g * H + t] = a * (1.0f / F);
}

// ---------------- head MLP ----------------
__global__ void head_k(const float* __restrict__ g0s, const float* __restrict__ rdegB,
                       const float* __restrict__ g1, const float* __restrict__ h2,
                       const float* __restrict__ W1h, const float* __restrict__ b1h,
                       const float* __restrict__ W2h, const float* __restrict__ b2h,
                       float* __restrict__ out) {
  __shared__ float gv[3 * H];
  __shared__ float z[H];
  int b = blockIdx.x, t = threadIdx.x;
  gv[t] = g0s[(size_t)b * H + t] * rdegB[b];
  gv[H + t] = g1[(size_t)b * H + t];
  gv[2 * H + t] = h2[(size_t)b * H + t];
  __syncthreads();
  float s = b1h[t];
  for (int k = 0; k < 3 * H; ++k) s += gv[k] * W1h[k * H + t];
  z[t] = fmaxf(s, 0.f);
  __syncthreads();
  if (t < C) {
    float o = b2h[t];
    for (int k = 0; k < H; ++k) o += z[k] * W2h[k * C + t];
    out[b * C + t] = o;
  }
}

}  // namespace

extern "C" void kernel_launch(void* const* d_in, const int* in_sizes, int n_in,
                              void* d_out, int out_size, void* d_ws, size_t ws_size,
                              hipStream_t stream) {
  (void)in_sizes; (void)n_in; (void)out_size; (void)ws_size;
  const float* x0   = (const float*)d_in[0];
  const int*   ei   = (const int*)d_in[1];
  const int*   src  = ei;
  const int*   dst  = ei + E;
  const int*   b0   = (const int*)d_in[2];
  const int*   a0l  = (const int*)d_in[3];
  const float* Wp   = (const float*)d_in[4];
  const float* bp   = (const float*)d_in[5];
  const float* e0in_Ws = (const float*)d_in[6];
  const float* e0in_Wn = (const float*)d_in[7];
  const float* e0in_b  = (const float*)d_in[8];
  const float* enc0_Ws = (const float*)d_in[9];
  const float* enc0_Wn = (const float*)d_in[10];
  const float* enc0_b  = (const float*)d_in[11];
  const float* e1in_Ws = (const float*)d_in[12];
  const float* e1in_b  = (const float*)d_in[13];
  const float* e2in_Ws = (const float*)d_in[14];
  const float* e2in_b  = (const float*)d_in[15];
  const float* enc1_Ws = (const float*)d_in[16];
  const float* enc1_b  = (const float*)d_in[17];
  const float* enc2_Ws = (const float*)d_in[18];
  const float* enc2_b  = (const float*)d_in[19];
  const float* A0 = (const float*)d_in[20];
  const float* A1 = (const float*)d_in[21];
  const float* A2 = (const float*)d_in[22];
  const float* U0 = (const float*)d_in[23];
  const float* U1 = (const float*)d_in[24];
  const float* D1 = (const float*)d_in[25];
  const float* D2 = (const float*)d_in[26];
  const float* ib0 = (const float*)d_in[27];
  const float* ib1 = (const float*)d_in[28];
  const float* ib2 = (const float*)d_in[29];
  const float* H1w = (const float*)d_in[30];
  const float* hb1 = (const float*)d_in[31];
  const float* H2w = (const float*)d_in[32];
  const float* hb2 = (const float*)d_in[33];
  float* out = (float*)d_out;

  // ---- workspace carve ----
  char* p = (char*)d_ws;
  auto carve = [&](size_t bytes) {
    char* r = p;
    p += (bytes + 255) & ~(size_t)255;
    return r;
  };
  char* z0 = p;  // zeroed-every-call region
  int*   deg    = (int*)carve((size_t)N * 4);
  int*   cursor = (int*)carve((size_t)N * 4);
  int*   cnt1   = (int*)carve((size_t)TF * 4);
  float* g0s    = (float*)carve((size_t)B * H * 4);
  size_t zbytes = (size_t)(p - z0);
  unsigned short* h0i  = (unsigned short*)carve((size_t)N * 256 * 2);
  unsigned short* aggi = (unsigned short*)carve((size_t)N * 256 * 2);
  unsigned short* h1a  = (unsigned short*)carve((size_t)2048 * 256 * 2);  // 16 blocks x 128 rows
  unsigned short* h2ai = (unsigned short*)carve((size_t)128 * 256 * 2);   // padded to 128 rows
  float* h1d  = (float*)carve((size_t)TF * H * 4);
  float* h2dA = (float*)carve((size_t)64 * H * 4);
  float* h2dB = (float*)carve((size_t)64 * H * 4);
  float* h2f  = (float*)carve((size_t)B * H * 4);
  float* p01s = (float*)carve((size_t)TF * H * 4);
  float* p12  = (float*)carve((size_t)64 * H * 4);
  float* g1   = (float*)carve((size_t)B * H * 4);
  float* rdeg = (float*)carve((size_t)N * 4);
  float* rdeg1 = (float*)carve((size_t)TF * 4);
  float* rdegB = (float*)carve(64 * 4);
  int* offs    = (int*)carve((size_t)(N + 64) * 4);
  int* srcS    = (int*)carve((size_t)E * 4);
  int* part    = (int*)carve(128 * 4);
  int* partEx  = (int*)carve(128 * 4);
  int* assign0 = (int*)carve((size_t)N * 4);
  unsigned short* wt  = (unsigned short*)carve((size_t)19 * 32768 * 2);
  unsigned short* wt9 = (unsigned short*)carve((size_t)16384 * 2);
  unsigned short* xs  = aggi;  // alias: x0-split used only before first agg_k

  const int HH = H * H;
  const int MG = (N + 127) / 128;  // 782

  // ---- CSR + histograms + weight/x0 split ----
  hipMemsetAsync(z0, 0, zbytes, stream);
  hist_edges<<<(E + 255) / 256, 256, 0, stream>>>(dst, deg);
  hist_nodes<<<(N + 255) / 256, 256, 0, stream>>>(b0, a0l, cnt1, assign0);
  const int nb1 = (N + 1023) / 1024;
  scan1<<<nb1, 256, 0, stream>>>(deg, offs, part);
  scan2<<<1, 128, 0, stream>>>(part, partEx, nb1);
  scan3<<<(N + 255) / 256, 256, 0, stream>>>(offs, partEx, deg, rdeg, cnt1, rdeg1,
                                             rdegB);
  scatter_k<<<(E + 255) / 256, 256, 0, stream>>>(src, dst, offs, cursor, srcS);
  {
    WPtrs wp;
    wp.w[0] = e0in_Ws;      wp.w[1] = e0in_Ws + HH;
    wp.w[2] = e0in_Wn;      wp.w[3] = e0in_Wn + HH;
    wp.w[4] = enc0_Ws;      wp.w[5] = enc0_Ws + HH;
    wp.w[6] = enc0_Wn;      wp.w[7] = enc0_Wn + HH;
    wp.w[8] = A0;
    wp.w[9] = D1;           wp.w[10] = A1;
    wp.w[11] = U0;          wp.w[12] = enc1_Ws;   wp.w[13] = enc1_Ws + HH;
    wp.w[14] = D2;          wp.w[15] = A2;
    wp.w[16] = U1;          wp.w[17] = enc2_Ws;   wp.w[18] = enc2_Ws + HH;
    conv_w<<<19 * 64, 256, 0, stream>>>(wp, wt);
  }
  conv_wp<<<32, 256, 0, stream>>>(Wp, wt9);
  x0split<<<(N * D0 + 255) / 256, 256, 0, stream>>>(x0, xs);

  // ---- input projection (MFMA, K=64) ----
  mgemm<64, false, false><<<MG, 256, 0, stream>>>(
      xs, wt9, nullptr, nullptr, nullptr, nullptr, bp, h0i, N);

  auto encEdgeM = [&](int wsIdx, int wnIdx, const float* barr) {
    for (int l = 0; l < 2; ++l) {
      agg_k<<<N / 4, 256, 0, stream>>>(h0i, offs, srcS, rdeg, aggi);
      mgemm<128, true, false, false><<<MG, 256, 0, stream>>>(
          h0i, wt + (size_t)(wsIdx + l) * 32768, aggi,
          wt + (size_t)(wnIdx + l) * 32768, nullptr, nullptr, barr + l * H, h0i, N);
    }
  };

  encEdgeM(0, 2, e0in_b);
  init_bcast<<<21, 128, 0, stream>>>(e1in_Ws, e1in_b, e2in_Ws, e2in_b, h1a, h2ai);
  // initial h2d = h2_init @ D2
  h2d_k<<<1, 512, 0, stream>>>(h2ai, wt + (size_t)14 * 32768, h2dA);

  float* h2dbuf[2] = {h2dA, h2dB};
  for (int step = 0; step < 2; ++step) {
    hipMemsetAsync(p01s, 0, (size_t)TF * H * 4, stream);
    pool_p01<<<400, 128, 0, stream>>>(h0i, a0l, b0, p01s);
    mean40i<<<B, 128, 0, stream>>>(h1a, p12);
    // warm chain weights (10 matrices = 640KB) into L3/L2
    warm_k<<<160, 256, 0, stream>>>((const uint4*)(wt + (size_t)9 * 32768),
                                    (unsigned*)cursor);
    // merged h1+h2 chains (17 blocks); h2 block also emits next step's h2d
    {
      ChainArgs ca;
      ca.Ai1 = h1a;  ca.Ai2 = h2ai;
      ca.P1 = p01s;  ca.P2 = p12;  ca.ps1 = rdeg1;
      ca.Gt1 = h2dbuf[step & 1];
      ca.w1[0] = wt + (size_t)9 * 32768;  ca.w1[1] = wt + (size_t)10 * 32768;
      ca.w1[2] = wt + (size_t)11 * 32768; ca.w1[3] = wt + (size_t)12 * 32768;
      ca.w1[4] = wt + (size_t)13 * 32768;
      ca.w2[0] = wt + (size_t)14 * 32768; ca.w2[1] = wt + (size_t)15 * 32768;
      ca.w2[2] = wt + (size_t)16 * 32768; ca.w2[3] = wt + (size_t)17 * 32768;
      ca.w2[4] = wt + (size_t)18 * 32768; ca.w2[5] = wt + (size_t)14 * 32768;
      ca.bn1 = ib1;  ca.be01 = enc1_b;  ca.be11 = enc1_b + H;
      ca.bn2 = ib2;  ca.be02 = enc2_b;  ca.be12 = enc2_b + H;
      ca.outD1 = h1d;
      ca.Ao1 = h1a;  ca.Ao2 = h2ai;
      ca.outF2 = h2f;
      ca.outDn2 = h2dbuf[(step + 1) & 1];
      ca.n1 = TF;  ca.n2 = B;
      fused_chain2<<<17, 512, 0, stream>>>(ca);
    }
    // n0 = relu(h0@A0 + h1d[assign0] + ib0)   (in-place, MFMA)
    mgemm<128, false, true><<<MG, 256, 0, stream>>>(
        h0i, wt + (size_t)8 * 32768, nullptr, nullptr, h1d, assign0, ib0, h0i, N);
    encEdgeM(4, 6, enc0_b);
  }

  pool_g0<<<400, 128, 0, stream>>>(h0i, b0, g0s);
  mean40i<<<B, 128, 0, stream>>>(h1a, g1);
  head_k<<<B, 128, 0, stream>>>(g0s, rdegB, g1, h2f, H1w, hb1, H2w, hb2, out);
}